// Round 1
// baseline (1336.821 us; speedup 1.0000x reference)
//
#include <hip/hip_runtime.h>
#include <math.h>

#define NEG_SLOPE 0.2f

__device__ __forceinline__ float leaky(float x) { return x >= 0.f ? x : NEG_SLOPE * x; }
__device__ __forceinline__ float elu1(float x)  { return x > 0.f ? x : expm1f(x); }

// ---------------- K1: h1 = x @ W1 : [N,512] @ [512,64] -> [N,64] ----------------
__global__ __launch_bounds__(256) void k_gemm1(const float* __restrict__ x,
                                               const float* __restrict__ W,
                                               float* __restrict__ h1, int N) {
  __shared__ float xs[64][33];
  __shared__ float ws[32][64];
  const int t = threadIdx.x;
  const int rowbase = blockIdx.x * 64;
  const int r0 = (t >> 4) << 2;   // 0..60
  const int c0 = (t & 15) << 2;   // 0..60
  float acc[4][4] = {};
  const int lr = t >> 3;          // 0..31
  const int lc = (t & 7) << 2;    // 0,4,..,28
  const int kr = t >> 4;          // 0..15
  const int kc = (t & 15) << 2;   // 0..60

  for (int k0 = 0; k0 < 512; k0 += 32) {
#pragma unroll
    for (int rr = 0; rr < 2; ++rr) {
      int row = rowbase + lr + rr * 32;
      float4 v = make_float4(0.f, 0.f, 0.f, 0.f);
      if (row < N) v = *(const float4*)(x + (size_t)row * 512 + k0 + lc);
      xs[lr + rr * 32][lc + 0] = v.x;
      xs[lr + rr * 32][lc + 1] = v.y;
      xs[lr + rr * 32][lc + 2] = v.z;
      xs[lr + rr * 32][lc + 3] = v.w;
    }
#pragma unroll
    for (int rr = 0; rr < 2; ++rr) {
      int k = k0 + kr + rr * 16;
      *(float4*)&ws[kr + rr * 16][kc] = *(const float4*)(W + (size_t)k * 64 + kc);
    }
    __syncthreads();
#pragma unroll
    for (int kk = 0; kk < 32; ++kk) {
      float a0 = xs[r0 + 0][kk];
      float a1 = xs[r0 + 1][kk];
      float a2 = xs[r0 + 2][kk];
      float a3 = xs[r0 + 3][kk];
      float4 b = *(float4*)&ws[kk][c0];
      acc[0][0] += a0 * b.x; acc[0][1] += a0 * b.y; acc[0][2] += a0 * b.z; acc[0][3] += a0 * b.w;
      acc[1][0] += a1 * b.x; acc[1][1] += a1 * b.y; acc[1][2] += a1 * b.z; acc[1][3] += a1 * b.w;
      acc[2][0] += a2 * b.x; acc[2][1] += a2 * b.y; acc[2][2] += a2 * b.z; acc[2][3] += a2 * b.w;
      acc[3][0] += a3 * b.x; acc[3][1] += a3 * b.y; acc[3][2] += a3 * b.z; acc[3][3] += a3 * b.w;
    }
    __syncthreads();
  }
#pragma unroll
  for (int i = 0; i < 4; ++i) {
    int row = rowbase + r0 + i;
    if (row < N) {
      float4 v = make_float4(acc[i][0], acc[i][1], acc[i][2], acc[i][3]);
      *(float4*)(h1 + (size_t)row * 64 + c0) = v;
    }
  }
}

// ---------------- K1b: per-(node,head) alphas + self-loop denom init ----------------
__global__ __launch_bounds__(256) void k_alpha1(const float* __restrict__ h1,
                                                const float* __restrict__ a1s,
                                                const float* __restrict__ a1d,
                                                float* __restrict__ as1,
                                                float* __restrict__ ad1,
                                                float* __restrict__ den1, int N) {
  int idx = blockIdx.x * blockDim.x + threadIdx.x;  // n*8 + h
  if (idx >= N * 8) return;
  int h = idx & 7;
  const float4* hp = (const float4*)(h1 + (size_t)idx * 8);
  float4 v0 = hp[0], v1 = hp[1];
  const float* s_ = a1s + h * 8;
  const float* d_ = a1d + h * 8;
  float ss = v0.x * s_[0] + v0.y * s_[1] + v0.z * s_[2] + v0.w * s_[3]
           + v1.x * s_[4] + v1.y * s_[5] + v1.z * s_[6] + v1.w * s_[7];
  float dd = v0.x * d_[0] + v0.y * d_[1] + v0.z * d_[2] + v0.w * d_[3]
           + v1.x * d_[4] + v1.y * d_[5] + v1.z * d_[6] + v1.w * d_[7];
  as1[idx] = ss;
  ad1[idx] = dd;
  den1[idx] = expf(leaky(ss + dd));  // self-loop contribution
}

// ---------------- K2: edge denom accumulation, layer 1 ----------------
__global__ __launch_bounds__(256) void k_edge_den1(const int* __restrict__ src,
                                                   const int* __restrict__ dst,
                                                   const float* __restrict__ as1,
                                                   const float* __restrict__ ad1,
                                                   float* __restrict__ den1, int E) {
  int e = blockIdx.x * blockDim.x + threadIdx.x;
  if (e >= E) return;
  int s = src[e], d = dst[e];
  const float4* ap = (const float4*)(as1 + (size_t)s * 8);
  const float4* bp = (const float4*)(ad1 + (size_t)d * 8);
  float4 a0 = ap[0], a1 = ap[1], b0 = bp[0], b1 = bp[1];
  float ex[8];
  ex[0] = expf(leaky(a0.x + b0.x));
  ex[1] = expf(leaky(a0.y + b0.y));
  ex[2] = expf(leaky(a0.z + b0.z));
  ex[3] = expf(leaky(a0.w + b0.w));
  ex[4] = expf(leaky(a1.x + b1.x));
  ex[5] = expf(leaky(a1.y + b1.y));
  ex[6] = expf(leaky(a1.z + b1.z));
  ex[7] = expf(leaky(a1.w + b1.w));
#pragma unroll
  for (int h = 0; h < 8; ++h) atomicAdd(den1 + (size_t)d * 8 + h, ex[h]);
}

// ---------------- K3: init out1 with self-loop term ----------------
__global__ __launch_bounds__(256) void k_out1_init(const float* __restrict__ h1,
                                                   const float* __restrict__ as1,
                                                   const float* __restrict__ ad1,
                                                   const float* __restrict__ den1,
                                                   float* __restrict__ out1, int N) {
  int idx = blockIdx.x * blockDim.x + threadIdx.x;  // n*64 + i
  if (idx >= N * 64) return;
  int n = idx >> 6;
  int h = (idx & 63) >> 3;
  float a = as1[n * 8 + h] + ad1[n * 8 + h];
  float attn = expf(leaky(a)) / (den1[n * 8 + h] + 1e-16f);
  out1[idx] = attn * h1[idx];
}

// ---------------- K4: edge scatter, layer 1 (wave per edge, 64 channels) ----------------
__global__ __launch_bounds__(256) void k_edge_sc1(const int* __restrict__ src,
                                                  const int* __restrict__ dst,
                                                  const float* __restrict__ as1,
                                                  const float* __restrict__ ad1,
                                                  const float* __restrict__ den1,
                                                  const float* __restrict__ h1,
                                                  float* __restrict__ out1, int E) {
  int wid = (blockIdx.x * blockDim.x + threadIdx.x) >> 6;
  int lane = threadIdx.x & 63;
  if (wid >= E) return;
  int s = src[wid], d = dst[wid];
  int h = lane >> 3;
  float a = as1[(size_t)s * 8 + h] + ad1[(size_t)d * 8 + h];
  float attn = expf(leaky(a)) / (den1[(size_t)d * 8 + h] + 1e-16f);
  atomicAdd(out1 + (size_t)d * 64 + lane, attn * h1[(size_t)s * 64 + lane]);
}

// ---------------- K5: layer-2 node kernel: elu(out1+b1) @ W2, alphas, denom init ----------------
__global__ __launch_bounds__(256) void k_layer2_node(const float* __restrict__ out1,
                                                     const float* __restrict__ b1,
                                                     const float* __restrict__ W2,
                                                     const float* __restrict__ a2s,
                                                     const float* __restrict__ a2d,
                                                     float* __restrict__ h2,
                                                     float* __restrict__ as2,
                                                     float* __restrict__ ad2,
                                                     float* __restrict__ den2, int N) {
  __shared__ float w2s[64 * 16];
  __shared__ float b1s[64];
  for (int i = threadIdx.x; i < 64 * 16; i += blockDim.x) w2s[i] = W2[i];
  if (threadIdx.x < 64) b1s[threadIdx.x] = b1[threadIdx.x];
  __syncthreads();
  int n = blockIdx.x * blockDim.x + threadIdx.x;
  if (n >= N) return;
  float v[64];
  const float4* op = (const float4*)(out1 + (size_t)n * 64);
#pragma unroll
  for (int j = 0; j < 16; ++j) {
    float4 q = op[j];
    v[j * 4 + 0] = elu1(q.x + b1s[j * 4 + 0]);
    v[j * 4 + 1] = elu1(q.y + b1s[j * 4 + 1]);
    v[j * 4 + 2] = elu1(q.z + b1s[j * 4 + 2]);
    v[j * 4 + 3] = elu1(q.w + b1s[j * 4 + 3]);
  }
  float hc[16] = {};
#pragma unroll
  for (int k = 0; k < 64; ++k) {
    float vk = v[k];
#pragma unroll
    for (int c = 0; c < 16; ++c) hc[c] += vk * w2s[k * 16 + c];
  }
  float ss = 0.f, dd = 0.f;
#pragma unroll
  for (int c = 0; c < 16; ++c) { ss += hc[c] * a2s[c]; dd += hc[c] * a2d[c]; }
  float4* hp = (float4*)(h2 + (size_t)n * 16);
  hp[0] = make_float4(hc[0], hc[1], hc[2], hc[3]);
  hp[1] = make_float4(hc[4], hc[5], hc[6], hc[7]);
  hp[2] = make_float4(hc[8], hc[9], hc[10], hc[11]);
  hp[3] = make_float4(hc[12], hc[13], hc[14], hc[15]);
  as2[n] = ss;
  ad2[n] = dd;
  den2[n] = expf(leaky(ss + dd));  // self loop
}

// ---------------- K6: edge denom, layer 2 ----------------
__global__ __launch_bounds__(256) void k_edge_den2(const int* __restrict__ src,
                                                   const int* __restrict__ dst,
                                                   const float* __restrict__ as2,
                                                   const float* __restrict__ ad2,
                                                   float* __restrict__ den2, int E) {
  int e = blockIdx.x * blockDim.x + threadIdx.x;
  if (e >= E) return;
  int s = src[e], d = dst[e];
  atomicAdd(den2 + d, expf(leaky(as2[s] + ad2[d])));
}

// ---------------- K7: init out2 with self-loop term ----------------
__global__ __launch_bounds__(256) void k_out2_init(const float* __restrict__ h2,
                                                   const float* __restrict__ as2,
                                                   const float* __restrict__ ad2,
                                                   const float* __restrict__ den2,
                                                   float* __restrict__ out2, int N) {
  int idx = blockIdx.x * blockDim.x + threadIdx.x;  // n*16 + c
  if (idx >= N * 16) return;
  int n = idx >> 4;
  float attn = expf(leaky(as2[n] + ad2[n])) / (den2[n] + 1e-16f);
  out2[idx] = attn * h2[idx];
}

// ---------------- K8: edge scatter, layer 2 (16 lanes per edge) ----------------
__global__ __launch_bounds__(256) void k_edge_sc2(const int* __restrict__ src,
                                                  const int* __restrict__ dst,
                                                  const float* __restrict__ as2,
                                                  const float* __restrict__ ad2,
                                                  const float* __restrict__ den2,
                                                  const float* __restrict__ h2,
                                                  float* __restrict__ out2, int E) {
  int tid = blockIdx.x * blockDim.x + threadIdx.x;
  int e = tid >> 4;
  int c = tid & 15;
  if (e >= E) return;
  int s = src[e], d = dst[e];
  float attn = expf(leaky(as2[s] + ad2[d])) / (den2[d] + 1e-16f);
  atomicAdd(out2 + (size_t)d * 16 + c, attn * h2[(size_t)s * 16 + c]);
}

// ---------------- K9: + b2, log_softmax ----------------
__global__ __launch_bounds__(256) void k_lsm(const float* __restrict__ out2,
                                             const float* __restrict__ b2,
                                             float* __restrict__ out, int N) {
  int n = blockIdx.x * blockDim.x + threadIdx.x;
  if (n >= N) return;
  float v[16];
  const float4* p = (const float4*)(out2 + (size_t)n * 16);
#pragma unroll
  for (int j = 0; j < 4; ++j) {
    float4 q = p[j];
    v[j * 4 + 0] = q.x + b2[j * 4 + 0];
    v[j * 4 + 1] = q.y + b2[j * 4 + 1];
    v[j * 4 + 2] = q.z + b2[j * 4 + 2];
    v[j * 4 + 3] = q.w + b2[j * 4 + 3];
  }
  float m = v[0];
#pragma unroll
  for (int c = 1; c < 16; ++c) m = fmaxf(m, v[c]);
  float sum = 0.f;
#pragma unroll
  for (int c = 0; c < 16; ++c) sum += expf(v[c] - m);
  float lse = m + logf(sum);
  float4* o = (float4*)(out + (size_t)n * 16);
#pragma unroll
  for (int j = 0; j < 4; ++j)
    o[j] = make_float4(v[j * 4 + 0] - lse, v[j * 4 + 1] - lse,
                       v[j * 4 + 2] - lse, v[j * 4 + 3] - lse);
}

extern "C" void kernel_launch(void* const* d_in, const int* in_sizes, int n_in,
                              void* d_out, int out_size, void* d_ws, size_t ws_size,
                              hipStream_t stream) {
  const float* x    = (const float*)d_in[0];
  const int*   ei   = (const int*)d_in[1];
  const float* W1   = (const float*)d_in[2];
  const float* a1s  = (const float*)d_in[3];
  const float* a1d  = (const float*)d_in[4];
  const float* b1   = (const float*)d_in[5];
  const float* W2   = (const float*)d_in[6];
  const float* a2s  = (const float*)d_in[7];
  const float* a2d  = (const float*)d_in[8];
  const float* b2   = (const float*)d_in[9];
  float* out = (float*)d_out;

  const int N = in_sizes[0] / 512;
  const int E = in_sizes[1] / 2;
  const int* src = ei;
  const int* dst = ei + E;

  float* w = (float*)d_ws;
  float* h1   = w;               w += (size_t)N * 64;
  float* out1 = w;               w += (size_t)N * 64;
  float* as1  = w;               w += (size_t)N * 8;
  float* ad1  = w;               w += (size_t)N * 8;
  float* den1 = w;               w += (size_t)N * 8;
  float* h2   = w;               w += (size_t)N * 16;
  float* as2  = w;               w += (size_t)N;
  float* ad2  = w;               w += (size_t)N;
  float* den2 = w;               w += (size_t)N;
  float* out2 = w;               w += (size_t)N * 16;

  // Layer 1
  k_gemm1<<<(N + 63) / 64, 256, 0, stream>>>(x, W1, h1, N);
  k_alpha1<<<(N * 8 + 255) / 256, 256, 0, stream>>>(h1, a1s, a1d, as1, ad1, den1, N);
  k_edge_den1<<<(E + 255) / 256, 256, 0, stream>>>(src, dst, as1, ad1, den1, E);
  k_out1_init<<<(N * 64 + 255) / 256, 256, 0, stream>>>(h1, as1, ad1, den1, out1, N);
  k_edge_sc1<<<(int)(((size_t)E * 64 + 255) / 256), 256, 0, stream>>>(src, dst, as1, ad1, den1, h1, out1, E);
  // Layer 2
  k_layer2_node<<<(N + 255) / 256, 256, 0, stream>>>(out1, b1, W2, a2s, a2d, h2, as2, ad2, den2, N);
  k_edge_den2<<<(E + 255) / 256, 256, 0, stream>>>(src, dst, as2, ad2, den2, E);
  k_out2_init<<<(N * 16 + 255) / 256, 256, 0, stream>>>(h2, as2, ad2, den2, out2, N);
  k_edge_sc2<<<(int)(((size_t)E * 16 + 255) / 256), 256, 0, stream>>>(src, dst, as2, ad2, den2, h2, out2, E);
  k_lsm<<<(N + 255) / 256, 256, 0, stream>>>(out2, b2, out, N);
}

// Round 2
// 746.566 us; speedup vs baseline: 1.7906x; 1.7906x over previous
//
#include <hip/hip_runtime.h>
#include <math.h>

#define NEG_SLOPE 0.2f

__device__ __forceinline__ float leaky(float x) { return x >= 0.f ? x : NEG_SLOPE * x; }
__device__ __forceinline__ float elu1(float x)  { return x > 0.f ? x : expm1f(x); }

// ---------------- K1: h1 = x @ W1 : [N,512] @ [512,64] -> [N,64] ----------------
__global__ __launch_bounds__(256) void k_gemm1(const float* __restrict__ x,
                                               const float* __restrict__ W,
                                               float* __restrict__ h1, int N) {
  __shared__ float xs[64][33];
  __shared__ float ws[32][64];
  const int t = threadIdx.x;
  const int rowbase = blockIdx.x * 64;
  const int r0 = (t >> 4) << 2;   // 0..60
  const int c0 = (t & 15) << 2;   // 0..60
  float acc[4][4] = {};
  const int lr = t >> 3;          // 0..31
  const int lc = (t & 7) << 2;    // 0,4,..,28
  const int kr = t >> 4;          // 0..15
  const int kc = (t & 15) << 2;   // 0..60

  for (int k0 = 0; k0 < 512; k0 += 32) {
#pragma unroll
    for (int rr = 0; rr < 2; ++rr) {
      int row = rowbase + lr + rr * 32;
      float4 v = make_float4(0.f, 0.f, 0.f, 0.f);
      if (row < N) v = *(const float4*)(x + (size_t)row * 512 + k0 + lc);
      xs[lr + rr * 32][lc + 0] = v.x;
      xs[lr + rr * 32][lc + 1] = v.y;
      xs[lr + rr * 32][lc + 2] = v.z;
      xs[lr + rr * 32][lc + 3] = v.w;
    }
#pragma unroll
    for (int rr = 0; rr < 2; ++rr) {
      int k = k0 + kr + rr * 16;
      *(float4*)&ws[kr + rr * 16][kc] = *(const float4*)(W + (size_t)k * 64 + kc);
    }
    __syncthreads();
#pragma unroll
    for (int kk = 0; kk < 32; ++kk) {
      float a0 = xs[r0 + 0][kk];
      float a1 = xs[r0 + 1][kk];
      float a2 = xs[r0 + 2][kk];
      float a3 = xs[r0 + 3][kk];
      float4 b = *(float4*)&ws[kk][c0];
      acc[0][0] += a0 * b.x; acc[0][1] += a0 * b.y; acc[0][2] += a0 * b.z; acc[0][3] += a0 * b.w;
      acc[1][0] += a1 * b.x; acc[1][1] += a1 * b.y; acc[1][2] += a1 * b.z; acc[1][3] += a1 * b.w;
      acc[2][0] += a2 * b.x; acc[2][1] += a2 * b.y; acc[2][2] += a2 * b.z; acc[2][3] += a2 * b.w;
      acc[3][0] += a3 * b.x; acc[3][1] += a3 * b.y; acc[3][2] += a3 * b.z; acc[3][3] += a3 * b.w;
    }
    __syncthreads();
  }
#pragma unroll
  for (int i = 0; i < 4; ++i) {
    int row = rowbase + r0 + i;
    if (row < N) {
      float4 v = make_float4(acc[i][0], acc[i][1], acc[i][2], acc[i][3]);
      *(float4*)(h1 + (size_t)row * 64 + c0) = v;
    }
  }
}

// ---------------- K1b: per-(node,head) alphas + self-loop denom init ----------------
__global__ __launch_bounds__(256) void k_alpha1(const float* __restrict__ h1,
                                                const float* __restrict__ a1s,
                                                const float* __restrict__ a1d,
                                                float* __restrict__ as1,
                                                float* __restrict__ ad1,
                                                float* __restrict__ den1, int N) {
  int idx = blockIdx.x * blockDim.x + threadIdx.x;  // n*8 + h
  if (idx >= N * 8) return;
  int h = idx & 7;
  const float4* hp = (const float4*)(h1 + (size_t)idx * 8);
  float4 v0 = hp[0], v1 = hp[1];
  const float* s_ = a1s + h * 8;
  const float* d_ = a1d + h * 8;
  float ss = v0.x * s_[0] + v0.y * s_[1] + v0.z * s_[2] + v0.w * s_[3]
           + v1.x * s_[4] + v1.y * s_[5] + v1.z * s_[6] + v1.w * s_[7];
  float dd = v0.x * d_[0] + v0.y * d_[1] + v0.z * d_[2] + v0.w * d_[3]
           + v1.x * d_[4] + v1.y * d_[5] + v1.z * d_[6] + v1.w * d_[7];
  as1[idx] = ss;
  ad1[idx] = dd;
  den1[idx] = expf(leaky(ss + dd));  // self-loop contribution (unnormalized)
}

// ---------------- K2: init out1un with self-loop numerator ----------------
__global__ __launch_bounds__(256) void k_out1_init(const float* __restrict__ h1,
                                                   const float* __restrict__ as1,
                                                   const float* __restrict__ ad1,
                                                   float* __restrict__ out1un, int N) {
  int idx = blockIdx.x * blockDim.x + threadIdx.x;  // n*64 + i
  if (idx >= N * 64) return;
  int n = idx >> 6;
  int h = (idx & 63) >> 3;
  float ex = expf(leaky(as1[n * 8 + h] + ad1[n * 8 + h]));
  out1un[idx] = ex * h1[idx];
}

// ---------------- K3: fused edge pass, layer 1 (wave per edge) ----------------
// lanes 0..63: numerator atomic (64 consecutive floats); lanes with (lane&7)==0
// also accumulate the denominator (8 consecutive floats, one 32B segment).
__global__ __launch_bounds__(256) void k_edge1(const int* __restrict__ src,
                                               const int* __restrict__ dst,
                                               const float* __restrict__ as1,
                                               const float* __restrict__ ad1,
                                               const float* __restrict__ h1,
                                               float* __restrict__ out1un,
                                               float* __restrict__ den1, int E) {
  int wid = (blockIdx.x * blockDim.x + threadIdx.x) >> 6;
  int lane = threadIdx.x & 63;
  if (wid >= E) return;
  int s = src[wid], d = dst[wid];
  int h = lane >> 3;
  float ex = expf(leaky(as1[(size_t)s * 8 + h] + ad1[(size_t)d * 8 + h]));
  atomicAdd(out1un + (size_t)d * 64 + lane, ex * h1[(size_t)s * 64 + lane]);
  if ((lane & 7) == 0) atomicAdd(den1 + (size_t)d * 8 + h, ex);
}

// ---------------- K4: layer-2 node kernel: normalize, elu, @W2, alphas ----------------
__global__ __launch_bounds__(256) void k_layer2_node(const float* __restrict__ out1un,
                                                     const float* __restrict__ den1,
                                                     const float* __restrict__ b1,
                                                     const float* __restrict__ W2,
                                                     const float* __restrict__ a2s,
                                                     const float* __restrict__ a2d,
                                                     float* __restrict__ h2,
                                                     float* __restrict__ as2,
                                                     float* __restrict__ ad2,
                                                     float* __restrict__ den2, int N) {
  __shared__ float w2s[64 * 16];
  __shared__ float b1s[64];
  for (int i = threadIdx.x; i < 64 * 16; i += blockDim.x) w2s[i] = W2[i];
  if (threadIdx.x < 64) b1s[threadIdx.x] = b1[threadIdx.x];
  __syncthreads();
  int n = blockIdx.x * blockDim.x + threadIdx.x;
  if (n >= N) return;
  float rden[8];
#pragma unroll
  for (int h = 0; h < 8; ++h) rden[h] = 1.f / (den1[(size_t)n * 8 + h] + 1e-16f);
  float v[64];
  const float4* op = (const float4*)(out1un + (size_t)n * 64);
#pragma unroll
  for (int j = 0; j < 16; ++j) {
    float4 q = op[j];
    float r = rden[j >> 1];
    v[j * 4 + 0] = elu1(q.x * r + b1s[j * 4 + 0]);
    v[j * 4 + 1] = elu1(q.y * r + b1s[j * 4 + 1]);
    v[j * 4 + 2] = elu1(q.z * r + b1s[j * 4 + 2]);
    v[j * 4 + 3] = elu1(q.w * r + b1s[j * 4 + 3]);
  }
  float hc[16] = {};
#pragma unroll
  for (int k = 0; k < 64; ++k) {
    float vk = v[k];
#pragma unroll
    for (int c = 0; c < 16; ++c) hc[c] += vk * w2s[k * 16 + c];
  }
  float ss = 0.f, dd = 0.f;
#pragma unroll
  for (int c = 0; c < 16; ++c) { ss += hc[c] * a2s[c]; dd += hc[c] * a2d[c]; }
  float4* hp = (float4*)(h2 + (size_t)n * 16);
  hp[0] = make_float4(hc[0], hc[1], hc[2], hc[3]);
  hp[1] = make_float4(hc[4], hc[5], hc[6], hc[7]);
  hp[2] = make_float4(hc[8], hc[9], hc[10], hc[11]);
  hp[3] = make_float4(hc[12], hc[13], hc[14], hc[15]);
  as2[n] = ss;
  ad2[n] = dd;
  den2[n] = expf(leaky(ss + dd));  // self loop (unnormalized)
}

// ---------------- K5: init out2un with self-loop numerator ----------------
__global__ __launch_bounds__(256) void k_out2_init(const float* __restrict__ h2,
                                                   const float* __restrict__ as2,
                                                   const float* __restrict__ ad2,
                                                   float* __restrict__ out2un, int N) {
  int idx = blockIdx.x * blockDim.x + threadIdx.x;  // n*16 + c
  if (idx >= N * 16) return;
  int n = idx >> 4;
  float ex = expf(leaky(as2[n] + ad2[n]));
  out2un[idx] = ex * h2[idx];
}

// ---------------- K6: fused edge pass, layer 2 (16 lanes per edge) ----------------
__global__ __launch_bounds__(256) void k_edge2(const int* __restrict__ src,
                                               const int* __restrict__ dst,
                                               const float* __restrict__ as2,
                                               const float* __restrict__ ad2,
                                               const float* __restrict__ h2,
                                               float* __restrict__ out2un,
                                               float* __restrict__ den2, int E) {
  int tid = blockIdx.x * blockDim.x + threadIdx.x;
  int e = tid >> 4;
  int c = tid & 15;
  if (e >= E) return;
  int s = src[e], d = dst[e];
  float ex = expf(leaky(as2[s] + ad2[d]));
  atomicAdd(out2un + (size_t)d * 16 + c, ex * h2[(size_t)s * 16 + c]);
  if (c == 0) atomicAdd(den2 + d, ex);
}

// ---------------- K7: normalize, + b2, log_softmax ----------------
__global__ __launch_bounds__(256) void k_lsm(const float* __restrict__ out2un,
                                             const float* __restrict__ den2,
                                             const float* __restrict__ b2,
                                             float* __restrict__ out, int N) {
  int n = blockIdx.x * blockDim.x + threadIdx.x;
  if (n >= N) return;
  float r = 1.f / (den2[n] + 1e-16f);
  float v[16];
  const float4* p = (const float4*)(out2un + (size_t)n * 16);
#pragma unroll
  for (int j = 0; j < 4; ++j) {
    float4 q = p[j];
    v[j * 4 + 0] = q.x * r + b2[j * 4 + 0];
    v[j * 4 + 1] = q.y * r + b2[j * 4 + 1];
    v[j * 4 + 2] = q.z * r + b2[j * 4 + 2];
    v[j * 4 + 3] = q.w * r + b2[j * 4 + 3];
  }
  float m = v[0];
#pragma unroll
  for (int c = 1; c < 16; ++c) m = fmaxf(m, v[c]);
  float sum = 0.f;
#pragma unroll
  for (int c = 0; c < 16; ++c) sum += expf(v[c] - m);
  float lse = m + logf(sum);
  float4* o = (float4*)(out + (size_t)n * 16);
#pragma unroll
  for (int j = 0; j < 4; ++j)
    o[j] = make_float4(v[j * 4 + 0] - lse, v[j * 4 + 1] - lse,
                       v[j * 4 + 2] - lse, v[j * 4 + 3] - lse);
}

extern "C" void kernel_launch(void* const* d_in, const int* in_sizes, int n_in,
                              void* d_out, int out_size, void* d_ws, size_t ws_size,
                              hipStream_t stream) {
  const float* x    = (const float*)d_in[0];
  const int*   ei   = (const int*)d_in[1];
  const float* W1   = (const float*)d_in[2];
  const float* a1s  = (const float*)d_in[3];
  const float* a1d  = (const float*)d_in[4];
  const float* b1   = (const float*)d_in[5];
  const float* W2   = (const float*)d_in[6];
  const float* a2s  = (const float*)d_in[7];
  const float* a2d  = (const float*)d_in[8];
  const float* b2   = (const float*)d_in[9];
  float* out = (float*)d_out;

  const int N = in_sizes[0] / 512;
  const int E = in_sizes[1] / 2;
  const int* src = ei;
  const int* dst = ei + E;

  float* w = (float*)d_ws;
  float* h1     = w;             w += (size_t)N * 64;
  float* out1un = w;             w += (size_t)N * 64;
  float* as1    = w;             w += (size_t)N * 8;
  float* ad1    = w;             w += (size_t)N * 8;
  float* den1   = w;             w += (size_t)N * 8;
  float* h2     = w;             w += (size_t)N * 16;
  float* as2    = w;             w += (size_t)N;
  float* ad2    = w;             w += (size_t)N;
  float* den2   = w;             w += (size_t)N;
  float* out2un = w;             w += (size_t)N * 16;

  // Layer 1
  k_gemm1<<<(N + 63) / 64, 256, 0, stream>>>(x, W1, h1, N);
  k_alpha1<<<(N * 8 + 255) / 256, 256, 0, stream>>>(h1, a1s, a1d, as1, ad1, den1, N);
  k_out1_init<<<(N * 64 + 255) / 256, 256, 0, stream>>>(h1, as1, ad1, out1un, N);
  k_edge1<<<(int)(((size_t)E * 64 + 255) / 256), 256, 0, stream>>>(src, dst, as1, ad1, h1, out1un, den1, E);
  // Layer 2
  k_layer2_node<<<(N + 255) / 256, 256, 0, stream>>>(out1un, den1, b1, W2, a2s, a2d, h2, as2, ad2, den2, N);
  k_out2_init<<<(N * 16 + 255) / 256, 256, 0, stream>>>(h2, as2, ad2, out2un, N);
  k_edge2<<<(int)(((size_t)E * 16 + 255) / 256), 256, 0, stream>>>(src, dst, as2, ad2, h2, out2un, den2, E);
  k_lsm<<<(N + 255) / 256, 256, 0, stream>>>(out2un, den2, b2, out, N);
}

// Round 3
// 563.648 us; speedup vs baseline: 2.3717x; 1.3245x over previous
//
#include <hip/hip_runtime.h>
#include <math.h>

#define NEG_SLOPE 0.2f

__device__ __forceinline__ float leaky(float x) { return x >= 0.f ? x : NEG_SLOPE * x; }
__device__ __forceinline__ float elu1(float x)  { return x > 0.f ? x : expm1f(x); }

// ---------------- K1: h1 = x @ W1 : [N,512] @ [512,64] -> [N,64] ----------------
__global__ __launch_bounds__(256) void k_gemm1(const float* __restrict__ x,
                                               const float* __restrict__ W,
                                               float* __restrict__ h1, int N) {
  __shared__ float xs[64][33];
  __shared__ float ws[32][64];
  const int t = threadIdx.x;
  const int rowbase = blockIdx.x * 64;
  const int r0 = (t >> 4) << 2;
  const int c0 = (t & 15) << 2;
  float acc[4][4] = {};
  const int lr = t >> 3;
  const int lc = (t & 7) << 2;
  const int kr = t >> 4;
  const int kc = (t & 15) << 2;

  for (int k0 = 0; k0 < 512; k0 += 32) {
#pragma unroll
    for (int rr = 0; rr < 2; ++rr) {
      int row = rowbase + lr + rr * 32;
      float4 v = make_float4(0.f, 0.f, 0.f, 0.f);
      if (row < N) v = *(const float4*)(x + (size_t)row * 512 + k0 + lc);
      xs[lr + rr * 32][lc + 0] = v.x;
      xs[lr + rr * 32][lc + 1] = v.y;
      xs[lr + rr * 32][lc + 2] = v.z;
      xs[lr + rr * 32][lc + 3] = v.w;
    }
#pragma unroll
    for (int rr = 0; rr < 2; ++rr) {
      int k = k0 + kr + rr * 16;
      *(float4*)&ws[kr + rr * 16][kc] = *(const float4*)(W + (size_t)k * 64 + kc);
    }
    __syncthreads();
#pragma unroll
    for (int kk = 0; kk < 32; ++kk) {
      float a0 = xs[r0 + 0][kk];
      float a1 = xs[r0 + 1][kk];
      float a2 = xs[r0 + 2][kk];
      float a3 = xs[r0 + 3][kk];
      float4 b = *(float4*)&ws[kk][c0];
      acc[0][0] += a0 * b.x; acc[0][1] += a0 * b.y; acc[0][2] += a0 * b.z; acc[0][3] += a0 * b.w;
      acc[1][0] += a1 * b.x; acc[1][1] += a1 * b.y; acc[1][2] += a1 * b.z; acc[1][3] += a1 * b.w;
      acc[2][0] += a2 * b.x; acc[2][1] += a2 * b.y; acc[2][2] += a2 * b.z; acc[2][3] += a2 * b.w;
      acc[3][0] += a3 * b.x; acc[3][1] += a3 * b.y; acc[3][2] += a3 * b.z; acc[3][3] += a3 * b.w;
    }
    __syncthreads();
  }
#pragma unroll
  for (int i = 0; i < 4; ++i) {
    int row = rowbase + r0 + i;
    if (row < N) {
      float4 v = make_float4(acc[i][0], acc[i][1], acc[i][2], acc[i][3]);
      *(float4*)(h1 + (size_t)row * 64 + c0) = v;
    }
  }
}

// ---------------- K1b: per-(node,head) alphas ----------------
__global__ __launch_bounds__(256) void k_alpha1(const float* __restrict__ h1,
                                                const float* __restrict__ a1s,
                                                const float* __restrict__ a1d,
                                                float* __restrict__ as1,
                                                float* __restrict__ ad1, int N) {
  int idx = blockIdx.x * blockDim.x + threadIdx.x;  // n*8 + h
  if (idx >= N * 8) return;
  int h = idx & 7;
  const float4* hp = (const float4*)(h1 + (size_t)idx * 8);
  float4 v0 = hp[0], v1 = hp[1];
  const float* s_ = a1s + h * 8;
  const float* d_ = a1d + h * 8;
  float ss = v0.x * s_[0] + v0.y * s_[1] + v0.z * s_[2] + v0.w * s_[3]
           + v1.x * s_[4] + v1.y * s_[5] + v1.z * s_[6] + v1.w * s_[7];
  float dd = v0.x * d_[0] + v0.y * d_[1] + v0.z * d_[2] + v0.w * d_[3]
           + v1.x * d_[4] + v1.y * d_[5] + v1.z * d_[6] + v1.w * d_[7];
  as1[idx] = ss;
  ad1[idx] = dd;
}

// ---------------- CSR build ----------------
__global__ __launch_bounds__(256) void k_zero(int* __restrict__ p, int n) {
  int i = blockIdx.x * blockDim.x + threadIdx.x;
  if (i < n) p[i] = 0;
}

__global__ __launch_bounds__(256) void k_hist(const int* __restrict__ dst,
                                              int* __restrict__ deg, int E) {
  int e = blockIdx.x * blockDim.x + threadIdx.x;
  if (e < E) atomicAdd(deg + dst[e], 1);
}

// per-block exclusive scan; block totals to bsum
__global__ __launch_bounds__(256) void k_scan1(const int* __restrict__ deg,
                                               int* __restrict__ rowptr,
                                               int* __restrict__ bsum, int N) {
  __shared__ int sm[256];
  int t = threadIdx.x;
  int i = blockIdx.x * 256 + t;
  int v = (i < N) ? deg[i] : 0;
  sm[t] = v;
  __syncthreads();
  int acc = v;
#pragma unroll
  for (int o = 1; o < 256; o <<= 1) {
    int u = (t >= o) ? sm[t - o] : 0;
    __syncthreads();
    acc += u;
    sm[t] = acc;
    __syncthreads();
  }
  if (i < N) rowptr[i] = acc - v;  // exclusive
  if (t == 255) bsum[blockIdx.x] = acc;
}

// single-block scan of block sums (NB <= 512)
__global__ __launch_bounds__(512) void k_scan2(int* __restrict__ bsum,
                                               int* __restrict__ boff, int NB) {
  __shared__ int sm[512];
  int t = threadIdx.x;
  int v = (t < NB) ? bsum[t] : 0;
  sm[t] = v;
  __syncthreads();
  int acc = v;
#pragma unroll
  for (int o = 1; o < 512; o <<= 1) {
    int u = (t >= o) ? sm[t - o] : 0;
    __syncthreads();
    acc += u;
    sm[t] = acc;
    __syncthreads();
  }
  boff[t] = acc - v;  // exclusive
}

__global__ __launch_bounds__(256) void k_scan3(int* __restrict__ rowptr,
                                               const int* __restrict__ boff,
                                               int* __restrict__ cursor, int N) {
  int i = blockIdx.x * blockDim.x + threadIdx.x;
  if (i >= N) return;
  int r = rowptr[i] + boff[i >> 8];
  rowptr[i] = r;
  cursor[i] = r;
}

__global__ __launch_bounds__(256) void k_scatter(const int* __restrict__ src,
                                                 const int* __restrict__ dst,
                                                 int* __restrict__ cursor,
                                                 int* __restrict__ srt, int E) {
  int e = blockIdx.x * blockDim.x + threadIdx.x;
  if (e >= E) return;
  int pos = atomicAdd(cursor + dst[e], 1);
  srt[pos] = src[e];
}

// ---------------- K agg1: gather-reduce layer 1, wave per dst, write normalized out1 ----------------
__global__ __launch_bounds__(256) void k_agg1(const int* __restrict__ rowptr,
                                              const int* __restrict__ deg,
                                              const int* __restrict__ srt,
                                              const float* __restrict__ as1,
                                              const float* __restrict__ ad1,
                                              const float* __restrict__ h1,
                                              float* __restrict__ out1, int N) {
  int wid = (blockIdx.x * blockDim.x + threadIdx.x) >> 6;  // dst node
  int lane = threadIdx.x & 63;
  if (wid >= N) return;
  int d = wid;
  int h = lane >> 3;
  float ad_h = ad1[(size_t)d * 8 + h];
  // self loop
  float ex0 = expf(leaky(as1[(size_t)d * 8 + h] + ad_h));
  float acc = ex0 * h1[(size_t)d * 64 + lane];
  float den = ex0;  // redundantly tracked per lane (uniform within head group)
  int start = rowptr[d];
  int len = deg[d];
  for (int k = 0; k < len; ++k) {
    int s = srt[start + k];
    float ex = expf(leaky(as1[(size_t)s * 8 + h] + ad_h));
    acc += ex * h1[(size_t)s * 64 + lane];
    den += ex;
  }
  out1[(size_t)d * 64 + lane] = acc / (den + 1e-16f);
}

// ---------------- K layer2 node: elu(out1+b1) @ W2, alphas ----------------
__global__ __launch_bounds__(256) void k_layer2_node(const float* __restrict__ out1,
                                                     const float* __restrict__ b1,
                                                     const float* __restrict__ W2,
                                                     const float* __restrict__ a2s,
                                                     const float* __restrict__ a2d,
                                                     float* __restrict__ h2,
                                                     float* __restrict__ as2,
                                                     float* __restrict__ ad2, int N) {
  __shared__ float w2s[64 * 16];
  __shared__ float b1s[64];
  for (int i = threadIdx.x; i < 64 * 16; i += blockDim.x) w2s[i] = W2[i];
  if (threadIdx.x < 64) b1s[threadIdx.x] = b1[threadIdx.x];
  __syncthreads();
  int n = blockIdx.x * blockDim.x + threadIdx.x;
  if (n >= N) return;
  float v[64];
  const float4* op = (const float4*)(out1 + (size_t)n * 64);
#pragma unroll
  for (int j = 0; j < 16; ++j) {
    float4 q = op[j];
    v[j * 4 + 0] = elu1(q.x + b1s[j * 4 + 0]);
    v[j * 4 + 1] = elu1(q.y + b1s[j * 4 + 1]);
    v[j * 4 + 2] = elu1(q.z + b1s[j * 4 + 2]);
    v[j * 4 + 3] = elu1(q.w + b1s[j * 4 + 3]);
  }
  float hc[16] = {};
#pragma unroll
  for (int k = 0; k < 64; ++k) {
    float vk = v[k];
#pragma unroll
    for (int c = 0; c < 16; ++c) hc[c] += vk * w2s[k * 16 + c];
  }
  float ss = 0.f, dd = 0.f;
#pragma unroll
  for (int c = 0; c < 16; ++c) { ss += hc[c] * a2s[c]; dd += hc[c] * a2d[c]; }
  float4* hp = (float4*)(h2 + (size_t)n * 16);
  hp[0] = make_float4(hc[0], hc[1], hc[2], hc[3]);
  hp[1] = make_float4(hc[4], hc[5], hc[6], hc[7]);
  hp[2] = make_float4(hc[8], hc[9], hc[10], hc[11]);
  hp[3] = make_float4(hc[12], hc[13], hc[14], hc[15]);
  as2[n] = ss;
  ad2[n] = dd;
}

// ---------------- K agg2: gather-reduce layer 2 + b2 + log_softmax, wave per dst ----------------
__global__ __launch_bounds__(256) void k_agg2(const int* __restrict__ rowptr,
                                              const int* __restrict__ deg,
                                              const int* __restrict__ srt,
                                              const float* __restrict__ as2,
                                              const float* __restrict__ ad2,
                                              const float* __restrict__ h2,
                                              const float* __restrict__ b2,
                                              float* __restrict__ out, int N) {
  int wid = (blockIdx.x * blockDim.x + threadIdx.x) >> 6;  // dst node
  int lane = threadIdx.x & 63;
  if (wid >= N) return;
  int d = wid;
  int c = lane & 15;
  int j = lane >> 4;  // edge subset 0..3
  float add = ad2[d];
  float acc = 0.f, den = 0.f;
  int start = rowptr[d];
  int len = deg[d];
  for (int k = j; k < len; k += 4) {
    int s = srt[start + k];
    float ex = expf(leaky(as2[s] + add));
    acc += ex * h2[(size_t)s * 16 + c];
    if (c == 0) den += ex;
  }
  // reduce across the 4 subsets
  acc += __shfl_down(acc, 32);
  acc += __shfl_down(acc, 16);
  den += __shfl_down(den, 32);
  den += __shfl_down(den, 16);
  den = __shfl(den, 0);
  if (lane < 16) {
    float ex0 = expf(leaky(as2[d] + add));
    acc += ex0 * h2[(size_t)d * 16 + c];
    den += ex0;
    float val = acc / (den + 1e-16f) + b2[c];
    float m = val;
#pragma unroll
    for (int o = 1; o < 16; o <<= 1) m = fmaxf(m, __shfl_xor(m, o));
    float s = expf(val - m);
#pragma unroll
    for (int o = 1; o < 16; o <<= 1) s += __shfl_xor(s, o);
    out[(size_t)d * 16 + c] = val - (m + logf(s));
  }
}

extern "C" void kernel_launch(void* const* d_in, const int* in_sizes, int n_in,
                              void* d_out, int out_size, void* d_ws, size_t ws_size,
                              hipStream_t stream) {
  const float* x    = (const float*)d_in[0];
  const int*   ei   = (const int*)d_in[1];
  const float* W1   = (const float*)d_in[2];
  const float* a1s  = (const float*)d_in[3];
  const float* a1d  = (const float*)d_in[4];
  const float* b1   = (const float*)d_in[5];
  const float* W2   = (const float*)d_in[6];
  const float* a2s  = (const float*)d_in[7];
  const float* a2d  = (const float*)d_in[8];
  const float* b2   = (const float*)d_in[9];
  float* out = (float*)d_out;

  const int N = in_sizes[0] / 512;
  const int E = in_sizes[1] / 2;
  const int* src = ei;
  const int* dst = ei + E;
  const int NB = (N + 255) / 256;

  float* w = (float*)d_ws;
  float* h1   = w;  w += (size_t)N * 64;
  float* out1 = w;  w += (size_t)N * 64;
  float* h2   = w;  w += (size_t)N * 16;
  float* as1  = w;  w += (size_t)N * 8;
  float* ad1  = w;  w += (size_t)N * 8;
  float* as2  = w;  w += (size_t)N;
  float* ad2  = w;  w += (size_t)N;
  int* iw = (int*)w;
  int* deg    = iw;  iw += N;
  int* rowptr = iw;  iw += N;
  int* cursor = iw;  iw += N;
  int* bsum   = iw;  iw += 512;
  int* boff   = iw;  iw += 512;
  int* srt    = iw;  iw += E;

  // CSR build (independent of h1 — scheduler can overlap with gemm1)
  k_zero<<<NB, 256, 0, stream>>>(deg, N);
  k_hist<<<(E + 255) / 256, 256, 0, stream>>>(dst, deg, E);
  k_scan1<<<NB, 256, 0, stream>>>(deg, rowptr, bsum, N);
  k_scan2<<<1, 512, 0, stream>>>(bsum, boff, NB);
  k_scan3<<<NB, 256, 0, stream>>>(rowptr, boff, cursor, N);
  k_scatter<<<(E + 255) / 256, 256, 0, stream>>>(src, dst, cursor, srt, E);

  // Layer 1
  k_gemm1<<<(N + 63) / 64, 256, 0, stream>>>(x, W1, h1, N);
  k_alpha1<<<(N * 8 + 255) / 256, 256, 0, stream>>>(h1, a1s, a1d, as1, ad1, N);
  k_agg1<<<(int)(((size_t)N * 64 + 255) / 256), 256, 0, stream>>>(rowptr, deg, srt, as1, ad1, h1, out1, N);

  // Layer 2
  k_layer2_node<<<(N + 255) / 256, 256, 0, stream>>>(out1, b1, W2, a2s, a2d, h2, as2, ad2, N);
  k_agg2<<<(int)(((size_t)N * 64 + 255) / 256), 256, 0, stream>>>(rowptr, deg, srt, as2, ad2, h2, b2, out, N);
}

// Round 4
// 503.663 us; speedup vs baseline: 2.6542x; 1.1191x over previous
//
#include <hip/hip_runtime.h>
#include <math.h>

#define NEG_SLOPE 0.2f

__device__ __forceinline__ float leaky(float x) { return x >= 0.f ? x : NEG_SLOPE * x; }
__device__ __forceinline__ float elu1(float x)  { return x > 0.f ? x : expm1f(x); }

__device__ __forceinline__ unsigned short f2bf(float f) {
  unsigned u = __float_as_uint(f);
  unsigned r = (u + 0x7FFFu + ((u >> 16) & 1u)) >> 16;
  return (unsigned short)r;
}
__device__ __forceinline__ float bf2f(unsigned short s) {
  return __uint_as_float((unsigned)s << 16);
}

// ---------------- K1: h1b = bf16(x @ W1) : [N,512] @ [512,64] -> [N,64] ----------------
__global__ __launch_bounds__(256) void k_gemm1(const float* __restrict__ x,
                                               const float* __restrict__ W,
                                               unsigned short* __restrict__ h1b, int N) {
  __shared__ float xs[64][33];
  __shared__ float ws[32][64];
  const int t = threadIdx.x;
  const int rowbase = blockIdx.x * 64;
  const int r0 = (t >> 4) << 2;
  const int c0 = (t & 15) << 2;
  float acc[4][4] = {};
  const int lr = t >> 3;
  const int lc = (t & 7) << 2;
  const int kr = t >> 4;
  const int kc = (t & 15) << 2;

  for (int k0 = 0; k0 < 512; k0 += 32) {
#pragma unroll
    for (int rr = 0; rr < 2; ++rr) {
      int row = rowbase + lr + rr * 32;
      float4 v = make_float4(0.f, 0.f, 0.f, 0.f);
      if (row < N) v = *(const float4*)(x + (size_t)row * 512 + k0 + lc);
      xs[lr + rr * 32][lc + 0] = v.x;
      xs[lr + rr * 32][lc + 1] = v.y;
      xs[lr + rr * 32][lc + 2] = v.z;
      xs[lr + rr * 32][lc + 3] = v.w;
    }
#pragma unroll
    for (int rr = 0; rr < 2; ++rr) {
      int k = k0 + kr + rr * 16;
      *(float4*)&ws[kr + rr * 16][kc] = *(const float4*)(W + (size_t)k * 64 + kc);
    }
    __syncthreads();
#pragma unroll
    for (int kk = 0; kk < 32; ++kk) {
      float a0 = xs[r0 + 0][kk];
      float a1 = xs[r0 + 1][kk];
      float a2 = xs[r0 + 2][kk];
      float a3 = xs[r0 + 3][kk];
      float4 b = *(float4*)&ws[kk][c0];
      acc[0][0] += a0 * b.x; acc[0][1] += a0 * b.y; acc[0][2] += a0 * b.z; acc[0][3] += a0 * b.w;
      acc[1][0] += a1 * b.x; acc[1][1] += a1 * b.y; acc[1][2] += a1 * b.z; acc[1][3] += a1 * b.w;
      acc[2][0] += a2 * b.x; acc[2][1] += a2 * b.y; acc[2][2] += a2 * b.z; acc[2][3] += a2 * b.w;
      acc[3][0] += a3 * b.x; acc[3][1] += a3 * b.y; acc[3][2] += a3 * b.z; acc[3][3] += a3 * b.w;
    }
    __syncthreads();
  }
#pragma unroll
  for (int i = 0; i < 4; ++i) {
    int row = rowbase + r0 + i;
    if (row < N) {
      ushort4 v;
      v.x = f2bf(acc[i][0]); v.y = f2bf(acc[i][1]);
      v.z = f2bf(acc[i][2]); v.w = f2bf(acc[i][3]);
      *(ushort4*)(h1b + (size_t)row * 64 + c0) = v;
    }
  }
}

// ---------------- K1b: per-(node,head) factored-exp alpha tables ----------------
// ef1s[n*16+h*2+{0,1}] = {exp(as), exp(0.2*as)};  ef1d likewise for ad.
__global__ __launch_bounds__(256) void k_alpha1(const unsigned short* __restrict__ h1b,
                                                const float* __restrict__ a1s,
                                                const float* __restrict__ a1d,
                                                float* __restrict__ ef1s,
                                                float* __restrict__ ef1d, int N) {
  int idx = blockIdx.x * blockDim.x + threadIdx.x;  // n*8 + h
  if (idx >= N * 8) return;
  int h = idx & 7;
  uint4 raw = *(const uint4*)(h1b + (size_t)idx * 8);
  float v[8];
  v[0] = bf2f((unsigned short)(raw.x & 0xFFFF)); v[1] = bf2f((unsigned short)(raw.x >> 16));
  v[2] = bf2f((unsigned short)(raw.y & 0xFFFF)); v[3] = bf2f((unsigned short)(raw.y >> 16));
  v[4] = bf2f((unsigned short)(raw.z & 0xFFFF)); v[5] = bf2f((unsigned short)(raw.z >> 16));
  v[6] = bf2f((unsigned short)(raw.w & 0xFFFF)); v[7] = bf2f((unsigned short)(raw.w >> 16));
  const float* s_ = a1s + h * 8;
  const float* d_ = a1d + h * 8;
  float ss = 0.f, dd = 0.f;
#pragma unroll
  for (int j = 0; j < 8; ++j) { ss += v[j] * s_[j]; dd += v[j] * d_[j]; }
  *(float2*)(ef1s + (size_t)idx * 2) = make_float2(expf(ss), expf(NEG_SLOPE * ss));
  *(float2*)(ef1d + (size_t)idx * 2) = make_float2(expf(dd), expf(NEG_SLOPE * dd));
}

// ---------------- CSR build ----------------
__global__ __launch_bounds__(256) void k_zero(int* __restrict__ p, int n) {
  int i = blockIdx.x * blockDim.x + threadIdx.x;
  if (i < n) p[i] = 0;
}

__global__ __launch_bounds__(256) void k_hist(const int* __restrict__ dst,
                                              int* __restrict__ deg, int E) {
  int e = blockIdx.x * blockDim.x + threadIdx.x;
  if (e < E) atomicAdd(deg + dst[e], 1);
}

__global__ __launch_bounds__(256) void k_scan1(const int* __restrict__ deg,
                                               int* __restrict__ rowptr,
                                               int* __restrict__ bsum, int N) {
  __shared__ int sm[256];
  int t = threadIdx.x;
  int i = blockIdx.x * 256 + t;
  int v = (i < N) ? deg[i] : 0;
  sm[t] = v;
  __syncthreads();
  int acc = v;
#pragma unroll
  for (int o = 1; o < 256; o <<= 1) {
    int u = (t >= o) ? sm[t - o] : 0;
    __syncthreads();
    acc += u;
    sm[t] = acc;
    __syncthreads();
  }
  if (i < N) rowptr[i] = acc - v;
  if (t == 255) bsum[blockIdx.x] = acc;
}

__global__ __launch_bounds__(512) void k_scan2(int* __restrict__ bsum,
                                               int* __restrict__ boff, int NB) {
  __shared__ int sm[512];
  int t = threadIdx.x;
  int v = (t < NB) ? bsum[t] : 0;
  sm[t] = v;
  __syncthreads();
  int acc = v;
#pragma unroll
  for (int o = 1; o < 512; o <<= 1) {
    int u = (t >= o) ? sm[t - o] : 0;
    __syncthreads();
    acc += u;
    sm[t] = acc;
    __syncthreads();
  }
  boff[t] = acc - v;
}

__global__ __launch_bounds__(256) void k_scan3(int* __restrict__ rowptr,
                                               const int* __restrict__ boff,
                                               int* __restrict__ cursor, int N) {
  int i = blockIdx.x * blockDim.x + threadIdx.x;
  if (i >= N) return;
  int r = rowptr[i] + boff[i >> 8];
  rowptr[i] = r;
  cursor[i] = r;
}

__global__ __launch_bounds__(256) void k_scatter(const int* __restrict__ src,
                                                 const int* __restrict__ dst,
                                                 int* __restrict__ cursor,
                                                 int* __restrict__ srt, int E) {
  int e = blockIdx.x * blockDim.x + threadIdx.x;
  if (e >= E) return;
  int pos = atomicAdd(cursor + dst[e], 1);
  srt[pos] = src[e];
}

// ---------------- K agg1: gather-reduce layer 1, wave per dst ----------------
__global__ __launch_bounds__(256) void k_agg1(const int* __restrict__ rowptr,
                                              const int* __restrict__ deg,
                                              const int* __restrict__ srt,
                                              const float* __restrict__ ef1s,
                                              const float* __restrict__ ef1d,
                                              const unsigned short* __restrict__ h1b,
                                              float* __restrict__ out1, int N) {
  int wid = (blockIdx.x * blockDim.x + threadIdx.x) >> 6;  // dst node
  int lane = threadIdx.x & 63;
  if (wid >= N) return;
  int d = wid;
  int h = lane >> 3;
  float2 dd = *(const float2*)(ef1d + (size_t)d * 16 + h * 2);  // {ead, fad}
  // self loop
  float2 ps = *(const float2*)(ef1s + (size_t)d * 16 + h * 2);
  float t0 = ps.x * dd.x, u0 = ps.y * dd.y;
  float ex0 = (t0 >= 1.f) ? t0 : u0;
  float acc = ex0 * bf2f(h1b[(size_t)d * 64 + lane]);
  float den = ex0;
  int start = rowptr[d];
  int len = deg[d];
  int k = 0;
  for (; k + 2 <= len; k += 2) {
    int s0 = srt[start + k];
    int s1 = srt[start + k + 1];
    float2 p0 = *(const float2*)(ef1s + (size_t)s0 * 16 + h * 2);
    float2 p1 = *(const float2*)(ef1s + (size_t)s1 * 16 + h * 2);
    float v0 = bf2f(h1b[(size_t)s0 * 64 + lane]);
    float v1 = bf2f(h1b[(size_t)s1 * 64 + lane]);
    float ta = p0.x * dd.x, ua = p0.y * dd.y;
    float tb = p1.x * dd.x, ub = p1.y * dd.y;
    float exa = (ta >= 1.f) ? ta : ua;
    float exb = (tb >= 1.f) ? tb : ub;
    acc += exa * v0 + exb * v1;
    den += exa + exb;
  }
  if (k < len) {
    int s0 = srt[start + k];
    float2 p0 = *(const float2*)(ef1s + (size_t)s0 * 16 + h * 2);
    float v0 = bf2f(h1b[(size_t)s0 * 64 + lane]);
    float ta = p0.x * dd.x, ua = p0.y * dd.y;
    float exa = (ta >= 1.f) ? ta : ua;
    acc += exa * v0;
    den += exa;
  }
  out1[(size_t)d * 64 + lane] = acc / (den + 1e-16f);
}

// ---------------- K layer2 node: elu(out1+b1) @ W2, factored-exp alpha tables, h2 bf16 ----------------
__global__ __launch_bounds__(256) void k_layer2_node(const float* __restrict__ out1,
                                                     const float* __restrict__ b1,
                                                     const float* __restrict__ W2,
                                                     const float* __restrict__ a2s,
                                                     const float* __restrict__ a2d,
                                                     unsigned short* __restrict__ h2b,
                                                     float* __restrict__ ef2s,
                                                     float* __restrict__ ef2d, int N) {
  __shared__ float w2s[64 * 16];
  __shared__ float b1s[64];
  for (int i = threadIdx.x; i < 64 * 16; i += blockDim.x) w2s[i] = W2[i];
  if (threadIdx.x < 64) b1s[threadIdx.x] = b1[threadIdx.x];
  __syncthreads();
  int n = blockIdx.x * blockDim.x + threadIdx.x;
  if (n >= N) return;
  float v[64];
  const float4* op = (const float4*)(out1 + (size_t)n * 64);
#pragma unroll
  for (int j = 0; j < 16; ++j) {
    float4 q = op[j];
    v[j * 4 + 0] = elu1(q.x + b1s[j * 4 + 0]);
    v[j * 4 + 1] = elu1(q.y + b1s[j * 4 + 1]);
    v[j * 4 + 2] = elu1(q.z + b1s[j * 4 + 2]);
    v[j * 4 + 3] = elu1(q.w + b1s[j * 4 + 3]);
  }
  float hc[16] = {};
#pragma unroll
  for (int k = 0; k < 64; ++k) {
    float vk = v[k];
#pragma unroll
    for (int c = 0; c < 16; ++c) hc[c] += vk * w2s[k * 16 + c];
  }
  float ss = 0.f, dd = 0.f;
#pragma unroll
  for (int c = 0; c < 16; ++c) { ss += hc[c] * a2s[c]; dd += hc[c] * a2d[c]; }
#pragma unroll
  for (int j = 0; j < 4; ++j) {
    ushort4 p;
    p.x = f2bf(hc[j * 4 + 0]); p.y = f2bf(hc[j * 4 + 1]);
    p.z = f2bf(hc[j * 4 + 2]); p.w = f2bf(hc[j * 4 + 3]);
    *(ushort4*)(h2b + (size_t)n * 16 + j * 4) = p;
  }
  *(float2*)(ef2s + (size_t)n * 2) = make_float2(expf(ss), expf(NEG_SLOPE * ss));
  *(float2*)(ef2d + (size_t)n * 2) = make_float2(expf(dd), expf(NEG_SLOPE * dd));
}

// ---------------- K agg2: gather-reduce layer 2 + b2 + log_softmax, wave per dst ----------------
__global__ __launch_bounds__(256) void k_agg2(const int* __restrict__ rowptr,
                                              const int* __restrict__ deg,
                                              const int* __restrict__ srt,
                                              const float* __restrict__ ef2s,
                                              const float* __restrict__ ef2d,
                                              const unsigned short* __restrict__ h2b,
                                              const float* __restrict__ b2,
                                              float* __restrict__ out, int N) {
  int wid = (blockIdx.x * blockDim.x + threadIdx.x) >> 6;  // dst node
  int lane = threadIdx.x & 63;
  if (wid >= N) return;
  int d = wid;
  int c = lane & 15;
  int j = lane >> 4;  // edge subset 0..3
  float2 ddp = *(const float2*)(ef2d + (size_t)d * 2);  // {ead, fad}
  float acc = 0.f, den = 0.f;
  int start = rowptr[d];
  int len = deg[d];
  for (int k = j; k < len; k += 4) {
    int s = srt[start + k];
    float2 p = *(const float2*)(ef2s + (size_t)s * 2);
    float t = p.x * ddp.x, u = p.y * ddp.y;
    float ex = (t >= 1.f) ? t : u;
    acc += ex * bf2f(h2b[(size_t)s * 16 + c]);
    if (c == 0) den += ex;
  }
  acc += __shfl_down(acc, 32);
  acc += __shfl_down(acc, 16);
  den += __shfl_down(den, 32);
  den += __shfl_down(den, 16);
  den = __shfl(den, 0);
  if (lane < 16) {
    float2 ps = *(const float2*)(ef2s + (size_t)d * 2);
    float t = ps.x * ddp.x, u = ps.y * ddp.y;
    float ex0 = (t >= 1.f) ? t : u;
    acc += ex0 * bf2f(h2b[(size_t)d * 16 + c]);
    den += ex0;
    float val = acc / (den + 1e-16f) + b2[c];
    float m = val;
#pragma unroll
    for (int o = 1; o < 16; o <<= 1) m = fmaxf(m, __shfl_xor(m, o));
    float s = expf(val - m);
#pragma unroll
    for (int o = 1; o < 16; o <<= 1) s += __shfl_xor(s, o);
    out[(size_t)d * 16 + c] = val - (m + logf(s));
  }
}

extern "C" void kernel_launch(void* const* d_in, const int* in_sizes, int n_in,
                              void* d_out, int out_size, void* d_ws, size_t ws_size,
                              hipStream_t stream) {
  const float* x    = (const float*)d_in[0];
  const int*   ei   = (const int*)d_in[1];
  const float* W1   = (const float*)d_in[2];
  const float* a1s  = (const float*)d_in[3];
  const float* a1d  = (const float*)d_in[4];
  const float* b1   = (const float*)d_in[5];
  const float* W2   = (const float*)d_in[6];
  const float* a2s  = (const float*)d_in[7];
  const float* a2d  = (const float*)d_in[8];
  const float* b2   = (const float*)d_in[9];
  float* out = (float*)d_out;

  const int N = in_sizes[0] / 512;
  const int E = in_sizes[1] / 2;
  const int* src = ei;
  const int* dst = ei + E;
  const int NB = (N + 255) / 256;

  float* w = (float*)d_ws;
  float* out1 = w;  w += (size_t)N * 64;
  float* ef1s = w;  w += (size_t)N * 16;
  float* ef1d = w;  w += (size_t)N * 16;
  float* ef2s = w;  w += (size_t)N * 2;
  float* ef2d = w;  w += (size_t)N * 2;
  unsigned short* h1b = (unsigned short*)w;  w += (size_t)N * 32;  // N*64 bf16
  unsigned short* h2b = (unsigned short*)w;  w += (size_t)N * 8;   // N*16 bf16
  int* iw = (int*)w;
  int* deg    = iw;  iw += N;
  int* rowptr = iw;  iw += N;
  int* cursor = iw;  iw += N;
  int* bsum   = iw;  iw += 512;
  int* boff   = iw;  iw += 512;
  int* srt    = iw;  iw += E;

  // CSR build (independent of h1 — overlaps gemm1 in-order on stream is fine)
  k_zero<<<NB, 256, 0, stream>>>(deg, N);
  k_hist<<<(E + 255) / 256, 256, 0, stream>>>(dst, deg, E);
  k_scan1<<<NB, 256, 0, stream>>>(deg, rowptr, bsum, N);
  k_scan2<<<1, 512, 0, stream>>>(bsum, boff, NB);
  k_scan3<<<NB, 256, 0, stream>>>(rowptr, boff, cursor, N);
  k_scatter<<<(E + 255) / 256, 256, 0, stream>>>(src, dst, cursor, srt, E);

  // Layer 1
  k_gemm1<<<(N + 63) / 64, 256, 0, stream>>>(x, W1, h1b, N);
  k_alpha1<<<(N * 8 + 255) / 256, 256, 0, stream>>>(h1b, a1s, a1d, ef1s, ef1d, N);
  k_agg1<<<(int)(((size_t)N * 64 + 255) / 256), 256, 0, stream>>>(rowptr, deg, srt, ef1s, ef1d, h1b, out1, N);

  // Layer 2
  k_layer2_node<<<(N + 255) / 256, 256, 0, stream>>>(out1, b1, W2, a2s, a2d, h2b, ef2s, ef2d, N);
  k_agg2<<<(int)(((size_t)N * 64 + 255) / 256), 256, 0, stream>>>(rowptr, deg, srt, ef2s, ef2d, h2b, b2, out, N);
}

// Round 5
// 378.168 us; speedup vs baseline: 3.5350x; 1.3318x over previous
//
#include <hip/hip_runtime.h>
#include <math.h>

#define NEG_SLOPE 0.2f
#define BKT_SHIFT 8                 // 256 dst nodes per bucket
#define BKT_RANGE 256
#define EPB 4096                    // edges per block in binning kernels

__device__ __forceinline__ float leaky(float x) { return x >= 0.f ? x : NEG_SLOPE * x; }
__device__ __forceinline__ float elu1(float x)  { return x > 0.f ? x : expm1f(x); }

__device__ __forceinline__ unsigned short f2bf(float f) {
  unsigned u = __float_as_uint(f);
  unsigned r = (u + 0x7FFFu + ((u >> 16) & 1u)) >> 16;
  return (unsigned short)r;
}
__device__ __forceinline__ float bf2f(unsigned short s) {
  return __uint_as_float((unsigned)s << 16);
}

// ---------------- K1: h1b = bf16(x @ W1) : [N,512] @ [512,64] -> [N,64] ----------------
__global__ __launch_bounds__(256) void k_gemm1(const float* __restrict__ x,
                                               const float* __restrict__ W,
                                               unsigned short* __restrict__ h1b, int N) {
  __shared__ float xs[64][33];
  __shared__ float ws[32][64];
  const int t = threadIdx.x;
  const int rowbase = blockIdx.x * 64;
  const int r0 = (t >> 4) << 2;
  const int c0 = (t & 15) << 2;
  float acc[4][4] = {};
  const int lr = t >> 3;
  const int lc = (t & 7) << 2;
  const int kr = t >> 4;
  const int kc = (t & 15) << 2;

  for (int k0 = 0; k0 < 512; k0 += 32) {
#pragma unroll
    for (int rr = 0; rr < 2; ++rr) {
      int row = rowbase + lr + rr * 32;
      float4 v = make_float4(0.f, 0.f, 0.f, 0.f);
      if (row < N) v = *(const float4*)(x + (size_t)row * 512 + k0 + lc);
      xs[lr + rr * 32][lc + 0] = v.x;
      xs[lr + rr * 32][lc + 1] = v.y;
      xs[lr + rr * 32][lc + 2] = v.z;
      xs[lr + rr * 32][lc + 3] = v.w;
    }
#pragma unroll
    for (int rr = 0; rr < 2; ++rr) {
      int k = k0 + kr + rr * 16;
      *(float4*)&ws[kr + rr * 16][kc] = *(const float4*)(W + (size_t)k * 64 + kc);
    }
    __syncthreads();
#pragma unroll
    for (int kk = 0; kk < 32; ++kk) {
      float a0 = xs[r0 + 0][kk];
      float a1 = xs[r0 + 1][kk];
      float a2 = xs[r0 + 2][kk];
      float a3 = xs[r0 + 3][kk];
      float4 b = *(float4*)&ws[kk][c0];
      acc[0][0] += a0 * b.x; acc[0][1] += a0 * b.y; acc[0][2] += a0 * b.z; acc[0][3] += a0 * b.w;
      acc[1][0] += a1 * b.x; acc[1][1] += a1 * b.y; acc[1][2] += a1 * b.z; acc[1][3] += a1 * b.w;
      acc[2][0] += a2 * b.x; acc[2][1] += a2 * b.y; acc[2][2] += a2 * b.z; acc[2][3] += a2 * b.w;
      acc[3][0] += a3 * b.x; acc[3][1] += a3 * b.y; acc[3][2] += a3 * b.z; acc[3][3] += a3 * b.w;
    }
    __syncthreads();
  }
#pragma unroll
  for (int i = 0; i < 4; ++i) {
    int row = rowbase + r0 + i;
    if (row < N) {
      ushort4 v;
      v.x = f2bf(acc[i][0]); v.y = f2bf(acc[i][1]);
      v.z = f2bf(acc[i][2]); v.w = f2bf(acc[i][3]);
      *(ushort4*)(h1b + (size_t)row * 64 + c0) = v;
    }
  }
}

// ---------------- K1b: per-(node,head) factored-exp alpha tables ----------------
__global__ __launch_bounds__(256) void k_alpha1(const unsigned short* __restrict__ h1b,
                                                const float* __restrict__ a1s,
                                                const float* __restrict__ a1d,
                                                float* __restrict__ ef1s,
                                                float* __restrict__ ef1d, int N) {
  int idx = blockIdx.x * blockDim.x + threadIdx.x;  // n*8 + h
  if (idx >= N * 8) return;
  int h = idx & 7;
  uint4 raw = *(const uint4*)(h1b + (size_t)idx * 8);
  float v[8];
  v[0] = bf2f((unsigned short)(raw.x & 0xFFFF)); v[1] = bf2f((unsigned short)(raw.x >> 16));
  v[2] = bf2f((unsigned short)(raw.y & 0xFFFF)); v[3] = bf2f((unsigned short)(raw.y >> 16));
  v[4] = bf2f((unsigned short)(raw.z & 0xFFFF)); v[5] = bf2f((unsigned short)(raw.z >> 16));
  v[6] = bf2f((unsigned short)(raw.w & 0xFFFF)); v[7] = bf2f((unsigned short)(raw.w >> 16));
  const float* s_ = a1s + h * 8;
  const float* d_ = a1d + h * 8;
  float ss = 0.f, dd = 0.f;
#pragma unroll
  for (int j = 0; j < 8; ++j) { ss += v[j] * s_[j]; dd += v[j] * d_[j]; }
  *(float2*)(ef1s + (size_t)idx * 2) = make_float2(expf(ss), expf(NEG_SLOPE * ss));
  *(float2*)(ef1d + (size_t)idx * 2) = make_float2(expf(dd), expf(NEG_SLOPE * dd));
}

// ---------------- CSR build: two-level bucketed counting sort ----------------
__global__ __launch_bounds__(512) void k_zero(int* __restrict__ p, int n) {
  int i = blockIdx.x * blockDim.x + threadIdx.x;
  if (i < n) p[i] = 0;
}

// bucket histogram with LDS staging
__global__ __launch_bounds__(256) void k_bhist(const int* __restrict__ dst,
                                               int* __restrict__ bucketCount,
                                               int E, int B) {
  __shared__ int h[512];
  int t = threadIdx.x;
  for (int i = t; i < B; i += 256) h[i] = 0;
  __syncthreads();
  int e0 = blockIdx.x * EPB;
#pragma unroll
  for (int i = 0; i < EPB / 256; ++i) {
    int e = e0 + i * 256 + t;
    if (e < E) atomicAdd(&h[dst[e] >> BKT_SHIFT], 1);
  }
  __syncthreads();
  for (int i = t; i < B; i += 256)
    if (h[i]) atomicAdd(bucketCount + i, h[i]);
}

// single-block exclusive scan of bucketCount -> bucketOff (B+1), init gCursor
__global__ __launch_bounds__(512) void k_bscan(const int* __restrict__ bucketCount,
                                               int* __restrict__ bucketOff,
                                               int* __restrict__ gCursor, int B, int E) {
  __shared__ int sm[512];
  int t = threadIdx.x;
  int v = (t < B) ? bucketCount[t] : 0;
  sm[t] = v;
  __syncthreads();
  int acc = v;
#pragma unroll
  for (int o = 1; o < 512; o <<= 1) {
    int u = (t >= o) ? sm[t - o] : 0;
    __syncthreads();
    acc += u;
    sm[t] = acc;
    __syncthreads();
  }
  if (t < B) {
    bucketOff[t] = acc - v;
    gCursor[t] = acc - v;
  }
  if (t == 0) bucketOff[B] = E;
}

// radix partition: write (src,dst) pairs grouped by bucket, per-(block,bucket) runs
__global__ __launch_bounds__(256) void k_bin(const int* __restrict__ src,
                                             const int* __restrict__ dst,
                                             int* __restrict__ gCursor,
                                             int2* __restrict__ binned,
                                             int E, int B) {
  __shared__ int hist[512];
  __shared__ int base[512];
  int t = threadIdx.x;
  for (int i = t; i < B; i += 256) hist[i] = 0;
  __syncthreads();
  int e0 = blockIdx.x * EPB;
#pragma unroll
  for (int i = 0; i < EPB / 256; ++i) {
    int e = e0 + i * 256 + t;
    if (e < E) atomicAdd(&hist[dst[e] >> BKT_SHIFT], 1);
  }
  __syncthreads();
  for (int i = t; i < B; i += 256) {
    int c = hist[i];
    base[i] = c ? atomicAdd(gCursor + i, c) : 0;
    hist[i] = 0;
  }
  __syncthreads();
#pragma unroll
  for (int i = 0; i < EPB / 256; ++i) {
    int e = e0 + i * 256 + t;
    if (e < E) {
      int d = dst[e];
      int b = d >> BKT_SHIFT;
      int r = atomicAdd(&hist[b], 1);
      binned[base[b] + r] = make_int2(src[e], d);
    }
  }
}

// per-bucket counting sort: deg/rowptr + srt window (L2-resident)
__global__ __launch_bounds__(256) void k_build(const int* __restrict__ bucketOff,
                                               const int2* __restrict__ binned,
                                               int* __restrict__ rowptr,
                                               int* __restrict__ deg,
                                               int* __restrict__ srt, int N) {
  __shared__ int ldeg[BKT_RANGE];
  __shared__ int sm[BKT_RANGE];
  __shared__ int lcur[BKT_RANGE];
  int t = threadIdx.x;
  int b = blockIdx.x;
  int nbase = b * BKT_RANGE;
  int estart = bucketOff[b];
  int eend = bucketOff[b + 1];
  ldeg[t] = 0;
  __syncthreads();
  for (int e = estart + t; e < eend; e += 256)
    atomicAdd(&ldeg[binned[e].y - nbase], 1);
  __syncthreads();
  // exclusive scan of ldeg
  int v = ldeg[t];
  sm[t] = v;
  __syncthreads();
  int acc = v;
#pragma unroll
  for (int o = 1; o < 256; o <<= 1) {
    int u = (t >= o) ? sm[t - o] : 0;
    __syncthreads();
    acc += u;
    sm[t] = acc;
    __syncthreads();
  }
  int excl = estart + acc - v;
  int node = nbase + t;
  if (node < N) {
    rowptr[node] = excl;
    deg[node] = v;
  }
  lcur[t] = excl;
  __syncthreads();
  for (int e = estart + t; e < eend; e += 256) {
    int2 p = binned[e];
    int pos = atomicAdd(&lcur[p.y - nbase], 1);
    srt[pos] = p.x;
  }
}

// ---------------- K agg1: gather-reduce layer 1, wave per dst ----------------
__global__ __launch_bounds__(256) void k_agg1(const int* __restrict__ rowptr,
                                              const int* __restrict__ deg,
                                              const int* __restrict__ srt,
                                              const float* __restrict__ ef1s,
                                              const float* __restrict__ ef1d,
                                              const unsigned short* __restrict__ h1b,
                                              float* __restrict__ out1, int N) {
  int wid = (blockIdx.x * blockDim.x + threadIdx.x) >> 6;  // dst node
  int lane = threadIdx.x & 63;
  if (wid >= N) return;
  int d = wid;
  int h = lane >> 3;
  float2 dd = *(const float2*)(ef1d + (size_t)d * 16 + h * 2);  // {ead, fad}
  float2 ps = *(const float2*)(ef1s + (size_t)d * 16 + h * 2);
  float t0 = ps.x * dd.x, u0 = ps.y * dd.y;
  float ex0 = (t0 >= 1.f) ? t0 : u0;
  float acc = ex0 * bf2f(h1b[(size_t)d * 64 + lane]);
  float den = ex0;
  int start = rowptr[d];
  int len = deg[d];
  int k = 0;
  for (; k + 2 <= len; k += 2) {
    int s0 = srt[start + k];
    int s1 = srt[start + k + 1];
    float2 p0 = *(const float2*)(ef1s + (size_t)s0 * 16 + h * 2);
    float2 p1 = *(const float2*)(ef1s + (size_t)s1 * 16 + h * 2);
    float v0 = bf2f(h1b[(size_t)s0 * 64 + lane]);
    float v1 = bf2f(h1b[(size_t)s1 * 64 + lane]);
    float ta = p0.x * dd.x, ua = p0.y * dd.y;
    float tb = p1.x * dd.x, ub = p1.y * dd.y;
    float exa = (ta >= 1.f) ? ta : ua;
    float exb = (tb >= 1.f) ? tb : ub;
    acc += exa * v0 + exb * v1;
    den += exa + exb;
  }
  if (k < len) {
    int s0 = srt[start + k];
    float2 p0 = *(const float2*)(ef1s + (size_t)s0 * 16 + h * 2);
    float v0 = bf2f(h1b[(size_t)s0 * 64 + lane]);
    float ta = p0.x * dd.x, ua = p0.y * dd.y;
    float exa = (ta >= 1.f) ? ta : ua;
    acc += exa * v0;
    den += exa;
  }
  out1[(size_t)d * 64 + lane] = acc / (den + 1e-16f);
}

// ---------------- K layer2 node ----------------
__global__ __launch_bounds__(256) void k_layer2_node(const float* __restrict__ out1,
                                                     const float* __restrict__ b1,
                                                     const float* __restrict__ W2,
                                                     const float* __restrict__ a2s,
                                                     const float* __restrict__ a2d,
                                                     unsigned short* __restrict__ h2b,
                                                     float* __restrict__ ef2s,
                                                     float* __restrict__ ef2d, int N) {
  __shared__ float w2s[64 * 16];
  __shared__ float b1s[64];
  for (int i = threadIdx.x; i < 64 * 16; i += blockDim.x) w2s[i] = W2[i];
  if (threadIdx.x < 64) b1s[threadIdx.x] = b1[threadIdx.x];
  __syncthreads();
  int n = blockIdx.x * blockDim.x + threadIdx.x;
  if (n >= N) return;
  float v[64];
  const float4* op = (const float4*)(out1 + (size_t)n * 64);
#pragma unroll
  for (int j = 0; j < 16; ++j) {
    float4 q = op[j];
    v[j * 4 + 0] = elu1(q.x + b1s[j * 4 + 0]);
    v[j * 4 + 1] = elu1(q.y + b1s[j * 4 + 1]);
    v[j * 4 + 2] = elu1(q.z + b1s[j * 4 + 2]);
    v[j * 4 + 3] = elu1(q.w + b1s[j * 4 + 3]);
  }
  float hc[16] = {};
#pragma unroll
  for (int k = 0; k < 64; ++k) {
    float vk = v[k];
#pragma unroll
    for (int c = 0; c < 16; ++c) hc[c] += vk * w2s[k * 16 + c];
  }
  float ss = 0.f, dd = 0.f;
#pragma unroll
  for (int c = 0; c < 16; ++c) { ss += hc[c] * a2s[c]; dd += hc[c] * a2d[c]; }
#pragma unroll
  for (int j = 0; j < 4; ++j) {
    ushort4 p;
    p.x = f2bf(hc[j * 4 + 0]); p.y = f2bf(hc[j * 4 + 1]);
    p.z = f2bf(hc[j * 4 + 2]); p.w = f2bf(hc[j * 4 + 3]);
    *(ushort4*)(h2b + (size_t)n * 16 + j * 4) = p;
  }
  *(float2*)(ef2s + (size_t)n * 2) = make_float2(expf(ss), expf(NEG_SLOPE * ss));
  *(float2*)(ef2d + (size_t)n * 2) = make_float2(expf(dd), expf(NEG_SLOPE * dd));
}

// ---------------- K agg2 ----------------
__global__ __launch_bounds__(256) void k_agg2(const int* __restrict__ rowptr,
                                              const int* __restrict__ deg,
                                              const int* __restrict__ srt,
                                              const float* __restrict__ ef2s,
                                              const float* __restrict__ ef2d,
                                              const unsigned short* __restrict__ h2b,
                                              const float* __restrict__ b2,
                                              float* __restrict__ out, int N) {
  int wid = (blockIdx.x * blockDim.x + threadIdx.x) >> 6;  // dst node
  int lane = threadIdx.x & 63;
  if (wid >= N) return;
  int d = wid;
  int c = lane & 15;
  int j = lane >> 4;
  float2 ddp = *(const float2*)(ef2d + (size_t)d * 2);
  float acc = 0.f, den = 0.f;
  int start = rowptr[d];
  int len = deg[d];
  for (int k = j; k < len; k += 4) {
    int s = srt[start + k];
    float2 p = *(const float2*)(ef2s + (size_t)s * 2);
    float t = p.x * ddp.x, u = p.y * ddp.y;
    float ex = (t >= 1.f) ? t : u;
    acc += ex * bf2f(h2b[(size_t)s * 16 + c]);
    if (c == 0) den += ex;
  }
  acc += __shfl_down(acc, 32);
  acc += __shfl_down(acc, 16);
  den += __shfl_down(den, 32);
  den += __shfl_down(den, 16);
  den = __shfl(den, 0);
  if (lane < 16) {
    float2 ps = *(const float2*)(ef2s + (size_t)d * 2);
    float t = ps.x * ddp.x, u = ps.y * ddp.y;
    float ex0 = (t >= 1.f) ? t : u;
    acc += ex0 * bf2f(h2b[(size_t)d * 16 + c]);
    den += ex0;
    float val = acc / (den + 1e-16f) + b2[c];
    float m = val;
#pragma unroll
    for (int o = 1; o < 16; o <<= 1) m = fmaxf(m, __shfl_xor(m, o));
    float s = expf(val - m);
#pragma unroll
    for (int o = 1; o < 16; o <<= 1) s += __shfl_xor(s, o);
    out[(size_t)d * 16 + c] = val - (m + logf(s));
  }
}

extern "C" void kernel_launch(void* const* d_in, const int* in_sizes, int n_in,
                              void* d_out, int out_size, void* d_ws, size_t ws_size,
                              hipStream_t stream) {
  const float* x    = (const float*)d_in[0];
  const int*   ei   = (const int*)d_in[1];
  const float* W1   = (const float*)d_in[2];
  const float* a1s  = (const float*)d_in[3];
  const float* a1d  = (const float*)d_in[4];
  const float* b1   = (const float*)d_in[5];
  const float* W2   = (const float*)d_in[6];
  const float* a2s  = (const float*)d_in[7];
  const float* a2d  = (const float*)d_in[8];
  const float* b2   = (const float*)d_in[9];
  float* out = (float*)d_out;

  const int N = in_sizes[0] / 512;
  const int E = in_sizes[1] / 2;
  const int* src = ei;
  const int* dst = ei + E;
  const int B = (N + BKT_RANGE - 1) >> BKT_SHIFT;     // buckets (<=512)
  const int EB = (E + EPB - 1) / EPB;                 // edge blocks

  float* w = (float*)d_ws;
  float* out1 = w;  w += (size_t)N * 64;   // binned (int2, E entries) aliases this
  float* ef1s = w;  w += (size_t)N * 16;
  float* ef1d = w;  w += (size_t)N * 16;
  float* ef2s = w;  w += (size_t)N * 2;
  float* ef2d = w;  w += (size_t)N * 2;
  unsigned short* h1b = (unsigned short*)w;  w += (size_t)N * 32;
  unsigned short* h2b = (unsigned short*)w;  w += (size_t)N * 8;
  int* iw = (int*)w;
  int* deg         = iw;  iw += N;
  int* rowptr      = iw;  iw += N;
  int* bucketCount = iw;  iw += 1024;
  int* bucketOff   = iw;  iw += 1024;
  int* gCursor     = iw;  iw += 1024;
  int* srt         = iw;  iw += E;
  int2* binned = (int2*)out1;  // dead before out1 is written

  // CSR build via bucketed counting sort
  k_zero<<<2, 512, 0, stream>>>(bucketCount, 1024);
  k_bhist<<<EB, 256, 0, stream>>>(dst, bucketCount, E, B);
  k_bscan<<<1, 512, 0, stream>>>(bucketCount, bucketOff, gCursor, B, E);
  k_bin<<<EB, 256, 0, stream>>>(src, dst, gCursor, binned, E, B);
  k_build<<<B, 256, 0, stream>>>(bucketOff, binned, rowptr, deg, srt, N);

  // Layer 1
  k_gemm1<<<(N + 63) / 64, 256, 0, stream>>>(x, W1, h1b, N);
  k_alpha1<<<(N * 8 + 255) / 256, 256, 0, stream>>>(h1b, a1s, a1d, ef1s, ef1d, N);
  k_agg1<<<(int)(((size_t)N * 64 + 255) / 256), 256, 0, stream>>>(rowptr, deg, srt, ef1s, ef1d, h1b, out1, N);

  // Layer 2
  k_layer2_node<<<(N + 255) / 256, 256, 0, stream>>>(out1, b1, W2, a2s, a2d, h2b, ef2s, ef2d, N);
  k_agg2<<<(int)(((size_t)N * 64 + 255) / 256), 256, 0, stream>>>(rowptr, deg, srt, ef2s, ef2d, h2b, b2, out, N);
}

// Round 6
// 322.675 us; speedup vs baseline: 4.1429x; 1.1720x over previous
//
#include <hip/hip_runtime.h>
#include <math.h>

#define NEG_SLOPE 0.2f
#define BKT_SHIFT 8                 // 256 dst nodes per bucket
#define BKT_RANGE 256
#define EPB 4096                    // edges per block in binning kernels

typedef __attribute__((ext_vector_type(8))) short bf16x8;
typedef __attribute__((ext_vector_type(4))) float f32x4;

__device__ __forceinline__ float leaky(float x) { return x >= 0.f ? x : NEG_SLOPE * x; }
__device__ __forceinline__ float elu1(float x)  { return x > 0.f ? x : expm1f(x); }

__device__ __forceinline__ unsigned short f2bf(float f) {
  unsigned u = __float_as_uint(f);
  unsigned r = (u + 0x7FFFu + ((u >> 16) & 1u)) >> 16;
  return (unsigned short)r;
}
__device__ __forceinline__ float bf2f(unsigned short s) {
  return __uint_as_float((unsigned)s << 16);
}

// ---------------- K0: Wt[c][k] = bf16(W1[k][c])  (one-shot transpose+convert) ----------------
__global__ __launch_bounds__(256) void k_cvtW(const float* __restrict__ W,
                                              unsigned short* __restrict__ Wt) {
  int i = blockIdx.x * 256 + threadIdx.x;  // i = k*64 + c
  if (i >= 512 * 64) return;
  int k = i >> 6, c = i & 63;
  Wt[(size_t)c * 512 + k] = f2bf(W[i]);
}

// ---------------- K1: h1b = bf16(x @ W1) via MFMA : [N,512]@[512,64] ----------------
// 4 waves/block; block tile 128x64; BK=64; LDS XOR-swizzled in 16B chunks.
__global__ __launch_bounds__(256) void k_gemm1_mfma(const float* __restrict__ x,
                                                    const unsigned short* __restrict__ Wt,
                                                    unsigned short* __restrict__ h1b, int N) {
  __shared__ unsigned short As[128 * 64];  // row r: 8 chunks of 8 bf16, chunk ch stored at ch^(r&7)
  __shared__ unsigned short Bs[64 * 64];   // Bt col c: 8 chunks, swizzle by c&7
  const int t = threadIdx.x;
  const int w = t >> 6;       // wave 0..3
  const int l = t & 63;
  const int fr = l & 15;
  const int fq = l >> 4;      // 0..3
  const int rowbase = blockIdx.x * 128;
  f32x4 acc[2][4] = {};

  for (int k0 = 0; k0 < 512; k0 += 64) {
    // ---- stage A (fully coalesced f32 reads, convert to bf16, swizzled LDS write)
#pragma unroll
    for (int j = 0; j < 8; ++j) {
      int idx = j * 256 + t;            // 0..2047 float4-slots of the 128x64 tile
      int row = idx >> 4;
      int cg  = idx & 15;               // col-group of 4 floats
      int grow = rowbase + row;
      float4 v = make_float4(0.f, 0.f, 0.f, 0.f);
      if (grow < N) v = *(const float4*)(x + (size_t)grow * 512 + k0 + cg * 4);
      uint2 pk;
      pk.x = (unsigned)f2bf(v.x) | ((unsigned)f2bf(v.y) << 16);
      pk.y = (unsigned)f2bf(v.z) | ((unsigned)f2bf(v.w) << 16);
      int ch = cg >> 1;
      int pch = ch ^ (row & 7);
      *((uint2*)(As + row * 64 + pch * 8 + (cg & 1) * 4)) = pk;
    }
    // ---- stage B: 512 chunks of 16B from Wt
#pragma unroll
    for (int rep = 0; rep < 2; ++rep) {
      int i = t + rep * 256;            // 0..511
      int c = i >> 3, ch = i & 7;
      uint4 v = *(const uint4*)(Wt + (size_t)c * 512 + k0 + ch * 8);
      *((uint4*)(Bs + c * 64 + (ch ^ (c & 7)) * 8)) = v;
    }
    __syncthreads();
    // ---- compute: 2 k-substeps of 32
#pragma unroll
    for (int ks = 0; ks < 2; ++ks) {
      bf16x8 a[2], b[4];
#pragma unroll
      for (int m = 0; m < 2; ++m) {
        int r = w * 32 + m * 16 + fr;
        int ch = (ks * 4 + fq) ^ (r & 7);
        a[m] = *((const bf16x8*)(As + r * 64 + ch * 8));
      }
#pragma unroll
      for (int n = 0; n < 4; ++n) {
        int c = n * 16 + fr;
        int ch = (ks * 4 + fq) ^ (c & 7);
        b[n] = *((const bf16x8*)(Bs + c * 64 + ch * 8));
      }
#pragma unroll
      for (int m = 0; m < 2; ++m)
#pragma unroll
        for (int n = 0; n < 4; ++n)
          acc[m][n] = __builtin_amdgcn_mfma_f32_16x16x32_bf16(a[m], b[n], acc[m][n], 0, 0, 0);
    }
    __syncthreads();
  }
  // ---- store: D row=(fq*4+reg), col=fr within each 16x16 frag
#pragma unroll
  for (int m = 0; m < 2; ++m) {
    int rb = rowbase + w * 32 + m * 16 + fq * 4;
#pragma unroll
    for (int reg = 0; reg < 4; ++reg) {
      int row = rb + reg;
      if (row < N) {
#pragma unroll
        for (int n = 0; n < 4; ++n)
          h1b[(size_t)row * 64 + n * 16 + fr] = f2bf(acc[m][n][reg]);
      }
    }
  }
}

// ---------------- K1b: per-(node,head) factored-exp alpha tables ----------------
__global__ __launch_bounds__(256) void k_alpha1(const unsigned short* __restrict__ h1b,
                                                const float* __restrict__ a1s,
                                                const float* __restrict__ a1d,
                                                float* __restrict__ ef1s,
                                                float* __restrict__ ef1d, int N) {
  int idx = blockIdx.x * blockDim.x + threadIdx.x;  // n*8 + h
  if (idx >= N * 8) return;
  int h = idx & 7;
  uint4 raw = *(const uint4*)(h1b + (size_t)idx * 8);
  float v[8];
  v[0] = bf2f((unsigned short)(raw.x & 0xFFFF)); v[1] = bf2f((unsigned short)(raw.x >> 16));
  v[2] = bf2f((unsigned short)(raw.y & 0xFFFF)); v[3] = bf2f((unsigned short)(raw.y >> 16));
  v[4] = bf2f((unsigned short)(raw.z & 0xFFFF)); v[5] = bf2f((unsigned short)(raw.z >> 16));
  v[6] = bf2f((unsigned short)(raw.w & 0xFFFF)); v[7] = bf2f((unsigned short)(raw.w >> 16));
  const float* s_ = a1s + h * 8;
  const float* d_ = a1d + h * 8;
  float ss = 0.f, dd = 0.f;
#pragma unroll
  for (int j = 0; j < 8; ++j) { ss += v[j] * s_[j]; dd += v[j] * d_[j]; }
  *(float2*)(ef1s + (size_t)idx * 2) = make_float2(expf(ss), expf(NEG_SLOPE * ss));
  *(float2*)(ef1d + (size_t)idx * 2) = make_float2(expf(dd), expf(NEG_SLOPE * dd));
}

// ---------------- CSR build: two-level bucketed counting sort ----------------
__global__ __launch_bounds__(512) void k_zero(int* __restrict__ p, int n) {
  int i = blockIdx.x * blockDim.x + threadIdx.x;
  if (i < n) p[i] = 0;
}

__global__ __launch_bounds__(256) void k_bhist(const int* __restrict__ dst,
                                               int* __restrict__ bucketCount,
                                               int E, int B) {
  __shared__ int h[512];
  int t = threadIdx.x;
  for (int i = t; i < B; i += 256) h[i] = 0;
  __syncthreads();
  int e0 = blockIdx.x * EPB;
#pragma unroll
  for (int i = 0; i < EPB / 256; ++i) {
    int e = e0 + i * 256 + t;
    if (e < E) atomicAdd(&h[dst[e] >> BKT_SHIFT], 1);
  }
  __syncthreads();
  for (int i = t; i < B; i += 256)
    if (h[i]) atomicAdd(bucketCount + i, h[i]);
}

__global__ __launch_bounds__(512) void k_bscan(const int* __restrict__ bucketCount,
                                               int* __restrict__ bucketOff,
                                               int* __restrict__ gCursor, int B, int E) {
  __shared__ int sm[512];
  int t = threadIdx.x;
  int v = (t < B) ? bucketCount[t] : 0;
  sm[t] = v;
  __syncthreads();
  int acc = v;
#pragma unroll
  for (int o = 1; o < 512; o <<= 1) {
    int u = (t >= o) ? sm[t - o] : 0;
    __syncthreads();
    acc += u;
    sm[t] = acc;
    __syncthreads();
  }
  if (t < B) {
    bucketOff[t] = acc - v;
    gCursor[t] = acc - v;
  }
  if (t == 0) bucketOff[B] = E;
}

__global__ __launch_bounds__(256) void k_bin(const int* __restrict__ src,
                                             const int* __restrict__ dst,
                                             int* __restrict__ gCursor,
                                             int2* __restrict__ binned,
                                             int E, int B) {
  __shared__ int hist[512];
  __shared__ int base[512];
  int t = threadIdx.x;
  for (int i = t; i < B; i += 256) hist[i] = 0;
  __syncthreads();
  int e0 = blockIdx.x * EPB;
#pragma unroll
  for (int i = 0; i < EPB / 256; ++i) {
    int e = e0 + i * 256 + t;
    if (e < E) atomicAdd(&hist[dst[e] >> BKT_SHIFT], 1);
  }
  __syncthreads();
  for (int i = t; i < B; i += 256) {
    int c = hist[i];
    base[i] = c ? atomicAdd(gCursor + i, c) : 0;
    hist[i] = 0;
  }
  __syncthreads();
#pragma unroll
  for (int i = 0; i < EPB / 256; ++i) {
    int e = e0 + i * 256 + t;
    if (e < E) {
      int d = dst[e];
      int b = d >> BKT_SHIFT;
      int r = atomicAdd(&hist[b], 1);
      binned[base[b] + r] = make_int2(src[e], d);
    }
  }
}

__global__ __launch_bounds__(256) void k_build(const int* __restrict__ bucketOff,
                                               const int2* __restrict__ binned,
                                               int* __restrict__ rowptr,
                                               int* __restrict__ deg,
                                               int* __restrict__ srt, int N) {
  __shared__ int ldeg[BKT_RANGE];
  __shared__ int sm[BKT_RANGE];
  __shared__ int lcur[BKT_RANGE];
  int t = threadIdx.x;
  int b = blockIdx.x;
  int nbase = b * BKT_RANGE;
  int estart = bucketOff[b];
  int eend = bucketOff[b + 1];
  ldeg[t] = 0;
  __syncthreads();
  for (int e = estart + t; e < eend; e += 256)
    atomicAdd(&ldeg[binned[e].y - nbase], 1);
  __syncthreads();
  int v = ldeg[t];
  sm[t] = v;
  __syncthreads();
  int acc = v;
#pragma unroll
  for (int o = 1; o < 256; o <<= 1) {
    int u = (t >= o) ? sm[t - o] : 0;
    __syncthreads();
    acc += u;
    sm[t] = acc;
    __syncthreads();
  }
  int excl = estart + acc - v;
  int node = nbase + t;
  if (node < N) {
    rowptr[node] = excl;
    deg[node] = v;
  }
  lcur[t] = excl;
  __syncthreads();
  for (int e = estart + t; e < eend; e += 256) {
    int2 p = binned[e];
    int pos = atomicAdd(&lcur[p.y - nbase], 1);
    srt[pos] = p.x;
  }
}

// ---------------- K agg1: gather-reduce layer 1, wave per dst ----------------
__global__ __launch_bounds__(256) void k_agg1(const int* __restrict__ rowptr,
                                              const int* __restrict__ deg,
                                              const int* __restrict__ srt,
                                              const float* __restrict__ ef1s,
                                              const float* __restrict__ ef1d,
                                              const unsigned short* __restrict__ h1b,
                                              float* __restrict__ out1, int N) {
  int wid = (blockIdx.x * blockDim.x + threadIdx.x) >> 6;  // dst node
  int lane = threadIdx.x & 63;
  if (wid >= N) return;
  int d = wid;
  int h = lane >> 3;
  float2 dd = *(const float2*)(ef1d + (size_t)d * 16 + h * 2);  // {ead, fad}
  float2 ps = *(const float2*)(ef1s + (size_t)d * 16 + h * 2);
  float t0 = ps.x * dd.x, u0 = ps.y * dd.y;
  float ex0 = (t0 >= 1.f) ? t0 : u0;
  float acc = ex0 * bf2f(h1b[(size_t)d * 64 + lane]);
  float den = ex0;
  int start = rowptr[d];
  int len = deg[d];
  int k = 0;
  for (; k + 2 <= len; k += 2) {
    int s0 = srt[start + k];
    int s1 = srt[start + k + 1];
    float2 p0 = *(const float2*)(ef1s + (size_t)s0 * 16 + h * 2);
    float2 p1 = *(const float2*)(ef1s + (size_t)s1 * 16 + h * 2);
    float v0 = bf2f(h1b[(size_t)s0 * 64 + lane]);
    float v1 = bf2f(h1b[(size_t)s1 * 64 + lane]);
    float ta = p0.x * dd.x, ua = p0.y * dd.y;
    float tb = p1.x * dd.x, ub = p1.y * dd.y;
    float exa = (ta >= 1.f) ? ta : ua;
    float exb = (tb >= 1.f) ? tb : ub;
    acc += exa * v0 + exb * v1;
    den += exa + exb;
  }
  if (k < len) {
    int s0 = srt[start + k];
    float2 p0 = *(const float2*)(ef1s + (size_t)s0 * 16 + h * 2);
    float v0 = bf2f(h1b[(size_t)s0 * 64 + lane]);
    float ta = p0.x * dd.x, ua = p0.y * dd.y;
    float exa = (ta >= 1.f) ? ta : ua;
    acc += exa * v0;
    den += exa;
  }
  out1[(size_t)d * 64 + lane] = acc / (den + 1e-16f);
}

// ---------------- K layer2 node ----------------
__global__ __launch_bounds__(256) void k_layer2_node(const float* __restrict__ out1,
                                                     const float* __restrict__ b1,
                                                     const float* __restrict__ W2,
                                                     const float* __restrict__ a2s,
                                                     const float* __restrict__ a2d,
                                                     unsigned short* __restrict__ h2b,
                                                     float* __restrict__ ef2s,
                                                     float* __restrict__ ef2d, int N) {
  __shared__ float w2s[64 * 16];
  __shared__ float b1s[64];
  for (int i = threadIdx.x; i < 64 * 16; i += blockDim.x) w2s[i] = W2[i];
  if (threadIdx.x < 64) b1s[threadIdx.x] = b1[threadIdx.x];
  __syncthreads();
  int n = blockIdx.x * blockDim.x + threadIdx.x;
  if (n >= N) return;
  float v[64];
  const float4* op = (const float4*)(out1 + (size_t)n * 64);
#pragma unroll
  for (int j = 0; j < 16; ++j) {
    float4 q = op[j];
    v[j * 4 + 0] = elu1(q.x + b1s[j * 4 + 0]);
    v[j * 4 + 1] = elu1(q.y + b1s[j * 4 + 1]);
    v[j * 4 + 2] = elu1(q.z + b1s[j * 4 + 2]);
    v[j * 4 + 3] = elu1(q.w + b1s[j * 4 + 3]);
  }
  float hc[16] = {};
#pragma unroll
  for (int k = 0; k < 64; ++k) {
    float vk = v[k];
#pragma unroll
    for (int c = 0; c < 16; ++c) hc[c] += vk * w2s[k * 16 + c];
  }
  float ss = 0.f, dd = 0.f;
#pragma unroll
  for (int c = 0; c < 16; ++c) { ss += hc[c] * a2s[c]; dd += hc[c] * a2d[c]; }
#pragma unroll
  for (int j = 0; j < 4; ++j) {
    ushort4 p;
    p.x = f2bf(hc[j * 4 + 0]); p.y = f2bf(hc[j * 4 + 1]);
    p.z = f2bf(hc[j * 4 + 2]); p.w = f2bf(hc[j * 4 + 3]);
    *(ushort4*)(h2b + (size_t)n * 16 + j * 4) = p;
  }
  *(float2*)(ef2s + (size_t)n * 2) = make_float2(expf(ss), expf(NEG_SLOPE * ss));
  *(float2*)(ef2d + (size_t)n * 2) = make_float2(expf(dd), expf(NEG_SLOPE * dd));
}

// ---------------- K agg2 ----------------
__global__ __launch_bounds__(256) void k_agg2(const int* __restrict__ rowptr,
                                              const int* __restrict__ deg,
                                              const int* __restrict__ srt,
                                              const float* __restrict__ ef2s,
                                              const float* __restrict__ ef2d,
                                              const unsigned short* __restrict__ h2b,
                                              const float* __restrict__ b2,
                                              float* __restrict__ out, int N) {
  int wid = (blockIdx.x * blockDim.x + threadIdx.x) >> 6;  // dst node
  int lane = threadIdx.x & 63;
  if (wid >= N) return;
  int d = wid;
  int c = lane & 15;
  int j = lane >> 4;
  float2 ddp = *(const float2*)(ef2d + (size_t)d * 2);
  float acc = 0.f, den = 0.f;
  int start = rowptr[d];
  int len = deg[d];
  for (int k = j; k < len; k += 4) {
    int s = srt[start + k];
    float2 p = *(const float2*)(ef2s + (size_t)s * 2);
    float t = p.x * ddp.x, u = p.y * ddp.y;
    float ex = (t >= 1.f) ? t : u;
    acc += ex * bf2f(h2b[(size_t)s * 16 + c]);
    if (c == 0) den += ex;
  }
  acc += __shfl_down(acc, 32);
  acc += __shfl_down(acc, 16);
  den += __shfl_down(den, 32);
  den += __shfl_down(den, 16);
  den = __shfl(den, 0);
  if (lane < 16) {
    float2 ps = *(const float2*)(ef2s + (size_t)d * 2);
    float t = ps.x * ddp.x, u = ps.y * ddp.y;
    float ex0 = (t >= 1.f) ? t : u;
    acc += ex0 * bf2f(h2b[(size_t)d * 16 + c]);
    den += ex0;
    float val = acc / (den + 1e-16f) + b2[c];
    float m = val;
#pragma unroll
    for (int o = 1; o < 16; o <<= 1) m = fmaxf(m, __shfl_xor(m, o));
    float s = expf(val - m);
#pragma unroll
    for (int o = 1; o < 16; o <<= 1) s += __shfl_xor(s, o);
    out[(size_t)d * 16 + c] = val - (m + logf(s));
  }
}

extern "C" void kernel_launch(void* const* d_in, const int* in_sizes, int n_in,
                              void* d_out, int out_size, void* d_ws, size_t ws_size,
                              hipStream_t stream) {
  const float* x    = (const float*)d_in[0];
  const int*   ei   = (const int*)d_in[1];
  const float* W1   = (const float*)d_in[2];
  const float* a1s  = (const float*)d_in[3];
  const float* a1d  = (const float*)d_in[4];
  const float* b1   = (const float*)d_in[5];
  const float* W2   = (const float*)d_in[6];
  const float* a2s  = (const float*)d_in[7];
  const float* a2d  = (const float*)d_in[8];
  const float* b2   = (const float*)d_in[9];
  float* out = (float*)d_out;

  const int N = in_sizes[0] / 512;
  const int E = in_sizes[1] / 2;
  const int* src = ei;
  const int* dst = ei + E;
  const int B = (N + BKT_RANGE - 1) >> BKT_SHIFT;
  const int EB = (E + EPB - 1) / EPB;

  float* w = (float*)d_ws;
  float* out1 = w;  w += (size_t)N * 64;   // binned (int2, E entries) aliases this
  float* ef1s = w;  w += (size_t)N * 16;
  float* ef1d = w;  w += (size_t)N * 16;
  float* ef2s = w;  w += (size_t)N * 2;
  float* ef2d = w;  w += (size_t)N * 2;
  unsigned short* h1b = (unsigned short*)w;  w += (size_t)N * 32;
  unsigned short* h2b = (unsigned short*)w;  w += (size_t)N * 8;
  unsigned short* Wt  = (unsigned short*)w;  w += 512 * 64 / 2;   // 64KB bf16 W1^T
  int* iw = (int*)w;
  int* deg         = iw;  iw += N;
  int* rowptr      = iw;  iw += N;
  int* bucketCount = iw;  iw += 1024;
  int* bucketOff   = iw;  iw += 1024;
  int* gCursor     = iw;  iw += 1024;
  int* srt         = iw;  iw += E;
  int2* binned = (int2*)out1;  // dead before out1 is written

  // CSR build via bucketed counting sort
  k_zero<<<2, 512, 0, stream>>>(bucketCount, 1024);
  k_bhist<<<EB, 256, 0, stream>>>(dst, bucketCount, E, B);
  k_bscan<<<1, 512, 0, stream>>>(bucketCount, bucketOff, gCursor, B, E);
  k_bin<<<EB, 256, 0, stream>>>(src, dst, gCursor, binned, E, B);
  k_build<<<B, 256, 0, stream>>>(bucketOff, binned, rowptr, deg, srt, N);

  // Layer 1
  k_cvtW<<<(512 * 64 + 255) / 256, 256, 0, stream>>>(W1, Wt);
  k_gemm1_mfma<<<(N + 127) / 128, 256, 0, stream>>>(x, Wt, h1b, N);
  k_alpha1<<<(N * 8 + 255) / 256, 256, 0, stream>>>(h1b, a1s, a1d, ef1s, ef1d, N);
  k_agg1<<<(int)(((size_t)N * 64 + 255) / 256), 256, 0, stream>>>(rowptr, deg, srt, ef1s, ef1d, h1b, out1, N);

  // Layer 2
  k_layer2_node<<<(N + 255) / 256, 256, 0, stream>>>(out1, b1, W2, a2s, a2d, h2b, ef2s, ef2d, N);
  k_agg2<<<(int)(((size_t)N * 64 + 255) / 256), 256, 0, stream>>>(rowptr, deg, srt, ef2s, ef2d, h2b, b2, out, N);
}

// Round 7
// 282.232 us; speedup vs baseline: 4.7366x; 1.1433x over previous
//
#include <hip/hip_runtime.h>
#include <math.h>

#define NEG_SLOPE 0.2f
#define BKT_SHIFT 8                 // 256 dst nodes per bucket
#define BKT_RANGE 256
#define EPB 4096                    // edges per block in binning kernels

typedef __attribute__((ext_vector_type(8))) short bf16x8;
typedef __attribute__((ext_vector_type(4))) float f32x4;

__device__ __forceinline__ float leaky(float x) { return x >= 0.f ? x : NEG_SLOPE * x; }
__device__ __forceinline__ float elu1(float x)  { return x > 0.f ? x : expm1f(x); }

__device__ __forceinline__ unsigned short f2bf(float f) {
  unsigned u = __float_as_uint(f);
  unsigned r = (u + 0x7FFFu + ((u >> 16) & 1u)) >> 16;
  return (unsigned short)r;
}
__device__ __forceinline__ float bf2f(unsigned short s) {
  return __uint_as_float((unsigned)s << 16);
}
// HW packed f32->bf16 (RNE), 1 instruction for 2 floats
__device__ __forceinline__ unsigned cvt_pk_bf16(float lo, float hi) {
  unsigned r;
  asm("v_cvt_pk_bf16_f32 %0, %1, %2" : "=v"(r) : "v"(lo), "v"(hi));
  return r;
}

// ---------------- K0: Wt[c][k] = bf16(W1[k][c]) ----------------
__global__ __launch_bounds__(256) void k_cvtW(const float* __restrict__ W,
                                              unsigned short* __restrict__ Wt) {
  int i = blockIdx.x * 256 + threadIdx.x;  // i = k*64 + c
  if (i >= 512 * 64) return;
  int k = i >> 6, c = i & 63;
  Wt[(size_t)c * 512 + k] = f2bf(W[i]);
}

// ---------------- K1: h1b = bf16(x @ W1) via MFMA : [N,512]@[512,64] ----------------
__global__ __launch_bounds__(256) void k_gemm1_mfma(const float* __restrict__ x,
                                                    const unsigned short* __restrict__ Wt,
                                                    unsigned short* __restrict__ h1b, int N) {
  __shared__ unsigned short As[128 * 64];
  __shared__ unsigned short Bs[64 * 64];
  const int t = threadIdx.x;
  const int w = t >> 6;
  const int l = t & 63;
  const int fr = l & 15;
  const int fq = l >> 4;
  const int rowbase = blockIdx.x * 128;
  f32x4 acc[2][4] = {};

  for (int k0 = 0; k0 < 512; k0 += 64) {
#pragma unroll
    for (int j = 0; j < 8; ++j) {
      int idx = j * 256 + t;
      int row = idx >> 4;
      int cg  = idx & 15;
      int grow = rowbase + row;
      float4 v = make_float4(0.f, 0.f, 0.f, 0.f);
      if (grow < N) v = *(const float4*)(x + (size_t)grow * 512 + k0 + cg * 4);
      uint2 pk;
      pk.x = cvt_pk_bf16(v.x, v.y);
      pk.y = cvt_pk_bf16(v.z, v.w);
      int ch = cg >> 1;
      int pch = ch ^ (row & 7);
      *((uint2*)(As + row * 64 + pch * 8 + (cg & 1) * 4)) = pk;
    }
#pragma unroll
    for (int rep = 0; rep < 2; ++rep) {
      int i = t + rep * 256;
      int c = i >> 3, ch = i & 7;
      uint4 v = *(const uint4*)(Wt + (size_t)c * 512 + k0 + ch * 8);
      *((uint4*)(Bs + c * 64 + (ch ^ (c & 7)) * 8)) = v;
    }
    __syncthreads();
#pragma unroll
    for (int ks = 0; ks < 2; ++ks) {
      bf16x8 a[2], b[4];
#pragma unroll
      for (int m = 0; m < 2; ++m) {
        int r = w * 32 + m * 16 + fr;
        int ch = (ks * 4 + fq) ^ (r & 7);
        a[m] = *((const bf16x8*)(As + r * 64 + ch * 8));
      }
#pragma unroll
      for (int n = 0; n < 4; ++n) {
        int c = n * 16 + fr;
        int ch = (ks * 4 + fq) ^ (c & 7);
        b[n] = *((const bf16x8*)(Bs + c * 64 + ch * 8));
      }
#pragma unroll
      for (int m = 0; m < 2; ++m)
#pragma unroll
        for (int n = 0; n < 4; ++n)
          acc[m][n] = __builtin_amdgcn_mfma_f32_16x16x32_bf16(a[m], b[n], acc[m][n], 0, 0, 0);
    }
    __syncthreads();
  }
#pragma unroll
  for (int m = 0; m < 2; ++m) {
    int rb = rowbase + w * 32 + m * 16 + fq * 4;
#pragma unroll
    for (int reg = 0; reg < 4; ++reg) {
      int row = rb + reg;
      if (row < N) {
#pragma unroll
        for (int n = 0; n < 4; ++n)
          h1b[(size_t)row * 64 + n * 16 + fr] = f2bf(acc[m][n][reg]);
      }
    }
  }
}

// ---------------- K1b: per-(node,head) factored-exp alpha tables ----------------
__global__ __launch_bounds__(256) void k_alpha1(const unsigned short* __restrict__ h1b,
                                                const float* __restrict__ a1s,
                                                const float* __restrict__ a1d,
                                                float* __restrict__ ef1s,
                                                float* __restrict__ ef1d, int N) {
  int idx = blockIdx.x * blockDim.x + threadIdx.x;  // n*8 + h
  if (idx >= N * 8) return;
  int h = idx & 7;
  uint4 raw = *(const uint4*)(h1b + (size_t)idx * 8);
  float v[8];
  v[0] = bf2f((unsigned short)(raw.x & 0xFFFF)); v[1] = bf2f((unsigned short)(raw.x >> 16));
  v[2] = bf2f((unsigned short)(raw.y & 0xFFFF)); v[3] = bf2f((unsigned short)(raw.y >> 16));
  v[4] = bf2f((unsigned short)(raw.z & 0xFFFF)); v[5] = bf2f((unsigned short)(raw.z >> 16));
  v[6] = bf2f((unsigned short)(raw.w & 0xFFFF)); v[7] = bf2f((unsigned short)(raw.w >> 16));
  const float* s_ = a1s + h * 8;
  const float* d_ = a1d + h * 8;
  float ss = 0.f, dd = 0.f;
#pragma unroll
  for (int j = 0; j < 8; ++j) { ss += v[j] * s_[j]; dd += v[j] * d_[j]; }
  *(float2*)(ef1s + (size_t)idx * 2) = make_float2(expf(ss), expf(NEG_SLOPE * ss));
  *(float2*)(ef1d + (size_t)idx * 2) = make_float2(expf(dd), expf(NEG_SLOPE * dd));
}

// ---------------- CSR build: two-level bucketed counting sort ----------------
__global__ __launch_bounds__(512) void k_zero(int* __restrict__ p, int n) {
  int i = blockIdx.x * blockDim.x + threadIdx.x;
  if (i < n) p[i] = 0;
}

__global__ __launch_bounds__(256) void k_bhist(const int* __restrict__ dst,
                                               int* __restrict__ bucketCount,
                                               int E, int B) {
  __shared__ int h[512];
  int t = threadIdx.x;
  for (int i = t; i < B; i += 256) h[i] = 0;
  __syncthreads();
  int e0 = blockIdx.x * EPB;
#pragma unroll
  for (int i = 0; i < EPB / 256; ++i) {
    int e = e0 + i * 256 + t;
    if (e < E) atomicAdd(&h[dst[e] >> BKT_SHIFT], 1);
  }
  __syncthreads();
  for (int i = t; i < B; i += 256)
    if (h[i]) atomicAdd(bucketCount + i, h[i]);
}

__global__ __launch_bounds__(512) void k_bscan(const int* __restrict__ bucketCount,
                                               int* __restrict__ bucketOff,
                                               int* __restrict__ gCursor, int B, int E) {
  __shared__ int sm[512];
  int t = threadIdx.x;
  int v = (t < B) ? bucketCount[t] : 0;
  sm[t] = v;
  __syncthreads();
  int acc = v;
#pragma unroll
  for (int o = 1; o < 512; o <<= 1) {
    int u = (t >= o) ? sm[t - o] : 0;
    __syncthreads();
    acc += u;
    sm[t] = acc;
    __syncthreads();
  }
  if (t < B) {
    bucketOff[t] = acc - v;
    gCursor[t] = acc - v;
  }
  if (t == 0) bucketOff[B] = E;
}

// radix partition: pack (local_dst<<24 | src) into u32 (src < 2^24)
__global__ __launch_bounds__(256) void k_bin(const int* __restrict__ src,
                                             const int* __restrict__ dst,
                                             int* __restrict__ gCursor,
                                             unsigned* __restrict__ binned,
                                             int E, int B) {
  __shared__ int hist[512];
  __shared__ int base[512];
  int t = threadIdx.x;
  for (int i = t; i < B; i += 256) hist[i] = 0;
  __syncthreads();
  int e0 = blockIdx.x * EPB;
#pragma unroll
  for (int i = 0; i < EPB / 256; ++i) {
    int e = e0 + i * 256 + t;
    if (e < E) atomicAdd(&hist[dst[e] >> BKT_SHIFT], 1);
  }
  __syncthreads();
  for (int i = t; i < B; i += 256) {
    int c = hist[i];
    base[i] = c ? atomicAdd(gCursor + i, c) : 0;
    hist[i] = 0;
  }
  __syncthreads();
#pragma unroll
  for (int i = 0; i < EPB / 256; ++i) {
    int e = e0 + i * 256 + t;
    if (e < E) {
      int d = dst[e];
      int b = d >> BKT_SHIFT;
      int r = atomicAdd(&hist[b], 1);
      binned[base[b] + r] = ((unsigned)(d & (BKT_RANGE - 1)) << 24) | (unsigned)src[e];
    }
  }
}

__global__ __launch_bounds__(256) void k_build(const int* __restrict__ bucketOff,
                                               const unsigned* __restrict__ binned,
                                               int* __restrict__ rowptr,
                                               int* __restrict__ deg,
                                               int* __restrict__ srt, int N) {
  __shared__ int ldeg[BKT_RANGE];
  __shared__ int sm[BKT_RANGE];
  __shared__ int lcur[BKT_RANGE];
  int t = threadIdx.x;
  int b = blockIdx.x;
  int nbase = b * BKT_RANGE;
  int estart = bucketOff[b];
  int eend = bucketOff[b + 1];
  ldeg[t] = 0;
  __syncthreads();
  for (int e = estart + t; e < eend; e += 256)
    atomicAdd(&ldeg[binned[e] >> 24], 1);
  __syncthreads();
  int v = ldeg[t];
  sm[t] = v;
  __syncthreads();
  int acc = v;
#pragma unroll
  for (int o = 1; o < 256; o <<= 1) {
    int u = (t >= o) ? sm[t - o] : 0;
    __syncthreads();
    acc += u;
    sm[t] = acc;
    __syncthreads();
  }
  int excl = estart + acc - v;
  int node = nbase + t;
  if (node < N) {
    rowptr[node] = excl;
    deg[node] = v;
  }
  lcur[t] = excl;
  __syncthreads();
  for (int e = estart + t; e < eend; e += 256) {
    unsigned p = binned[e];
    int pos = atomicAdd(&lcur[p >> 24], 1);
    srt[pos] = (int)(p & 0xFFFFFFu);
  }
}

// ---------------- K agg1f: gather-reduce layer 1 FUSED with layer-2 node work ----------------
// wave per dst: gather+softmax-normalize h1 -> elu(+b1) -> @W2 -> alpha2 tables
__global__ __launch_bounds__(256) void k_agg1f(const int* __restrict__ rowptr,
                                               const int* __restrict__ deg,
                                               const int* __restrict__ srt,
                                               const float* __restrict__ ef1s,
                                               const float* __restrict__ ef1d,
                                               const unsigned short* __restrict__ h1b,
                                               const float* __restrict__ b1,
                                               const float* __restrict__ W2,
                                               const float* __restrict__ a2s,
                                               const float* __restrict__ a2d,
                                               unsigned short* __restrict__ h2b,
                                               float* __restrict__ ef2s,
                                               float* __restrict__ ef2d, int N) {
  __shared__ float vsm[4][64];
  const int t = threadIdx.x;
  const int w = t >> 6;
  const int lane = t & 63;
  const int wid = blockIdx.x * 4 + w;
  // per-lane constants (uniform across nodes)
  const int c = lane & 15;
  const int jj = lane >> 4;
  float b1r = b1[lane];
  float a2sr = a2s[c];
  float a2dr = a2d[c];
  float wreg[16];
#pragma unroll
  for (int m = 0; m < 16; ++m) wreg[m] = W2[(jj * 16 + m) * 16 + c];
  if (wid >= N) return;
  const int d = wid;
  const int h = lane >> 3;

  float2 dd = *(const float2*)(ef1d + (size_t)d * 16 + h * 2);  // {ead, fad}
  float2 ps = *(const float2*)(ef1s + (size_t)d * 16 + h * 2);
  float t0 = ps.x * dd.x, u0 = ps.y * dd.y;
  float ex0 = (t0 >= 1.f) ? t0 : u0;
  float acc = ex0 * bf2f(h1b[(size_t)d * 64 + lane]);
  float den = ex0;
  int start = rowptr[d];
  int len = deg[d];
  int k = 0;
  for (; k + 4 <= len; k += 4) {
    int s0 = srt[start + k + 0];
    int s1 = srt[start + k + 1];
    int s2 = srt[start + k + 2];
    int s3 = srt[start + k + 3];
    float2 p0 = *(const float2*)(ef1s + (size_t)s0 * 16 + h * 2);
    float2 p1 = *(const float2*)(ef1s + (size_t)s1 * 16 + h * 2);
    float2 p2 = *(const float2*)(ef1s + (size_t)s2 * 16 + h * 2);
    float2 p3 = *(const float2*)(ef1s + (size_t)s3 * 16 + h * 2);
    float v0 = bf2f(h1b[(size_t)s0 * 64 + lane]);
    float v1 = bf2f(h1b[(size_t)s1 * 64 + lane]);
    float v2 = bf2f(h1b[(size_t)s2 * 64 + lane]);
    float v3 = bf2f(h1b[(size_t)s3 * 64 + lane]);
    float ea = p0.x * dd.x, fa = p0.y * dd.y;
    float eb = p1.x * dd.x, fb = p1.y * dd.y;
    float ec = p2.x * dd.x, fc = p2.y * dd.y;
    float ed = p3.x * dd.x, fd = p3.y * dd.y;
    float xa = (ea >= 1.f) ? ea : fa;
    float xb = (eb >= 1.f) ? eb : fb;
    float xc = (ec >= 1.f) ? ec : fc;
    float xd = (ed >= 1.f) ? ed : fd;
    acc += xa * v0 + xb * v1;
    acc += xc * v2 + xd * v3;
    den += (xa + xb) + (xc + xd);
  }
  for (; k < len; ++k) {
    int s0 = srt[start + k];
    float2 p0 = *(const float2*)(ef1s + (size_t)s0 * 16 + h * 2);
    float v0 = bf2f(h1b[(size_t)s0 * 64 + lane]);
    float ea = p0.x * dd.x, fa = p0.y * dd.y;
    float xa = (ea >= 1.f) ? ea : fa;
    acc += xa * v0;
    den += xa;
  }
  // ---- fused layer-2 node work ----
  float v = elu1(acc / (den + 1e-16f) + b1r);
  vsm[w][lane] = v;
  float partial = 0.f;
#pragma unroll
  for (int m = 0; m < 16; ++m) partial = fmaf(vsm[w][jj * 16 + m], wreg[m], partial);
  // alpha2 dots: full-wave reduce of partial * a2{s,d}[c]
  float qs = partial * a2sr;
  float qd = partial * a2dr;
#pragma unroll
  for (int o = 1; o < 64; o <<= 1) {
    qs += __shfl_xor(qs, o);
    qd += __shfl_xor(qd, o);
  }
  // hc[c]: reduce partial across jj groups
  float p2 = partial + __shfl_down(partial, 32);
  float hcv = p2 + __shfl_down(p2, 16);
  if (lane < 16) h2b[(size_t)d * 16 + c] = f2bf(hcv);
  if (lane == 0) {
    *(float2*)(ef2s + (size_t)d * 2) = make_float2(expf(qs), expf(NEG_SLOPE * qs));
    *(float2*)(ef2d + (size_t)d * 2) = make_float2(expf(qd), expf(NEG_SLOPE * qd));
  }
}

// ---------------- K agg2: gather-reduce layer 2 + b2 + log_softmax ----------------
__global__ __launch_bounds__(256) void k_agg2(const int* __restrict__ rowptr,
                                              const int* __restrict__ deg,
                                              const int* __restrict__ srt,
                                              const float* __restrict__ ef2s,
                                              const float* __restrict__ ef2d,
                                              const unsigned short* __restrict__ h2b,
                                              const float* __restrict__ b2,
                                              float* __restrict__ out, int N) {
  int wid = (blockIdx.x * blockDim.x + threadIdx.x) >> 6;
  int lane = threadIdx.x & 63;
  if (wid >= N) return;
  int d = wid;
  int c = lane & 15;
  int j = lane >> 4;
  float2 ddp = *(const float2*)(ef2d + (size_t)d * 2);
  float acc = 0.f, den = 0.f;
  int start = rowptr[d];
  int len = deg[d];
  int k = j;
  for (; k + 8 <= len; k += 8) {
    int s0 = srt[start + k];
    int s1 = srt[start + k + 4];
    float2 p0 = *(const float2*)(ef2s + (size_t)s0 * 2);
    float2 p1 = *(const float2*)(ef2s + (size_t)s1 * 2);
    float v0 = bf2f(h2b[(size_t)s0 * 16 + c]);
    float v1 = bf2f(h2b[(size_t)s1 * 16 + c]);
    float ta = p0.x * ddp.x, ua = p0.y * ddp.y;
    float tb = p1.x * ddp.x, ub = p1.y * ddp.y;
    float xa = (ta >= 1.f) ? ta : ua;
    float xb = (tb >= 1.f) ? tb : ub;
    acc += xa * v0 + xb * v1;
    if (c == 0) den += xa + xb;
  }
  for (; k < len; k += 4) {
    int s = srt[start + k];
    float2 p = *(const float2*)(ef2s + (size_t)s * 2);
    float tt = p.x * ddp.x, u = p.y * ddp.y;
    float ex = (tt >= 1.f) ? tt : u;
    acc += ex * bf2f(h2b[(size_t)s * 16 + c]);
    if (c == 0) den += ex;
  }
  acc += __shfl_down(acc, 32);
  acc += __shfl_down(acc, 16);
  den += __shfl_down(den, 32);
  den += __shfl_down(den, 16);
  den = __shfl(den, 0);
  if (lane < 16) {
    float2 ps = *(const float2*)(ef2s + (size_t)d * 2);
    float tt = ps.x * ddp.x, u = ps.y * ddp.y;
    float ex0 = (tt >= 1.f) ? tt : u;
    acc += ex0 * bf2f(h2b[(size_t)d * 16 + c]);
    den += ex0;
    float val = acc / (den + 1e-16f) + b2[c];
    float m = val;
#pragma unroll
    for (int o = 1; o < 16; o <<= 1) m = fmaxf(m, __shfl_xor(m, o));
    float s = expf(val - m);
#pragma unroll
    for (int o = 1; o < 16; o <<= 1) s += __shfl_xor(s, o);
    out[(size_t)d * 16 + c] = val - (m + logf(s));
  }
}

extern "C" void kernel_launch(void* const* d_in, const int* in_sizes, int n_in,
                              void* d_out, int out_size, void* d_ws, size_t ws_size,
                              hipStream_t stream) {
  const float* x    = (const float*)d_in[0];
  const int*   ei   = (const int*)d_in[1];
  const float* W1   = (const float*)d_in[2];
  const float* a1s  = (const float*)d_in[3];
  const float* a1d  = (const float*)d_in[4];
  const float* b1   = (const float*)d_in[5];
  const float* W2   = (const float*)d_in[6];
  const float* a2s  = (const float*)d_in[7];
  const float* a2d  = (const float*)d_in[8];
  const float* b2   = (const float*)d_in[9];
  float* out = (float*)d_out;

  const int N = in_sizes[0] / 512;
  const int E = in_sizes[1] / 2;
  const int* src = ei;
  const int* dst = ei + E;
  const int B = (N + BKT_RANGE - 1) >> BKT_SHIFT;
  const int EB = (E + EPB - 1) / EPB;

  float* w = (float*)d_ws;
  float* ef1s = w;  w += (size_t)N * 16;
  float* ef1d = w;  w += (size_t)N * 16;
  float* ef2s = w;  w += (size_t)N * 2;
  float* ef2d = w;  w += (size_t)N * 2;
  unsigned short* h1b = (unsigned short*)w;  w += (size_t)N * 32;
  unsigned short* h2b = (unsigned short*)w;  w += (size_t)N * 8;
  unsigned short* Wt  = (unsigned short*)w;  w += 512 * 64 / 2;
  int* iw = (int*)w;
  int* deg         = iw;  iw += N;
  int* rowptr      = iw;  iw += N;
  int* bucketCount = iw;  iw += 1024;
  int* bucketOff   = iw;  iw += 1024;
  int* gCursor     = iw;  iw += 1024;
  int* srt         = iw;  iw += E;
  unsigned* binned = (unsigned*)iw;  iw += E;

  // CSR build via bucketed counting sort
  k_zero<<<2, 512, 0, stream>>>(bucketCount, 1024);
  k_bhist<<<EB, 256, 0, stream>>>(dst, bucketCount, E, B);
  k_bscan<<<1, 512, 0, stream>>>(bucketCount, bucketOff, gCursor, B, E);
  k_bin<<<EB, 256, 0, stream>>>(src, dst, gCursor, binned, E, B);
  k_build<<<B, 256, 0, stream>>>(bucketOff, binned, rowptr, deg, srt, N);

  // Layer 1 (+ fused layer-2 node work)
  k_cvtW<<<(512 * 64 + 255) / 256, 256, 0, stream>>>(W1, Wt);
  k_gemm1_mfma<<<(N + 127) / 128, 256, 0, stream>>>(x, Wt, h1b, N);
  k_alpha1<<<(N * 8 + 255) / 256, 256, 0, stream>>>(h1b, a1s, a1d, ef1s, ef1d, N);
  k_agg1f<<<(N + 3) / 4, 256, 0, stream>>>(rowptr, deg, srt, ef1s, ef1d, h1b,
                                           b1, W2, a2s, a2d, h2b, ef2s, ef2d, N);

  // Layer 2
  k_agg2<<<(int)(((size_t)N * 64 + 255) / 256), 256, 0, stream>>>(rowptr, deg, srt, ef2s, ef2d, h2b, b2, out, N);
}

// Round 8
// 253.302 us; speedup vs baseline: 5.2776x; 1.1142x over previous
//
#include <hip/hip_runtime.h>
#include <math.h>

#define NEG_SLOPE 0.2f
#define BKT_SHIFT 8                 // 256 dst nodes per bucket
#define BKT_RANGE 256
#define EPB 4096                    // edges per block in binning kernels

typedef __attribute__((ext_vector_type(8))) short bf16x8;
typedef __attribute__((ext_vector_type(4))) float f32x4;

__device__ __forceinline__ float elu1(float x)  { return x > 0.f ? x : expm1f(x); }

__device__ __forceinline__ unsigned short f2bf(float f) {
  unsigned u = __float_as_uint(f);
  unsigned r = (u + 0x7FFFu + ((u >> 16) & 1u)) >> 16;
  return (unsigned short)r;
}
__device__ __forceinline__ float bf2f(unsigned short s) {
  return __uint_as_float((unsigned)s << 16);
}
__device__ __forceinline__ float bflo(unsigned u) { return __uint_as_float(u << 16); }
__device__ __forceinline__ float bfhi(unsigned u) { return __uint_as_float(u & 0xFFFF0000u); }
// HW packed f32->bf16 (RNE)
__device__ __forceinline__ unsigned cvt_pk_bf16(float lo, float hi) {
  unsigned r;
  asm("v_cvt_pk_bf16_f32 %0, %1, %2" : "=v"(r) : "v"(lo), "v"(hi));
  return r;
}

// ---------------- K0: Wt[c][k] = bf16(W1[k][c]) ----------------
__global__ __launch_bounds__(256) void k_cvtW(const float* __restrict__ W,
                                              unsigned short* __restrict__ Wt) {
  int i = blockIdx.x * 256 + threadIdx.x;  // i = k*64 + c
  if (i >= 512 * 64) return;
  int k = i >> 6, c = i & 63;
  Wt[(size_t)c * 512 + k] = f2bf(W[i]);
}

// ---------------- K1: h1b = bf16(x @ W1) via MFMA ----------------
__global__ __launch_bounds__(256) void k_gemm1_mfma(const float* __restrict__ x,
                                                    const unsigned short* __restrict__ Wt,
                                                    unsigned short* __restrict__ h1b, int N) {
  __shared__ unsigned short As[128 * 64];
  __shared__ unsigned short Bs[64 * 64];
  const int t = threadIdx.x;
  const int w = t >> 6;
  const int l = t & 63;
  const int fr = l & 15;
  const int fq = l >> 4;
  const int rowbase = blockIdx.x * 128;
  f32x4 acc[2][4] = {};

  for (int k0 = 0; k0 < 512; k0 += 64) {
#pragma unroll
    for (int j = 0; j < 8; ++j) {
      int idx = j * 256 + t;
      int row = idx >> 4;
      int cg  = idx & 15;
      int grow = rowbase + row;
      float4 v = make_float4(0.f, 0.f, 0.f, 0.f);
      if (grow < N) v = *(const float4*)(x + (size_t)grow * 512 + k0 + cg * 4);
      uint2 pk;
      pk.x = cvt_pk_bf16(v.x, v.y);
      pk.y = cvt_pk_bf16(v.z, v.w);
      int ch = cg >> 1;
      int pch = ch ^ (row & 7);
      *((uint2*)(As + row * 64 + pch * 8 + (cg & 1) * 4)) = pk;
    }
#pragma unroll
    for (int rep = 0; rep < 2; ++rep) {
      int i = t + rep * 256;
      int c = i >> 3, ch = i & 7;
      uint4 v = *(const uint4*)(Wt + (size_t)c * 512 + k0 + ch * 8);
      *((uint4*)(Bs + c * 64 + (ch ^ (c & 7)) * 8)) = v;
    }
    __syncthreads();
#pragma unroll
    for (int ks = 0; ks < 2; ++ks) {
      bf16x8 a[2], b[4];
#pragma unroll
      for (int m = 0; m < 2; ++m) {
        int r = w * 32 + m * 16 + fr;
        int ch = (ks * 4 + fq) ^ (r & 7);
        a[m] = *((const bf16x8*)(As + r * 64 + ch * 8));
      }
#pragma unroll
      for (int n = 0; n < 4; ++n) {
        int c = n * 16 + fr;
        int ch = (ks * 4 + fq) ^ (c & 7);
        b[n] = *((const bf16x8*)(Bs + c * 64 + ch * 8));
      }
#pragma unroll
      for (int m = 0; m < 2; ++m)
#pragma unroll
        for (int n = 0; n < 4; ++n)
          acc[m][n] = __builtin_amdgcn_mfma_f32_16x16x32_bf16(a[m], b[n], acc[m][n], 0, 0, 0);
    }
    __syncthreads();
  }
#pragma unroll
  for (int m = 0; m < 2; ++m) {
    int rb = rowbase + w * 32 + m * 16 + fq * 4;
#pragma unroll
    for (int reg = 0; reg < 4; ++reg) {
      int row = rb + reg;
      if (row < N) {
#pragma unroll
        for (int n = 0; n < 4; ++n)
          h1b[(size_t)row * 64 + n * 16 + fr] = f2bf(acc[m][n][reg]);
      }
    }
  }
}

// ---------------- K1b: per-(node,head) factored-exp alpha tables ----------------
__global__ __launch_bounds__(256) void k_alpha1(const unsigned short* __restrict__ h1b,
                                                const float* __restrict__ a1s,
                                                const float* __restrict__ a1d,
                                                float* __restrict__ ef1s,
                                                float* __restrict__ ef1d, int N) {
  int idx = blockIdx.x * blockDim.x + threadIdx.x;  // n*8 + h
  if (idx >= N * 8) return;
  int h = idx & 7;
  uint4 raw = *(const uint4*)(h1b + (size_t)idx * 8);
  float v[8];
  v[0] = bflo(raw.x); v[1] = bfhi(raw.x);
  v[2] = bflo(raw.y); v[3] = bfhi(raw.y);
  v[4] = bflo(raw.z); v[5] = bfhi(raw.z);
  v[6] = bflo(raw.w); v[7] = bfhi(raw.w);
  const float* s_ = a1s + h * 8;
  const float* d_ = a1d + h * 8;
  float ss = 0.f, dd = 0.f;
#pragma unroll
  for (int j = 0; j < 8; ++j) { ss += v[j] * s_[j]; dd += v[j] * d_[j]; }
  *(float2*)(ef1s + (size_t)idx * 2) = make_float2(expf(ss), expf(NEG_SLOPE * ss));
  *(float2*)(ef1d + (size_t)idx * 2) = make_float2(expf(dd), expf(NEG_SLOPE * dd));
}

// ---------------- CSR build: two-level bucketed counting sort ----------------
__global__ __launch_bounds__(512) void k_zero(int* __restrict__ p, int n) {
  int i = blockIdx.x * blockDim.x + threadIdx.x;
  if (i < n) p[i] = 0;
}

__global__ __launch_bounds__(256) void k_bhist(const int* __restrict__ dst,
                                               int* __restrict__ bucketCount,
                                               int E, int B) {
  __shared__ int h[512];
  int t = threadIdx.x;
  for (int i = t; i < B; i += 256) h[i] = 0;
  __syncthreads();
  int e0 = blockIdx.x * EPB;
#pragma unroll
  for (int i = 0; i < EPB / 256; ++i) {
    int e = e0 + i * 256 + t;
    if (e < E) atomicAdd(&h[dst[e] >> BKT_SHIFT], 1);
  }
  __syncthreads();
  for (int i = t; i < B; i += 256)
    if (h[i]) atomicAdd(bucketCount + i, h[i]);
}

__global__ __launch_bounds__(512) void k_bscan(const int* __restrict__ bucketCount,
                                               int* __restrict__ bucketOff,
                                               int* __restrict__ gCursor, int B, int E) {
  __shared__ int sm[512];
  int t = threadIdx.x;
  int v = (t < B) ? bucketCount[t] : 0;
  sm[t] = v;
  __syncthreads();
  int acc = v;
#pragma unroll
  for (int o = 1; o < 512; o <<= 1) {
    int u = (t >= o) ? sm[t - o] : 0;
    __syncthreads();
    acc += u;
    sm[t] = acc;
    __syncthreads();
  }
  if (t < B) {
    bucketOff[t] = acc - v;
    gCursor[t] = acc - v;
  }
  if (t == 0) bucketOff[B] = E;
}

__global__ __launch_bounds__(256) void k_bin(const int* __restrict__ src,
                                             const int* __restrict__ dst,
                                             int* __restrict__ gCursor,
                                             unsigned* __restrict__ binned,
                                             int E, int B) {
  __shared__ int hist[512];
  __shared__ int base[512];
  int t = threadIdx.x;
  for (int i = t; i < B; i += 256) hist[i] = 0;
  __syncthreads();
  int e0 = blockIdx.x * EPB;
#pragma unroll
  for (int i = 0; i < EPB / 256; ++i) {
    int e = e0 + i * 256 + t;
    if (e < E) atomicAdd(&hist[dst[e] >> BKT_SHIFT], 1);
  }
  __syncthreads();
  for (int i = t; i < B; i += 256) {
    int c = hist[i];
    base[i] = c ? atomicAdd(gCursor + i, c) : 0;
    hist[i] = 0;
  }
  __syncthreads();
#pragma unroll
  for (int i = 0; i < EPB / 256; ++i) {
    int e = e0 + i * 256 + t;
    if (e < E) {
      int d = dst[e];
      int b = d >> BKT_SHIFT;
      int r = atomicAdd(&hist[b], 1);
      binned[base[b] + r] = ((unsigned)(d & (BKT_RANGE - 1)) << 24) | (unsigned)src[e];
    }
  }
}

__global__ __launch_bounds__(256) void k_build(const int* __restrict__ bucketOff,
                                               const unsigned* __restrict__ binned,
                                               int* __restrict__ rowptr,
                                               int* __restrict__ deg,
                                               int* __restrict__ srt, int N) {
  __shared__ int ldeg[BKT_RANGE];
  __shared__ int sm[BKT_RANGE];
  __shared__ int lcur[BKT_RANGE];
  int t = threadIdx.x;
  int b = blockIdx.x;
  int nbase = b * BKT_RANGE;
  int estart = bucketOff[b];
  int eend = bucketOff[b + 1];
  ldeg[t] = 0;
  __syncthreads();
  for (int e = estart + t; e < eend; e += 256)
    atomicAdd(&ldeg[binned[e] >> 24], 1);
  __syncthreads();
  int v = ldeg[t];
  sm[t] = v;
  __syncthreads();
  int acc = v;
#pragma unroll
  for (int o = 1; o < 256; o <<= 1) {
    int u = (t >= o) ? sm[t - o] : 0;
    __syncthreads();
    acc += u;
    sm[t] = acc;
    __syncthreads();
  }
  int excl = estart + acc - v;
  int node = nbase + t;
  if (node < N) {
    rowptr[node] = excl;
    deg[node] = v;
  }
  lcur[t] = excl;
  __syncthreads();
  for (int e = estart + t; e < eend; e += 256) {
    unsigned p = binned[e];
    int pos = atomicAdd(&lcur[p >> 24], 1);
    srt[pos] = (int)(p & 0xFFFFFFu);
  }
}

// ---------------- K agg1f: gather-reduce L1 + fused L2 node work ----------------
// wave per dst; lane = (slot = lane>>4, c4 = lane&15); each lane: 4 channels
// 4*c4..4*c4+3 (head h = c4>>1), 4 edges in flight (one per slot).
__global__ __launch_bounds__(256) void k_agg1f(const int* __restrict__ rowptr,
                                               const int* __restrict__ deg,
                                               const int* __restrict__ srt,
                                               const float* __restrict__ ef1s,
                                               const float* __restrict__ ef1d,
                                               const unsigned short* __restrict__ h1b,
                                               const float* __restrict__ b1,
                                               const float* __restrict__ W2,
                                               const float* __restrict__ a2s,
                                               const float* __restrict__ a2d,
                                               unsigned short* __restrict__ h2b,
                                               float* __restrict__ ef2s,
                                               float* __restrict__ ef2d, int N) {
  __shared__ float vsm[4][64];
  const int t = threadIdx.x;
  const int w = t >> 6;
  const int lane = t & 63;
  const int wid = blockIdx.x * 4 + w;
  const int slot = lane >> 4;
  const int c4 = lane & 15;
  const int h = c4 >> 1;
  // per-lane constants for the fused matvec (c = c4, jj = slot)
  float a2sr = a2s[c4];
  float a2dr = a2d[c4];
  float wreg[16];
#pragma unroll
  for (int m = 0; m < 16; ++m) wreg[m] = W2[(slot * 16 + m) * 16 + c4];
  float4 b1v = *(const float4*)(b1 + c4 * 4);
  if (wid >= N) return;
  const int d = wid;

  float2 ddv = *(const float2*)(ef1d + (size_t)d * 16 + h * 2);  // {ead, fad}
  // self loop (slot 0 only)
  float2 psv = *(const float2*)(ef1s + (size_t)d * 16 + h * 2);
  uint2 sv = *(const uint2*)(h1b + (size_t)d * 64 + c4 * 4);
  float ex0 = fmaxf(psv.x * ddv.x, psv.y * ddv.y);
  ex0 = (slot == 0) ? ex0 : 0.f;
  float a0 = ex0 * bflo(sv.x), a1 = ex0 * bfhi(sv.x);
  float a2 = ex0 * bflo(sv.y), a3 = ex0 * bfhi(sv.y);
  float den = ex0;

  int start = rowptr[d];
  int len = deg[d];
  for (int k = 0; k < len; k += 4) {
    int idx = k + slot;
    bool valid = idx < len;
    int s = d;
    if (valid) s = srt[start + idx];
    float2 p = *(const float2*)(ef1s + (size_t)s * 16 + h * 2);
    uint2 hv = *(const uint2*)(h1b + (size_t)s * 64 + c4 * 4);
    float ex = fmaxf(p.x * ddv.x, p.y * ddv.y);
    ex = valid ? ex : 0.f;
    a0 = fmaf(ex, bflo(hv.x), a0);
    a1 = fmaf(ex, bfhi(hv.x), a1);
    a2 = fmaf(ex, bflo(hv.y), a2);
    a3 = fmaf(ex, bfhi(hv.y), a3);
    den += ex;
  }
  // reduce across slots (lane bits 4,5)
#pragma unroll
  for (int o = 16; o < 64; o <<= 1) {
    a0 += __shfl_xor(a0, o);
    a1 += __shfl_xor(a1, o);
    a2 += __shfl_xor(a2, o);
    a3 += __shfl_xor(a3, o);
    den += __shfl_xor(den, o);
  }
  float rden = 1.f / (den + 1e-16f);
  // ---- fused layer-2 node work ----
  if (slot == 0) {
    float4 vv;
    vv.x = elu1(a0 * rden + b1v.x);
    vv.y = elu1(a1 * rden + b1v.y);
    vv.z = elu1(a2 * rden + b1v.z);
    vv.w = elu1(a3 * rden + b1v.w);
    *(float4*)&vsm[w][c4 * 4] = vv;
  }
  float partial = 0.f;
#pragma unroll
  for (int m = 0; m < 16; ++m) partial = fmaf(vsm[w][slot * 16 + m], wreg[m], partial);
  float qs = partial * a2sr;
  float qd = partial * a2dr;
#pragma unroll
  for (int o = 1; o < 64; o <<= 1) {
    qs += __shfl_xor(qs, o);
    qd += __shfl_xor(qd, o);
  }
  float p2 = partial + __shfl_down(partial, 32);
  float hcv = p2 + __shfl_down(p2, 16);
  if (lane < 16) h2b[(size_t)d * 16 + c4] = f2bf(hcv);
  if (lane == 0) {
    *(float2*)(ef2s + (size_t)d * 2) = make_float2(expf(qs), expf(NEG_SLOPE * qs));
    *(float2*)(ef2d + (size_t)d * 2) = make_float2(expf(qd), expf(NEG_SLOPE * qd));
  }
}

// ---------------- K agg2: gather-reduce layer 2 + b2 + log_softmax ----------------
// wave per dst; lane = (slot = lane>>2, cg = lane&3); lane: channels 4*cg..4*cg+3;
// 16 edges in flight.
__global__ __launch_bounds__(256) void k_agg2(const int* __restrict__ rowptr,
                                              const int* __restrict__ deg,
                                              const int* __restrict__ srt,
                                              const float* __restrict__ ef2s,
                                              const float* __restrict__ ef2d,
                                              const unsigned short* __restrict__ h2b,
                                              const float* __restrict__ b2,
                                              float* __restrict__ out, int N) {
  const int t = threadIdx.x;
  const int lane = t & 63;
  const int wid = (blockIdx.x * 256 + t) >> 6;
  const int slot = lane >> 2;
  const int cg = lane & 3;
  float4 b2v = *(const float4*)(b2 + cg * 4);
  if (wid >= N) return;
  const int d = wid;
  float2 ddp = *(const float2*)(ef2d + (size_t)d * 2);
  // self loop (slot 0)
  float2 ps0 = *(const float2*)(ef2s + (size_t)d * 2);
  uint2 sv = *(const uint2*)(h2b + (size_t)d * 16 + cg * 4);
  float ex0 = fmaxf(ps0.x * ddp.x, ps0.y * ddp.y);
  ex0 = (slot == 0) ? ex0 : 0.f;
  float a0 = ex0 * bflo(sv.x), a1 = ex0 * bfhi(sv.x);
  float a2 = ex0 * bflo(sv.y), a3 = ex0 * bfhi(sv.y);
  float den = ex0;

  int start = rowptr[d];
  int len = deg[d];
  for (int k = 0; k < len; k += 16) {
    int idx = k + slot;
    bool valid = idx < len;
    int s = d;
    if (valid) s = srt[start + idx];
    float2 p = *(const float2*)(ef2s + (size_t)s * 2);
    uint2 hv = *(const uint2*)(h2b + (size_t)s * 16 + cg * 4);
    float ex = fmaxf(p.x * ddp.x, p.y * ddp.y);
    ex = valid ? ex : 0.f;
    a0 = fmaf(ex, bflo(hv.x), a0);
    a1 = fmaf(ex, bfhi(hv.x), a1);
    a2 = fmaf(ex, bflo(hv.y), a2);
    a3 = fmaf(ex, bfhi(hv.y), a3);
    den += ex;
  }
  // reduce across slots (lane bits 2..5)
#pragma unroll
  for (int o = 4; o < 64; o <<= 1) {
    a0 += __shfl_xor(a0, o);
    a1 += __shfl_xor(a1, o);
    a2 += __shfl_xor(a2, o);
    a3 += __shfl_xor(a3, o);
    den += __shfl_xor(den, o);
  }
  float rden = 1.f / (den + 1e-16f);
  float v0 = a0 * rden + b2v.x;
  float v1 = a1 * rden + b2v.y;
  float v2 = a2 * rden + b2v.z;
  float v3 = a3 * rden + b2v.w;
  // log_softmax over 16 channels spread across 4-lane groups (lane bits 0,1)
  float m = fmaxf(fmaxf(v0, v1), fmaxf(v2, v3));
  m = fmaxf(m, __shfl_xor(m, 1));
  m = fmaxf(m, __shfl_xor(m, 2));
  float s = expf(v0 - m) + expf(v1 - m) + expf(v2 - m) + expf(v3 - m);
  s += __shfl_xor(s, 1);
  s += __shfl_xor(s, 2);
  float lse = m + logf(s);
  if (lane < 4) {
    float4 o4 = make_float4(v0 - lse, v1 - lse, v2 - lse, v3 - lse);
    *(float4*)(out + (size_t)d * 16 + cg * 4) = o4;
  }
}

extern "C" void kernel_launch(void* const* d_in, const int* in_sizes, int n_in,
                              void* d_out, int out_size, void* d_ws, size_t ws_size,
                              hipStream_t stream) {
  const float* x    = (const float*)d_in[0];
  const int*   ei   = (const int*)d_in[1];
  const float* W1   = (const float*)d_in[2];
  const float* a1s  = (const float*)d_in[3];
  const float* a1d  = (const float*)d_in[4];
  const float* b1   = (const float*)d_in[5];
  const float* W2   = (const float*)d_in[6];
  const float* a2s  = (const float*)d_in[7];
  const float* a2d  = (const float*)d_in[8];
  const float* b2   = (const float*)d_in[9];
  float* out = (float*)d_out;

  const int N = in_sizes[0] / 512;
  const int E = in_sizes[1] / 2;
  const int* src = ei;
  const int* dst = ei + E;
  const int B = (N + BKT_RANGE - 1) >> BKT_SHIFT;
  const int EB = (E + EPB - 1) / EPB;

  float* w = (float*)d_ws;
  float* ef1s = w;  w += (size_t)N * 16;
  float* ef1d = w;  w += (size_t)N * 16;
  float* ef2s = w;  w += (size_t)N * 2;
  float* ef2d = w;  w += (size_t)N * 2;
  unsigned short* h1b = (unsigned short*)w;  w += (size_t)N * 32;
  unsigned short* h2b = (unsigned short*)w;  w += (size_t)N * 8;
  unsigned short* Wt  = (unsigned short*)w;  w += 512 * 64 / 2;
  int* iw = (int*)w;
  int* deg         = iw;  iw += N;
  int* rowptr      = iw;  iw += N;
  int* bucketCount = iw;  iw += 1024;
  int* bucketOff   = iw;  iw += 1024;
  int* gCursor     = iw;  iw += 1024;
  int* srt         = iw;  iw += E;
  unsigned* binned = (unsigned*)iw;  iw += E;

  // CSR build via bucketed counting sort
  k_zero<<<2, 512, 0, stream>>>(bucketCount, 1024);
  k_bhist<<<EB, 256, 0, stream>>>(dst, bucketCount, E, B);
  k_bscan<<<1, 512, 0, stream>>>(bucketCount, bucketOff, gCursor, B, E);
  k_bin<<<EB, 256, 0, stream>>>(src, dst, gCursor, binned, E, B);
  k_build<<<B, 256, 0, stream>>>(bucketOff, binned, rowptr, deg, srt, N);

  // Layer 1 (+ fused layer-2 node work)
  k_cvtW<<<(512 * 64 + 255) / 256, 256, 0, stream>>>(W1, Wt);
  k_gemm1_mfma<<<(N + 127) / 128, 256, 0, stream>>>(x, Wt, h1b, N);
  k_alpha1<<<(N * 8 + 255) / 256, 256, 0, stream>>>(h1b, a1s, a1d, ef1s, ef1d, N);
  k_agg1f<<<(N + 3) / 4, 256, 0, stream>>>(rowptr, deg, srt, ef1s, ef1d, h1b,
                                           b1, W2, a2s, a2d, h2b, ef2s, ef2d, N);

  // Layer 2
  k_agg2<<<(N + 3) / 4, 256, 0, stream>>>(rowptr, deg, srt, ef2s, ef2d, h2b, b2, out, N);
}

// Round 9
// 242.294 us; speedup vs baseline: 5.5174x; 1.0454x over previous
//
#include <hip/hip_runtime.h>
#include <math.h>

#define NEG_SLOPE 0.2f
#define BKT_SHIFT 8                 // 256 dst nodes per bucket
#define BKT_RANGE 256
#define EPB 4096                    // edges per block in binning kernels

typedef __attribute__((ext_vector_type(8))) short bf16x8;
typedef __attribute__((ext_vector_type(4))) float f32x4;

__device__ __forceinline__ float elu1(float x)  { return x > 0.f ? x : expm1f(x); }

__device__ __forceinline__ unsigned short f2bf(float f) {
  unsigned u = __float_as_uint(f);
  unsigned r = (u + 0x7FFFu + ((u >> 16) & 1u)) >> 16;
  return (unsigned short)r;
}
__device__ __forceinline__ float bflo(unsigned u) { return __uint_as_float(u << 16); }
__device__ __forceinline__ float bfhi(unsigned u) { return __uint_as_float(u & 0xFFFF0000u); }
// HW packed f32->bf16 (RNE)
__device__ __forceinline__ unsigned cvt_pk_bf16(float lo, float hi) {
  unsigned r;
  asm("v_cvt_pk_bf16_f32 %0, %1, %2" : "=v"(r) : "v"(lo), "v"(hi));
  return r;
}

// ---------------- K0: Wt[c][k] = bf16(W1[k][c])  + zero bucketCount ----------------
__global__ __launch_bounds__(256) void k_cvtW_zero(const float* __restrict__ W,
                                                   unsigned short* __restrict__ Wt,
                                                   int* __restrict__ bucketCount) {
  int i = blockIdx.x * 256 + threadIdx.x;  // i = k*64 + c
  if (i < 1024) bucketCount[i] = 0;
  if (i >= 512 * 64) return;
  int k = i >> 6, c = i & 63;
  Wt[(size_t)c * 512 + k] = f2bf(W[i]);
}

// ---------------- K1: h1b = bf16(x @ W1) via MFMA ----------------
__global__ __launch_bounds__(256) void k_gemm1_mfma(const float* __restrict__ x,
                                                    const unsigned short* __restrict__ Wt,
                                                    unsigned short* __restrict__ h1b, int N) {
  __shared__ unsigned short As[128 * 64];
  __shared__ unsigned short Bs[64 * 64];
  const int t = threadIdx.x;
  const int w = t >> 6;
  const int l = t & 63;
  const int fr = l & 15;
  const int fq = l >> 4;
  const int rowbase = blockIdx.x * 128;
  f32x4 acc[2][4] = {};

  for (int k0 = 0; k0 < 512; k0 += 64) {
#pragma unroll
    for (int j = 0; j < 8; ++j) {
      int idx = j * 256 + t;
      int row = idx >> 4;
      int cg  = idx & 15;
      int grow = rowbase + row;
      float4 v = make_float4(0.f, 0.f, 0.f, 0.f);
      if (grow < N) v = *(const float4*)(x + (size_t)grow * 512 + k0 + cg * 4);
      uint2 pk;
      pk.x = cvt_pk_bf16(v.x, v.y);
      pk.y = cvt_pk_bf16(v.z, v.w);
      int ch = cg >> 1;
      int pch = ch ^ (row & 7);
      *((uint2*)(As + row * 64 + pch * 8 + (cg & 1) * 4)) = pk;
    }
#pragma unroll
    for (int rep = 0; rep < 2; ++rep) {
      int i = t + rep * 256;
      int c = i >> 3, ch = i & 7;
      uint4 v = *(const uint4*)(Wt + (size_t)c * 512 + k0 + ch * 8);
      *((uint4*)(Bs + c * 64 + (ch ^ (c & 7)) * 8)) = v;
    }
    __syncthreads();
#pragma unroll
    for (int ks = 0; ks < 2; ++ks) {
      bf16x8 a[2], b[4];
#pragma unroll
      for (int m = 0; m < 2; ++m) {
        int r = w * 32 + m * 16 + fr;
        int ch = (ks * 4 + fq) ^ (r & 7);
        a[m] = *((const bf16x8*)(As + r * 64 + ch * 8));
      }
#pragma unroll
      for (int n = 0; n < 4; ++n) {
        int c = n * 16 + fr;
        int ch = (ks * 4 + fq) ^ (c & 7);
        b[n] = *((const bf16x8*)(Bs + c * 64 + ch * 8));
      }
#pragma unroll
      for (int m = 0; m < 2; ++m)
#pragma unroll
        for (int n = 0; n < 4; ++n)
          acc[m][n] = __builtin_amdgcn_mfma_f32_16x16x32_bf16(a[m], b[n], acc[m][n], 0, 0, 0);
    }
    __syncthreads();
  }
#pragma unroll
  for (int m = 0; m < 2; ++m) {
    int rb = rowbase + w * 32 + m * 16 + fq * 4;
#pragma unroll
    for (int reg = 0; reg < 4; ++reg) {
      int row = rb + reg;
      if (row < N) {
#pragma unroll
        for (int n = 0; n < 4; ++n)
          h1b[(size_t)row * 64 + n * 16 + fr] = f2bf(acc[m][n][reg]);
      }
    }
  }
}

// ---------------- K1b: alpha tables (packed bf16) + fp8 copy of h1 ----------------
// thread = (n, h): reads 8 bf16 channels, writes ef1sp (u32 = 2xbf16), ef1d (f32x2),
// and h1f8 chunk (8 channels -> 2 u32 of fp8 e4m3).
__global__ __launch_bounds__(256) void k_alpha1(const unsigned short* __restrict__ h1b,
                                                const float* __restrict__ a1s,
                                                const float* __restrict__ a1d,
                                                unsigned* __restrict__ ef1sp,
                                                float* __restrict__ ef1d,
                                                unsigned* __restrict__ h1f8, int N) {
  int idx = blockIdx.x * blockDim.x + threadIdx.x;  // n*8 + h
  if (idx >= N * 8) return;
  int h = idx & 7;
  uint4 raw = *(const uint4*)(h1b + (size_t)idx * 8);
  float v[8];
  v[0] = bflo(raw.x); v[1] = bfhi(raw.x);
  v[2] = bflo(raw.y); v[3] = bfhi(raw.y);
  v[4] = bflo(raw.z); v[5] = bfhi(raw.z);
  v[6] = bflo(raw.w); v[7] = bfhi(raw.w);
  const float* s_ = a1s + h * 8;
  const float* d_ = a1d + h * 8;
  float ss = 0.f, dd = 0.f;
#pragma unroll
  for (int j = 0; j < 8; ++j) { ss += v[j] * s_[j]; dd += v[j] * d_[j]; }
  ef1sp[idx] = cvt_pk_bf16(expf(ss), expf(NEG_SLOPE * ss));
  *(float2*)(ef1d + (size_t)idx * 2) = make_float2(expf(dd), expf(NEG_SLOPE * dd));
  // fp8 pack: 8 channels -> 2 u32
  unsigned lo = 0, hi = 0;
  lo = __builtin_amdgcn_cvt_pk_fp8_f32(v[0], v[1], lo, 0);
  lo = __builtin_amdgcn_cvt_pk_fp8_f32(v[2], v[3], lo, 1);
  hi = __builtin_amdgcn_cvt_pk_fp8_f32(v[4], v[5], hi, 0);
  hi = __builtin_amdgcn_cvt_pk_fp8_f32(v[6], v[7], hi, 1);
  *(uint2*)(h1f8 + (size_t)idx * 2) = make_uint2(lo, hi);
}

// ---------------- CSR build: two-level bucketed counting sort ----------------
__global__ __launch_bounds__(256) void k_bhist(const int* __restrict__ dst,
                                               int* __restrict__ bucketCount,
                                               int E, int B) {
  __shared__ int h[512];
  int t = threadIdx.x;
  for (int i = t; i < B; i += 256) h[i] = 0;
  __syncthreads();
  int e0 = blockIdx.x * EPB;
#pragma unroll
  for (int i = 0; i < EPB / 256; ++i) {
    int e = e0 + i * 256 + t;
    if (e < E) atomicAdd(&h[dst[e] >> BKT_SHIFT], 1);
  }
  __syncthreads();
  for (int i = t; i < B; i += 256)
    if (h[i]) atomicAdd(bucketCount + i, h[i]);
}

__global__ __launch_bounds__(512) void k_bscan(const int* __restrict__ bucketCount,
                                               int* __restrict__ bucketOff,
                                               int* __restrict__ gCursor, int B, int E) {
  __shared__ int sm[512];
  int t = threadIdx.x;
  int v = (t < B) ? bucketCount[t] : 0;
  sm[t] = v;
  __syncthreads();
  int acc = v;
#pragma unroll
  for (int o = 1; o < 512; o <<= 1) {
    int u = (t >= o) ? sm[t - o] : 0;
    __syncthreads();
    acc += u;
    sm[t] = acc;
    __syncthreads();
  }
  if (t < B) {
    bucketOff[t] = acc - v;
    gCursor[t] = acc - v;
  }
  if (t == 0) bucketOff[B] = E;
}

__global__ __launch_bounds__(256) void k_bin(const int* __restrict__ src,
                                             const int* __restrict__ dst,
                                             int* __restrict__ gCursor,
                                             unsigned* __restrict__ binned,
                                             int E, int B) {
  __shared__ int hist[512];
  __shared__ int base[512];
  int t = threadIdx.x;
  for (int i = t; i < B; i += 256) hist[i] = 0;
  __syncthreads();
  int e0 = blockIdx.x * EPB;
#pragma unroll
  for (int i = 0; i < EPB / 256; ++i) {
    int e = e0 + i * 256 + t;
    if (e < E) atomicAdd(&hist[dst[e] >> BKT_SHIFT], 1);
  }
  __syncthreads();
  for (int i = t; i < B; i += 256) {
    int c = hist[i];
    base[i] = c ? atomicAdd(gCursor + i, c) : 0;
    hist[i] = 0;
  }
  __syncthreads();
#pragma unroll
  for (int i = 0; i < EPB / 256; ++i) {
    int e = e0 + i * 256 + t;
    if (e < E) {
      int d = dst[e];
      int b = d >> BKT_SHIFT;
      int r = atomicAdd(&hist[b], 1);
      binned[base[b] + r] = ((unsigned)(d & (BKT_RANGE - 1)) << 24) | (unsigned)src[e];
    }
  }
}

__global__ __launch_bounds__(256) void k_build(const int* __restrict__ bucketOff,
                                               const unsigned* __restrict__ binned,
                                               int* __restrict__ rowptr,
                                               int* __restrict__ deg,
                                               int* __restrict__ srt, int N) {
  __shared__ int ldeg[BKT_RANGE];
  __shared__ int sm[BKT_RANGE];
  __shared__ int lcur[BKT_RANGE];
  int t = threadIdx.x;
  int b = blockIdx.x;
  int nbase = b * BKT_RANGE;
  int estart = bucketOff[b];
  int eend = bucketOff[b + 1];
  ldeg[t] = 0;
  __syncthreads();
  for (int e = estart + t; e < eend; e += 256)
    atomicAdd(&ldeg[binned[e] >> 24], 1);
  __syncthreads();
  int v = ldeg[t];
  sm[t] = v;
  __syncthreads();
  int acc = v;
#pragma unroll
  for (int o = 1; o < 256; o <<= 1) {
    int u = (t >= o) ? sm[t - o] : 0;
    __syncthreads();
    acc += u;
    sm[t] = acc;
    __syncthreads();
  }
  int excl = estart + acc - v;
  int node = nbase + t;
  if (node < N) {
    rowptr[node] = excl;
    deg[node] = v;
  }
  lcur[t] = excl;
  __syncthreads();
  for (int e = estart + t; e < eend; e += 256) {
    unsigned p = binned[e];
    int pos = atomicAdd(&lcur[p >> 24], 1);
    srt[pos] = (int)(p & 0xFFFFFFu);
  }
}

// ---------------- K agg1f: gather-reduce L1 (fp8 payload) + fused L2 node work ----------------
// wave per dst; lane = (slot = lane>>4, c4 = lane&15); lane: channels 4*c4..4*c4+3
// (head h = c4>>1), 4 edges in flight.
__global__ __launch_bounds__(256) void k_agg1f(const int* __restrict__ rowptr,
                                               const int* __restrict__ deg,
                                               const int* __restrict__ srt,
                                               const unsigned* __restrict__ ef1sp,
                                               const float* __restrict__ ef1d,
                                               const unsigned* __restrict__ h1f8,
                                               const float* __restrict__ b1,
                                               const float* __restrict__ W2,
                                               const float* __restrict__ a2s,
                                               const float* __restrict__ a2d,
                                               unsigned short* __restrict__ h2b,
                                               unsigned* __restrict__ ef2sp,
                                               float* __restrict__ ef2d, int N) {
  __shared__ float vsm[4][64];
  const int t = threadIdx.x;
  const int w = t >> 6;
  const int lane = t & 63;
  const int wid = blockIdx.x * 4 + w;
  const int slot = lane >> 4;
  const int c4 = lane & 15;
  const int h = c4 >> 1;
  float a2sr = a2s[c4];
  float a2dr = a2d[c4];
  float wreg[16];
#pragma unroll
  for (int m = 0; m < 16; ++m) wreg[m] = W2[(slot * 16 + m) * 16 + c4];
  float4 b1v = *(const float4*)(b1 + c4 * 4);
  if (wid >= N) return;
  const int d = wid;

  float2 ddv = *(const float2*)(ef1d + (size_t)d * 16 + h * 2);  // {ead, fad}
  // self loop (slot 0 only)
  unsigned es0 = ef1sp[(size_t)d * 8 + h];
  unsigned sv = h1f8[(size_t)d * 16 + c4];
  float ex0 = fmaxf(bflo(es0) * ddv.x, bfhi(es0) * ddv.y);
  ex0 = (slot == 0) ? ex0 : 0.f;
  float a0 = ex0 * __builtin_amdgcn_cvt_f32_fp8(sv, 0);
  float a1 = ex0 * __builtin_amdgcn_cvt_f32_fp8(sv, 1);
  float a2 = ex0 * __builtin_amdgcn_cvt_f32_fp8(sv, 2);
  float a3 = ex0 * __builtin_amdgcn_cvt_f32_fp8(sv, 3);
  float den = ex0;

  int start = rowptr[d];
  int len = deg[d];
  for (int k = 0; k < len; k += 4) {
    int idx = k + slot;
    bool valid = idx < len;
    int s = d;
    if (valid) s = srt[start + idx];
    unsigned es = ef1sp[(size_t)s * 8 + h];
    unsigned hv = h1f8[(size_t)s * 16 + c4];
    float ex = fmaxf(bflo(es) * ddv.x, bfhi(es) * ddv.y);
    ex = valid ? ex : 0.f;
    a0 = fmaf(ex, __builtin_amdgcn_cvt_f32_fp8(hv, 0), a0);
    a1 = fmaf(ex, __builtin_amdgcn_cvt_f32_fp8(hv, 1), a1);
    a2 = fmaf(ex, __builtin_amdgcn_cvt_f32_fp8(hv, 2), a2);
    a3 = fmaf(ex, __builtin_amdgcn_cvt_f32_fp8(hv, 3), a3);
    den += ex;
  }
  // reduce across slots (lane bits 4,5)
#pragma unroll
  for (int o = 16; o < 64; o <<= 1) {
    a0 += __shfl_xor(a0, o);
    a1 += __shfl_xor(a1, o);
    a2 += __shfl_xor(a2, o);
    a3 += __shfl_xor(a3, o);
    den += __shfl_xor(den, o);
  }
  float rden = 1.f / (den + 1e-16f);
  // ---- fused layer-2 node work ----
  if (slot == 0) {
    float4 vv;
    vv.x = elu1(a0 * rden + b1v.x);
    vv.y = elu1(a1 * rden + b1v.y);
    vv.z = elu1(a2 * rden + b1v.z);
    vv.w = elu1(a3 * rden + b1v.w);
    *(float4*)&vsm[w][c4 * 4] = vv;
  }
  float partial = 0.f;
#pragma unroll
  for (int m = 0; m < 16; ++m) partial = fmaf(vsm[w][slot * 16 + m], wreg[m], partial);
  float qs = partial * a2sr;
  float qd = partial * a2dr;
#pragma unroll
  for (int o = 1; o < 64; o <<= 1) {
    qs += __shfl_xor(qs, o);
    qd += __shfl_xor(qd, o);
  }
  float p2 = partial + __shfl_down(partial, 32);
  float hcv = p2 + __shfl_down(p2, 16);
  if (lane < 16) h2b[(size_t)d * 16 + c4] = f2bf(hcv);
  if (lane == 0) {
    ef2sp[d] = cvt_pk_bf16(expf(qs), expf(NEG_SLOPE * qs));
    *(float2*)(ef2d + (size_t)d * 2) = make_float2(expf(qd), expf(NEG_SLOPE * qd));
  }
}

// ---------------- K agg2: gather-reduce layer 2 + b2 + log_softmax ----------------
__global__ __launch_bounds__(256) void k_agg2(const int* __restrict__ rowptr,
                                              const int* __restrict__ deg,
                                              const int* __restrict__ srt,
                                              const unsigned* __restrict__ ef2sp,
                                              const float* __restrict__ ef2d,
                                              const unsigned short* __restrict__ h2b,
                                              const float* __restrict__ b2,
                                              float* __restrict__ out, int N) {
  const int t = threadIdx.x;
  const int lane = t & 63;
  const int wid = (blockIdx.x * 256 + t) >> 6;
  const int slot = lane >> 2;
  const int cg = lane & 3;
  float4 b2v = *(const float4*)(b2 + cg * 4);
  if (wid >= N) return;
  const int d = wid;
  float2 ddp = *(const float2*)(ef2d + (size_t)d * 2);
  // self loop (slot 0)
  unsigned ps0 = ef2sp[d];
  uint2 sv = *(const uint2*)(h2b + (size_t)d * 16 + cg * 4);
  float ex0 = fmaxf(bflo(ps0) * ddp.x, bfhi(ps0) * ddp.y);
  ex0 = (slot == 0) ? ex0 : 0.f;
  float a0 = ex0 * bflo(sv.x), a1 = ex0 * bfhi(sv.x);
  float a2 = ex0 * bflo(sv.y), a3 = ex0 * bfhi(sv.y);
  float den = ex0;

  int start = rowptr[d];
  int len = deg[d];
  for (int k = 0; k < len; k += 16) {
    int idx = k + slot;
    bool valid = idx < len;
    int s = d;
    if (valid) s = srt[start + idx];
    unsigned ps = ef2sp[s];
    uint2 hv = *(const uint2*)(h2b + (size_t)s * 16 + cg * 4);
    float ex = fmaxf(bflo(ps) * ddp.x, bfhi(ps) * ddp.y);
    ex = valid ? ex : 0.f;
    a0 = fmaf(ex, bflo(hv.x), a0);
    a1 = fmaf(ex, bfhi(hv.x), a1);
    a2 = fmaf(ex, bflo(hv.y), a2);
    a3 = fmaf(ex, bfhi(hv.y), a3);
    den += ex;
  }
#pragma unroll
  for (int o = 4; o < 64; o <<= 1) {
    a0 += __shfl_xor(a0, o);
    a1 += __shfl_xor(a1, o);
    a2 += __shfl_xor(a2, o);
    a3 += __shfl_xor(a3, o);
    den += __shfl_xor(den, o);
  }
  float rden = 1.f / (den + 1e-16f);
  float v0 = a0 * rden + b2v.x;
  float v1 = a1 * rden + b2v.y;
  float v2 = a2 * rden + b2v.z;
  float v3 = a3 * rden + b2v.w;
  float m = fmaxf(fmaxf(v0, v1), fmaxf(v2, v3));
  m = fmaxf(m, __shfl_xor(m, 1));
  m = fmaxf(m, __shfl_xor(m, 2));
  float s = expf(v0 - m) + expf(v1 - m) + expf(v2 - m) + expf(v3 - m);
  s += __shfl_xor(s, 1);
  s += __shfl_xor(s, 2);
  float lse = m + logf(s);
  if (lane < 4) {
    float4 o4 = make_float4(v0 - lse, v1 - lse, v2 - lse, v3 - lse);
    *(float4*)(out + (size_t)d * 16 + cg * 4) = o4;
  }
}

extern "C" void kernel_launch(void* const* d_in, const int* in_sizes, int n_in,
                              void* d_out, int out_size, void* d_ws, size_t ws_size,
                              hipStream_t stream) {
  const float* x    = (const float*)d_in[0];
  const int*   ei   = (const int*)d_in[1];
  const float* W1   = (const float*)d_in[2];
  const float* a1s  = (const float*)d_in[3];
  const float* a1d  = (const float*)d_in[4];
  const float* b1   = (const float*)d_in[5];
  const float* W2   = (const float*)d_in[6];
  const float* a2s  = (const float*)d_in[7];
  const float* a2d  = (const float*)d_in[8];
  const float* b2   = (const float*)d_in[9];
  float* out = (float*)d_out;

  const int N = in_sizes[0] / 512;
  const int E = in_sizes[1] / 2;
  const int* src = ei;
  const int* dst = ei + E;
  const int B = (N + BKT_RANGE - 1) >> BKT_SHIFT;
  const int EB = (E + EPB - 1) / EPB;

  float* w = (float*)d_ws;
  float* ef1d = w;  w += (size_t)N * 16;
  float* ef2d = w;  w += (size_t)N * 2;
  unsigned* ef1sp = (unsigned*)w;  w += (size_t)N * 8;
  unsigned* ef2sp = (unsigned*)w;  w += (size_t)N;
  unsigned* h1f8  = (unsigned*)w;  w += (size_t)N * 16;
  unsigned short* h1b = (unsigned short*)w;  w += (size_t)N * 32;
  unsigned short* h2b = (unsigned short*)w;  w += (size_t)N * 8;
  unsigned short* Wt  = (unsigned short*)w;  w += 512 * 64 / 2;
  int* iw = (int*)w;
  int* deg         = iw;  iw += N;
  int* rowptr      = iw;  iw += N;
  int* bucketCount = iw;  iw += 1024;
  int* bucketOff   = iw;  iw += 1024;
  int* gCursor     = iw;  iw += 1024;
  int* srt         = iw;  iw += E;
  unsigned* binned = (unsigned*)iw;  iw += E;

  // K0 first: converts W and zeroes bucketCount for the CSR build
  k_cvtW_zero<<<(512 * 64 + 255) / 256, 256, 0, stream>>>(W1, Wt, bucketCount);

  // CSR build via bucketed counting sort
  k_bhist<<<EB, 256, 0, stream>>>(dst, bucketCount, E, B);
  k_bscan<<<1, 512, 0, stream>>>(bucketCount, bucketOff, gCursor, B, E);
  k_bin<<<EB, 256, 0, stream>>>(src, dst, gCursor, binned, E, B);
  k_build<<<B, 256, 0, stream>>>(bucketOff, binned, rowptr, deg, srt, N);

  // Layer 1 (+ fused layer-2 node work)
  k_gemm1_mfma<<<(N + 127) / 128, 256, 0, stream>>>(x, Wt, h1b, N);
  k_alpha1<<<(N * 8 + 255) / 256, 256, 0, stream>>>(h1b, a1s, a1d, ef1sp, ef1d, h1f8, N);
  k_agg1f<<<(N + 3) / 4, 256, 0, stream>>>(rowptr, deg, srt, ef1sp, ef1d, h1f8,
                                           b1, W2, a2s, a2d, h2b, ef2sp, ef2d, N);

  // Layer 2
  k_agg2<<<(N + 3) / 4, 256, 0, stream>>>(rowptr, deg, srt, ef2sp, ef2d, h2b, b2, out, N);
}

// Round 10
// 222.594 us; speedup vs baseline: 6.0057x; 1.0885x over previous
//
#include <hip/hip_runtime.h>
#include <math.h>

#define NEG_SLOPE 0.2f
#define BKT_SHIFT 8                 // 256 dst nodes per bucket
#define BKT_RANGE 256
#define EPB 4096                    // edges per block in binning kernels

typedef __attribute__((ext_vector_type(8))) short bf16x8;
typedef __attribute__((ext_vector_type(4))) float f32x4;

__device__ __forceinline__ float elu1(float x)  { return x > 0.f ? x : expm1f(x); }

__device__ __forceinline__ unsigned short f2bf(float f) {
  unsigned u = __float_as_uint(f);
  unsigned r = (u + 0x7FFFu + ((u >> 16) & 1u)) >> 16;
  return (unsigned short)r;
}
__device__ __forceinline__ float bflo(unsigned u) { return __uint_as_float(u << 16); }
__device__ __forceinline__ float bfhi(unsigned u) { return __uint_as_float(u & 0xFFFF0000u); }
// HW packed f32->bf16 (RNE)
__device__ __forceinline__ unsigned cvt_pk_bf16(float lo, float hi) {
  unsigned r;
  asm("v_cvt_pk_bf16_f32 %0, %1, %2" : "=v"(r) : "v"(lo), "v"(hi));
  return r;
}

// ---------------- K0: Wt[c][k] = bf16(W1[k][c])  + zero bucketCount ----------------
__global__ __launch_bounds__(256) void k_cvtW_zero(const float* __restrict__ W,
                                                   unsigned short* __restrict__ Wt,
                                                   int* __restrict__ bucketCount) {
  int i = blockIdx.x * 256 + threadIdx.x;  // i = k*64 + c
  if (i < 1024) bucketCount[i] = 0;
  if (i >= 512 * 64) return;
  int k = i >> 6, c = i & 63;
  Wt[(size_t)c * 512 + k] = f2bf(W[i]);
}

// ---------------- K1: MFMA GEMM + fused alpha/fp8 epilogue ----------------
// h1 never hits HBM in bf16: epilogue emits h1f8 (fp8 payload) + ef1sp/ef1dp
// (packed bf16 exp tables) directly from the accumulator tile via LDS staging.
__global__ __launch_bounds__(256) void k_gemm1_mfma(const float* __restrict__ x,
                                                    const unsigned short* __restrict__ Wt,
                                                    const float* __restrict__ a1s,
                                                    const float* __restrict__ a1d,
                                                    unsigned* __restrict__ h1f8,
                                                    unsigned* __restrict__ ef1sp,
                                                    unsigned* __restrict__ ef1dp, int N) {
  __shared__ __align__(16) unsigned short As[128 * 64];
  __shared__ __align__(16) unsigned short Bs[64 * 64];
  const int t = threadIdx.x;
  const int w = t >> 6;
  const int l = t & 63;
  const int fr = l & 15;
  const int fq = l >> 4;
  const int rowbase = blockIdx.x * 128;
  f32x4 acc[2][4] = {};

  for (int k0 = 0; k0 < 512; k0 += 64) {
#pragma unroll
    for (int j = 0; j < 8; ++j) {
      int idx = j * 256 + t;
      int row = idx >> 4;
      int cg  = idx & 15;
      int grow = rowbase + row;
      float4 v = make_float4(0.f, 0.f, 0.f, 0.f);
      if (grow < N) v = *(const float4*)(x + (size_t)grow * 512 + k0 + cg * 4);
      uint2 pk;
      pk.x = cvt_pk_bf16(v.x, v.y);
      pk.y = cvt_pk_bf16(v.z, v.w);
      int ch = cg >> 1;
      int pch = ch ^ (row & 7);
      *((uint2*)(As + row * 64 + pch * 8 + (cg & 1) * 4)) = pk;
    }
#pragma unroll
    for (int rep = 0; rep < 2; ++rep) {
      int i = t + rep * 256;
      int c = i >> 3, ch = i & 7;
      uint4 v = *(const uint4*)(Wt + (size_t)c * 512 + k0 + ch * 8);
      *((uint4*)(Bs + c * 64 + (ch ^ (c & 7)) * 8)) = v;
    }
    __syncthreads();
#pragma unroll
    for (int ks = 0; ks < 2; ++ks) {
      bf16x8 a[2], b[4];
#pragma unroll
      for (int m = 0; m < 2; ++m) {
        int r = w * 32 + m * 16 + fr;
        int ch = (ks * 4 + fq) ^ (r & 7);
        a[m] = *((const bf16x8*)(As + r * 64 + ch * 8));
      }
#pragma unroll
      for (int n = 0; n < 4; ++n) {
        int c = n * 16 + fr;
        int ch = (ks * 4 + fq) ^ (c & 7);
        b[n] = *((const bf16x8*)(Bs + c * 64 + ch * 8));
      }
#pragma unroll
      for (int m = 0; m < 2; ++m)
#pragma unroll
        for (int n = 0; n < 4; ++n)
          acc[m][n] = __builtin_amdgcn_mfma_f32_16x16x32_bf16(a[m], b[n], acc[m][n], 0, 0, 0);
    }
    __syncthreads();
  }

  // ---- fused epilogue: stage tile half (64 rows x 64 cols f32) in LDS ----
  float* Asf = (float*)As;   // 16 KB = 64x64 f32
#pragma unroll
  for (int m = 0; m < 2; ++m) {
    if (m) __syncthreads();
#pragma unroll
    for (int reg = 0; reg < 4; ++reg) {
      int lrow = w * 16 + fq * 4 + reg;
#pragma unroll
      for (int n = 0; n < 4; ++n)
        Asf[lrow * 64 + n * 16 + fr] = acc[m][n][reg];
    }
    __syncthreads();
    // fp8 pack: 64 rows x 16 u32
#pragma unroll
    for (int p = 0; p < 4; ++p) {
      int flat = p * 256 + t;
      int lrow = flat >> 4, j = flat & 15;
      int g = rowbase + ((lrow >> 4) << 5) + m * 16 + (lrow & 15);
      float4 f = *(float4*)(Asf + lrow * 64 + j * 4);
      unsigned u = __builtin_amdgcn_cvt_pk_fp8_f32(f.x, f.y, 0u, 0);
      u = __builtin_amdgcn_cvt_pk_fp8_f32(f.z, f.w, u, 1);
      if (g < N) h1f8[(size_t)g * 16 + j] = u;
    }
    // alpha tables: 64 rows x 8 heads
#pragma unroll
    for (int p = 0; p < 2; ++p) {
      int flat = p * 256 + t;
      int lrow = flat >> 3, hh = flat & 7;
      int g = rowbase + ((lrow >> 4) << 5) + m * 16 + (lrow & 15);
      float4 f0 = *(float4*)(Asf + lrow * 64 + hh * 8);
      float4 f1 = *(float4*)(Asf + lrow * 64 + hh * 8 + 4);
      const float* sa = a1s + hh * 8;
      const float* da = a1d + hh * 8;
      float ss = f0.x*sa[0]+f0.y*sa[1]+f0.z*sa[2]+f0.w*sa[3]
               + f1.x*sa[4]+f1.y*sa[5]+f1.z*sa[6]+f1.w*sa[7];
      float dd = f0.x*da[0]+f0.y*da[1]+f0.z*da[2]+f0.w*da[3]
               + f1.x*da[4]+f1.y*da[5]+f1.z*da[6]+f1.w*da[7];
      if (g < N) {
        ef1sp[(size_t)g * 8 + hh] = cvt_pk_bf16(expf(ss), expf(NEG_SLOPE * ss));
        ef1dp[(size_t)g * 8 + hh] = cvt_pk_bf16(expf(dd), expf(NEG_SLOPE * dd));
      }
    }
  }
}

// ---------------- CSR build: two-level bucketed counting sort ----------------
__global__ __launch_bounds__(256) void k_bhist(const int* __restrict__ dst,
                                               int* __restrict__ bucketCount,
                                               int E, int B) {
  __shared__ int h[512];
  int t = threadIdx.x;
  for (int i = t; i < B; i += 256) h[i] = 0;
  __syncthreads();
  int e0 = blockIdx.x * EPB;
#pragma unroll
  for (int i = 0; i < EPB / 256; ++i) {
    int e = e0 + i * 256 + t;
    if (e < E) atomicAdd(&h[dst[e] >> BKT_SHIFT], 1);
  }
  __syncthreads();
  for (int i = t; i < B; i += 256)
    if (h[i]) atomicAdd(bucketCount + i, h[i]);
}

__global__ __launch_bounds__(512) void k_bscan(const int* __restrict__ bucketCount,
                                               int* __restrict__ bucketOff,
                                               int* __restrict__ gCursor, int B, int E) {
  __shared__ int sm[512];
  int t = threadIdx.x;
  int v = (t < B) ? bucketCount[t] : 0;
  sm[t] = v;
  __syncthreads();
  int acc = v;
#pragma unroll
  for (int o = 1; o < 512; o <<= 1) {
    int u = (t >= o) ? sm[t - o] : 0;
    __syncthreads();
    acc += u;
    sm[t] = acc;
    __syncthreads();
  }
  if (t < B) {
    bucketOff[t] = acc - v;
    gCursor[t] = acc - v;
  }
  if (t == 0) bucketOff[B] = E;
}

__global__ __launch_bounds__(256) void k_bin(const int* __restrict__ src,
                                             const int* __restrict__ dst,
                                             int* __restrict__ gCursor,
                                             unsigned* __restrict__ binned,
                                             int E, int B) {
  __shared__ int hist[512];
  __shared__ int base[512];
  int t = threadIdx.x;
  for (int i = t; i < B; i += 256) hist[i] = 0;
  __syncthreads();
  int e0 = blockIdx.x * EPB;
#pragma unroll
  for (int i = 0; i < EPB / 256; ++i) {
    int e = e0 + i * 256 + t;
    if (e < E) atomicAdd(&hist[dst[e] >> BKT_SHIFT], 1);
  }
  __syncthreads();
  for (int i = t; i < B; i += 256) {
    int c = hist[i];
    base[i] = c ? atomicAdd(gCursor + i, c) : 0;
    hist[i] = 0;
  }
  __syncthreads();
#pragma unroll
  for (int i = 0; i < EPB / 256; ++i) {
    int e = e0 + i * 256 + t;
    if (e < E) {
      int d = dst[e];
      int b = d >> BKT_SHIFT;
      int r = atomicAdd(&hist[b], 1);
      binned[base[b] + r] = ((unsigned)(d & (BKT_RANGE - 1)) << 24) | (unsigned)src[e];
    }
  }
}

__global__ __launch_bounds__(256) void k_build(const int* __restrict__ bucketOff,
                                               const unsigned* __restrict__ binned,
                                               int* __restrict__ rowptr,
                                               int* __restrict__ deg,
                                               int* __restrict__ srt, int N) {
  __shared__ int ldeg[BKT_RANGE];
  __shared__ int sm[BKT_RANGE];
  __shared__ int lcur[BKT_RANGE];
  int t = threadIdx.x;
  int b = blockIdx.x;
  int nbase = b * BKT_RANGE;
  int estart = bucketOff[b];
  int eend = bucketOff[b + 1];
  ldeg[t] = 0;
  __syncthreads();
  for (int e = estart + t; e < eend; e += 256)
    atomicAdd(&ldeg[binned[e] >> 24], 1);
  __syncthreads();
  int v = ldeg[t];
  sm[t] = v;
  __syncthreads();
  int acc = v;
#pragma unroll
  for (int o = 1; o < 256; o <<= 1) {
    int u = (t >= o) ? sm[t - o] : 0;
    __syncthreads();
    acc += u;
    sm[t] = acc;
    __syncthreads();
  }
  int excl = estart + acc - v;
  int node = nbase + t;
  if (node < N) {
    rowptr[node] = excl;
    deg[node] = v;
  }
  lcur[t] = excl;
  __syncthreads();
  for (int e = estart + t; e < eend; e += 256) {
    unsigned p = binned[e];
    int pos = atomicAdd(&lcur[p >> 24], 1);
    srt[pos] = (int)(p & 0xFFFFFFu);
  }
}

// ---------------- K agg1f: gather-reduce L1 (fp8) + fused L2 node work ----------------
// wave per dst; slot = lane>>4 (4 edges in flight), c4 = lane&15 (4 channels).
// srt indices batch-loaded 64 at a time, distributed via shfl (no dependent load).
__global__ __launch_bounds__(256) void k_agg1f(const int* __restrict__ rowptr,
                                               const int* __restrict__ deg,
                                               const int* __restrict__ srt,
                                               const unsigned* __restrict__ ef1sp,
                                               const unsigned* __restrict__ ef1dp,
                                               const unsigned* __restrict__ h1f8,
                                               const float* __restrict__ b1,
                                               const float* __restrict__ W2,
                                               const float* __restrict__ a2s,
                                               const float* __restrict__ a2d,
                                               unsigned short* __restrict__ h2b,
                                               unsigned* __restrict__ ef2sp,
                                               float* __restrict__ ef2d, int N) {
  __shared__ float vsm[4][64];
  const int t = threadIdx.x;
  const int w = t >> 6;
  const int lane = t & 63;
  const int wid = blockIdx.x * 4 + w;
  const int slot = lane >> 4;
  const int c4 = lane & 15;
  const int h = c4 >> 1;
  float a2sr = a2s[c4];
  float a2dr = a2d[c4];
  float wreg[16];
#pragma unroll
  for (int m = 0; m < 16; ++m) wreg[m] = W2[(slot * 16 + m) * 16 + c4];
  float4 b1v = *(const float4*)(b1 + c4 * 4);
  if (wid >= N) return;
  const int d = wid;

  unsigned ddu = ef1dp[(size_t)d * 8 + h];
  float ddx = bflo(ddu), ddy = bfhi(ddu);
  // self loop (slot 0 only)
  unsigned es0 = ef1sp[(size_t)d * 8 + h];
  unsigned sv = h1f8[(size_t)d * 16 + c4];
  float ex0 = fmaxf(bflo(es0) * ddx, bfhi(es0) * ddy);
  ex0 = (slot == 0) ? ex0 : 0.f;
  float a0 = ex0 * __builtin_amdgcn_cvt_f32_fp8(sv, 0);
  float a1 = ex0 * __builtin_amdgcn_cvt_f32_fp8(sv, 1);
  float a2 = ex0 * __builtin_amdgcn_cvt_f32_fp8(sv, 2);
  float a3 = ex0 * __builtin_amdgcn_cvt_f32_fp8(sv, 3);
  float den = ex0;

  int start = rowptr[d];
  int len = deg[d];
  for (int kb = 0; kb < len; kb += 64) {
    int li = kb + lane;
    int sreg = (li < len) ? srt[start + li] : 0;
    int nit = min(16, (len - kb + 3) >> 2);
#pragma unroll 2
    for (int it = 0; it < nit; ++it) {
      int idx = kb + it * 4 + slot;
      int s = __shfl(sreg, it * 4 + slot);
      bool valid = idx < len;
      unsigned es = ef1sp[(size_t)s * 8 + h];
      unsigned hv = h1f8[(size_t)s * 16 + c4];
      float ex = fmaxf(bflo(es) * ddx, bfhi(es) * ddy);
      ex = valid ? ex : 0.f;
      a0 = fmaf(ex, __builtin_amdgcn_cvt_f32_fp8(hv, 0), a0);
      a1 = fmaf(ex, __builtin_amdgcn_cvt_f32_fp8(hv, 1), a1);
      a2 = fmaf(ex, __builtin_amdgcn_cvt_f32_fp8(hv, 2), a2);
      a3 = fmaf(ex, __builtin_amdgcn_cvt_f32_fp8(hv, 3), a3);
      den += ex;
    }
  }
  // reduce across slots (lane bits 4,5)
#pragma unroll
  for (int o = 16; o < 64; o <<= 1) {
    a0 += __shfl_xor(a0, o);
    a1 += __shfl_xor(a1, o);
    a2 += __shfl_xor(a2, o);
    a3 += __shfl_xor(a3, o);
    den += __shfl_xor(den, o);
  }
  float rden = 1.f / (den + 1e-16f);
  // ---- fused layer-2 node work ----
  if (slot == 0) {
    float4 vv;
    vv.x = elu1(a0 * rden + b1v.x);
    vv.y = elu1(a1 * rden + b1v.y);
    vv.z = elu1(a2 * rden + b1v.z);
    vv.w = elu1(a3 * rden + b1v.w);
    *(float4*)&vsm[w][c4 * 4] = vv;
  }
  float partial = 0.f;
#pragma unroll
  for (int m = 0; m < 16; ++m) partial = fmaf(vsm[w][slot * 16 + m], wreg[m], partial);
  float qs = partial * a2sr;
  float qd = partial * a2dr;
#pragma unroll
  for (int o = 1; o < 64; o <<= 1) {
    qs += __shfl_xor(qs, o);
    qd += __shfl_xor(qd, o);
  }
  float p2 = partial + __shfl_down(partial, 32);
  float hcv = p2 + __shfl_down(p2, 16);
  if (lane < 16) h2b[(size_t)d * 16 + c4] = f2bf(hcv);
  if (lane == 0) {
    ef2sp[d] = cvt_pk_bf16(expf(qs), expf(NEG_SLOPE * qs));
    *(float2*)(ef2d + (size_t)d * 2) = make_float2(expf(qd), expf(NEG_SLOPE * qd));
  }
}

// ---------------- K agg2: gather-reduce layer 2 + b2 + log_softmax ----------------
// slot = lane>>2 (16 edges in flight), cg = lane&3 (4 channels); batched srt.
__global__ __launch_bounds__(256) void k_agg2(const int* __restrict__ rowptr,
                                              const int* __restrict__ deg,
                                              const int* __restrict__ srt,
                                              const unsigned* __restrict__ ef2sp,
                                              const float* __restrict__ ef2d,
                                              const unsigned short* __restrict__ h2b,
                                              const float* __restrict__ b2,
                                              float* __restrict__ out, int N) {
  const int t = threadIdx.x;
  const int lane = t & 63;
  const int wid = (blockIdx.x * 256 + t) >> 6;
  const int slot = lane >> 2;
  const int cg = lane & 3;
  float4 b2v = *(const float4*)(b2 + cg * 4);
  if (wid >= N) return;
  const int d = wid;
  float2 ddp = *(const float2*)(ef2d + (size_t)d * 2);
  unsigned ps0 = ef2sp[d];
  uint2 sv = *(const uint2*)(h2b + (size_t)d * 16 + cg * 4);
  float ex0 = fmaxf(bflo(ps0) * ddp.x, bfhi(ps0) * ddp.y);
  ex0 = (slot == 0) ? ex0 : 0.f;
  float a0 = ex0 * bflo(sv.x), a1 = ex0 * bfhi(sv.x);
  float a2 = ex0 * bflo(sv.y), a3 = ex0 * bfhi(sv.y);
  float den = ex0;

  int start = rowptr[d];
  int len = deg[d];
  for (int kb = 0; kb < len; kb += 64) {
    int li = kb + lane;
    int sreg = (li < len) ? srt[start + li] : 0;
    int nit = min(4, (len - kb + 15) >> 4);
#pragma unroll 2
    for (int it = 0; it < nit; ++it) {
      int idx = kb + it * 16 + slot;
      int s = __shfl(sreg, it * 16 + slot);
      bool valid = idx < len;
      unsigned ps = ef2sp[s];
      uint2 hv = *(const uint2*)(h2b + (size_t)s * 16 + cg * 4);
      float ex = fmaxf(bflo(ps) * ddp.x, bfhi(ps) * ddp.y);
      ex = valid ? ex : 0.f;
      a0 = fmaf(ex, bflo(hv.x), a0);
      a1 = fmaf(ex, bfhi(hv.x), a1);
      a2 = fmaf(ex, bflo(hv.y), a2);
      a3 = fmaf(ex, bfhi(hv.y), a3);
      den += ex;
    }
  }
#pragma unroll
  for (int o = 4; o < 64; o <<= 1) {
    a0 += __shfl_xor(a0, o);
    a1 += __shfl_xor(a1, o);
    a2 += __shfl_xor(a2, o);
    a3 += __shfl_xor(a3, o);
    den += __shfl_xor(den, o);
  }
  float rden = 1.f / (den + 1e-16f);
  float v0 = a0 * rden + b2v.x;
  float v1 = a1 * rden + b2v.y;
  float v2 = a2 * rden + b2v.z;
  float v3 = a3 * rden + b2v.w;
  float m = fmaxf(fmaxf(v0, v1), fmaxf(v2, v3));
  m = fmaxf(m, __shfl_xor(m, 1));
  m = fmaxf(m, __shfl_xor(m, 2));
  float s = expf(v0 - m) + expf(v1 - m) + expf(v2 - m) + expf(v3 - m);
  s += __shfl_xor(s, 1);
  s += __shfl_xor(s, 2);
  float lse = m + logf(s);
  if (lane < 4) {
    float4 o4 = make_float4(v0 - lse, v1 - lse, v2 - lse, v3 - lse);
    *(float4*)(out + (size_t)d * 16 + cg * 4) = o4;
  }
}

extern "C" void kernel_launch(void* const* d_in, const int* in_sizes, int n_in,
                              void* d_out, int out_size, void* d_ws, size_t ws_size,
                              hipStream_t stream) {
  const float* x    = (const float*)d_in[0];
  const int*   ei   = (const int*)d_in[1];
  const float* W1   = (const float*)d_in[2];
  const float* a1s  = (const float*)d_in[3];
  const float* a1d  = (const float*)d_in[4];
  const float* b1   = (const float*)d_in[5];
  const float* W2   = (const float*)d_in[6];
  const float* a2s  = (const float*)d_in[7];
  const float* a2d  = (const float*)d_in[8];
  const float* b2   = (const float*)d_in[9];
  float* out = (float*)d_out;

  const int N = in_sizes[0] / 512;
  const int E = in_sizes[1] / 2;
  const int* src = ei;
  const int* dst = ei + E;
  const int B = (N + BKT_RANGE - 1) >> BKT_SHIFT;
  const int EB = (E + EPB - 1) / EPB;

  float* w = (float*)d_ws;
  float* ef2d = w;  w += (size_t)N * 2;
  unsigned* ef1sp = (unsigned*)w;  w += (size_t)N * 8;
  unsigned* ef1dp = (unsigned*)w;  w += (size_t)N * 8;
  unsigned* ef2sp = (unsigned*)w;  w += (size_t)N;
  unsigned* h1f8  = (unsigned*)w;  w += (size_t)N * 16;
  unsigned short* h2b = (unsigned short*)w;  w += (size_t)N * 8;
  unsigned short* Wt  = (unsigned short*)w;  w += 512 * 64 / 2;
  int* iw = (int*)w;
  int* deg         = iw;  iw += N;
  int* rowptr      = iw;  iw += N;
  int* bucketCount = iw;  iw += 1024;
  int* bucketOff   = iw;  iw += 1024;
  int* gCursor     = iw;  iw += 1024;
  int* srt         = iw;  iw += E;
  unsigned* binned = (unsigned*)iw;  iw += E;

  // K0 first: converts W and zeroes bucketCount for the CSR build
  k_cvtW_zero<<<(512 * 64 + 255) / 256, 256, 0, stream>>>(W1, Wt, bucketCount);

  // CSR build via bucketed counting sort
  k_bhist<<<EB, 256, 0, stream>>>(dst, bucketCount, E, B);
  k_bscan<<<1, 512, 0, stream>>>(bucketCount, bucketOff, gCursor, B, E);
  k_bin<<<EB, 256, 0, stream>>>(src, dst, gCursor, binned, E, B);
  k_build<<<B, 256, 0, stream>>>(bucketOff, binned, rowptr, deg, srt, N);

  // Layer 1: GEMM with fused alpha/fp8 epilogue, then gather (+fused L2 node work)
  k_gemm1_mfma<<<(N + 127) / 128, 256, 0, stream>>>(x, Wt, a1s, a1d, h1f8, ef1sp, ef1dp, N);
  k_agg1f<<<(N + 3) / 4, 256, 0, stream>>>(rowptr, deg, srt, ef1sp, ef1dp, h1f8,
                                           b1, W2, a2s, a2d, h2b, ef2sp, ef2d, N);

  // Layer 2
  k_agg2<<<(N + 3) / 4, 256, 0, stream>>>(rowptr, deg, srt, ef2sp, ef2d, h2b, b2, out, N);
}

// Round 11
// 211.987 us; speedup vs baseline: 6.3062x; 1.0500x over previous
//
#include <hip/hip_runtime.h>
#include <math.h>

#define NEG_SLOPE 0.2f
#define BKT_SHIFT 8                 // 256 dst nodes per bucket
#define BKT_RANGE 256
#define EPB 4096                    // edges per block in binning kernels

typedef __attribute__((ext_vector_type(8))) short bf16x8;
typedef __attribute__((ext_vector_type(4))) float f32x4;

__device__ __forceinline__ float elu1(float x)  { return x > 0.f ? x : expm1f(x); }

__device__ __forceinline__ unsigned short f2bf(float f) {
  unsigned u = __float_as_uint(f);
  unsigned r = (u + 0x7FFFu + ((u >> 16) & 1u)) >> 16;
  return (unsigned short)r;
}
__device__ __forceinline__ float bflo(unsigned u) { return __uint_as_float(u << 16); }
__device__ __forceinline__ float bfhi(unsigned u) { return __uint_as_float(u & 0xFFFF0000u); }
// HW packed f32->bf16 (RNE)
__device__ __forceinline__ unsigned cvt_pk_bf16(float lo, float hi) {
  unsigned r;
  asm("v_cvt_pk_bf16_f32 %0, %1, %2" : "=v"(r) : "v"(lo), "v"(hi));
  return r;
}

// ---------------- K0: Wt[c][k] = bf16(W1[k][c])  + zero bucketCount/gCursorRel ----------------
__global__ __launch_bounds__(256) void k_cvtW_zero(const float* __restrict__ W,
                                                   unsigned short* __restrict__ Wt,
                                                   int* __restrict__ bucketCount) {
  int i = blockIdx.x * 256 + threadIdx.x;  // i = k*64 + c
  if (i < 1024) bucketCount[i] = 0;        // covers bucketCount[512] + gCursorRel[512]
  if (i >= 512 * 64) return;
  int k = i >> 6, c = i & 63;
  Wt[(size_t)c * 512 + k] = f2bf(W[i]);
}

// ---------------- K1: MFMA GEMM (A direct-to-reg) + fused alpha/fp8 epilogue ----------------
// hx row per node (24 u32 = 96B): words 0..7 = packed {exp(as),exp(.2as)} per head;
// words 8..23 = 64 channels fp8 e4m3. ef1dp separate (dst-side only).
__global__ __launch_bounds__(256) void k_gemm1_mfma(const float* __restrict__ x,
                                                    const unsigned short* __restrict__ Wt,
                                                    const float* __restrict__ a1s,
                                                    const float* __restrict__ a1d,
                                                    unsigned* __restrict__ hx,
                                                    unsigned* __restrict__ ef1dp, int N) {
  __shared__ __align__(16) float Sm[64 * 64];        // 16 KB: Bs (8KB) in loop, Asf in epilogue
  unsigned short* Bs = (unsigned short*)Sm;
  float* Asf = Sm;
  const int t = threadIdx.x;
  const int w = t >> 6;
  const int l = t & 63;
  const int fr = l & 15;
  const int fq = l >> 4;
  const int rowbase = blockIdx.x * 128;
  f32x4 acc[2][4] = {};

  const int r0g = rowbase + w * 32 + fr;
  const int r1g = r0g + 16;
  const bool v0 = r0g < N, v1 = r1g < N;
  const float* xr0 = x + (size_t)r0g * 512 + fq * 8;
  const float* xr1 = x + (size_t)r1g * 512 + fq * 8;

  for (int k0 = 0; k0 < 512; k0 += 64) {
    // ---- stage B: 512 chunks of 16B, XOR-swizzled
#pragma unroll
    for (int rep = 0; rep < 2; ++rep) {
      int i = t + rep * 256;
      int c = i >> 3, ch = i & 7;
      uint4 v = *(const uint4*)(Wt + (size_t)c * 512 + k0 + ch * 8);
      *((uint4*)(Bs + c * 64 + (ch ^ (c & 7)) * 8)) = v;
    }
    // ---- load A fragments direct from x (per-wave-private rows), cvt in reg
    bf16x8 a[2][2];
#pragma unroll
    for (int m = 0; m < 2; ++m) {
      const float* xr = m ? xr1 : xr0;
      bool vv = m ? v1 : v0;
#pragma unroll
      for (int ks = 0; ks < 2; ++ks) {
        float4 f0 = make_float4(0.f, 0.f, 0.f, 0.f), f1 = f0;
        if (vv) {
          f0 = *(const float4*)(xr + k0 + ks * 32);
          f1 = *(const float4*)(xr + k0 + ks * 32 + 4);
        }
        union { unsigned u[4]; bf16x8 v8; } un;
        un.u[0] = cvt_pk_bf16(f0.x, f0.y);
        un.u[1] = cvt_pk_bf16(f0.z, f0.w);
        un.u[2] = cvt_pk_bf16(f1.x, f1.y);
        un.u[3] = cvt_pk_bf16(f1.z, f1.w);
        a[m][ks] = un.v8;
      }
    }
    __syncthreads();
#pragma unroll
    for (int ks = 0; ks < 2; ++ks) {
      bf16x8 b[4];
#pragma unroll
      for (int n = 0; n < 4; ++n) {
        int c = n * 16 + fr;
        int ch = (ks * 4 + fq) ^ (c & 7);
        b[n] = *((const bf16x8*)(Bs + c * 64 + ch * 8));
      }
#pragma unroll
      for (int m = 0; m < 2; ++m)
#pragma unroll
        for (int n = 0; n < 4; ++n)
          acc[m][n] = __builtin_amdgcn_mfma_f32_16x16x32_bf16(a[m][ks], b[n], acc[m][n], 0, 0, 0);
    }
    __syncthreads();
  }

  // ---- fused epilogue: stage tile half (64 rows x 64 cols f32) in LDS (reuses Bs space)
#pragma unroll
  for (int m = 0; m < 2; ++m) {
    if (m) __syncthreads();
#pragma unroll
    for (int reg = 0; reg < 4; ++reg) {
      int lrow = w * 16 + fq * 4 + reg;
#pragma unroll
      for (int n = 0; n < 4; ++n)
        Asf[lrow * 64 + n * 16 + fr] = acc[m][n][reg];
    }
    __syncthreads();
    // fp8 pack: 64 rows x 16 u32 -> hx words 8..23
#pragma unroll
    for (int p = 0; p < 4; ++p) {
      int flat = p * 256 + t;
      int lrow = flat >> 4, j = flat & 15;
      int g = rowbase + ((lrow >> 4) << 5) + m * 16 + (lrow & 15);
      float4 f = *(float4*)(Asf + lrow * 64 + j * 4);
      unsigned u = __builtin_amdgcn_cvt_pk_fp8_f32(f.x, f.y, 0u, 0);
      u = __builtin_amdgcn_cvt_pk_fp8_f32(f.z, f.w, u, 1);
      if (g < N) hx[(size_t)g * 24 + 8 + j] = u;
    }
    // alpha tables: 64 rows x 8 heads -> hx words 0..7 + ef1dp
#pragma unroll
    for (int p = 0; p < 2; ++p) {
      int flat = p * 256 + t;
      int lrow = flat >> 3, hh = flat & 7;
      int g = rowbase + ((lrow >> 4) << 5) + m * 16 + (lrow & 15);
      float4 f0 = *(float4*)(Asf + lrow * 64 + hh * 8);
      float4 f1 = *(float4*)(Asf + lrow * 64 + hh * 8 + 4);
      const float* sa = a1s + hh * 8;
      const float* da = a1d + hh * 8;
      float ss = f0.x*sa[0]+f0.y*sa[1]+f0.z*sa[2]+f0.w*sa[3]
               + f1.x*sa[4]+f1.y*sa[5]+f1.z*sa[6]+f1.w*sa[7];
      float dd = f0.x*da[0]+f0.y*da[1]+f0.z*da[2]+f0.w*da[3]
               + f1.x*da[4]+f1.y*da[5]+f1.z*da[6]+f1.w*da[7];
      if (g < N) {
        hx[(size_t)g * 24 + hh] = cvt_pk_bf16(expf(ss), expf(NEG_SLOPE * ss));
        ef1dp[(size_t)g * 8 + hh] = cvt_pk_bf16(expf(dd), expf(NEG_SLOPE * dd));
      }
    }
  }
}

// ---------------- CSR build ----------------
__global__ __launch_bounds__(256) void k_bhist(const int* __restrict__ dst,
                                               int* __restrict__ bucketCount,
                                               int E, int B) {
  __shared__ int h[512];
  int t = threadIdx.x;
  for (int i = t; i < B; i += 256) h[i] = 0;
  __syncthreads();
  int e0 = blockIdx.x * EPB;
#pragma unroll
  for (int i = 0; i < EPB / 256; ++i) {
    int e = e0 + i * 256 + t;
    if (e < E) atomicAdd(&h[dst[e] >> BKT_SHIFT], 1);
  }
  __syncthreads();
  for (int i = t; i < B; i += 256)
    if (h[i]) atomicAdd(bucketCount + i, h[i]);
}

// radix partition with LOCAL bucket scan (k_bscan deleted); gCursorRel is relative.
__global__ __launch_bounds__(256) void k_bin(const int* __restrict__ src,
                                             const int* __restrict__ dst,
                                             const int* __restrict__ bucketCount,
                                             int* __restrict__ gCursorRel,
                                             unsigned* __restrict__ binned,
                                             int E, int B) {
  __shared__ int sc[512];
  __shared__ int hist[512];
  __shared__ int base[512];
  int t = threadIdx.x;
  sc[t]       = (t < B) ? bucketCount[t] : 0;
  sc[t + 256] = (t + 256 < B) ? bucketCount[t + 256] : 0;
  for (int i = t; i < 512; i += 256) hist[i] = 0;
  __syncthreads();
  // inclusive Jacobi scan over 512, 2 elems/thread (read-barrier-write-barrier)
  for (int o = 1; o < 512; o <<= 1) {
    int a0 = (t >= o) ? sc[t - o] : 0;
    int a1 = (t + 256 >= o) ? sc[t + 256 - o] : 0;
    __syncthreads();
    sc[t] += a0;
    sc[t + 256] += a1;
    __syncthreads();
  }
  int e0 = blockIdx.x * EPB;
#pragma unroll
  for (int i = 0; i < EPB / 256; ++i) {
    int e = e0 + i * 256 + t;
    if (e < E) atomicAdd(&hist[dst[e] >> BKT_SHIFT], 1);
  }
  __syncthreads();
  for (int i = t; i < B; i += 256) {
    int c = hist[i];
    int excl = sc[i] - bucketCount[i];
    base[i] = c ? (excl + atomicAdd(gCursorRel + i, c)) : 0;
    hist[i] = 0;
  }
  __syncthreads();
#pragma unroll
  for (int i = 0; i < EPB / 256; ++i) {
    int e = e0 + i * 256 + t;
    if (e < E) {
      int d = dst[e];
      int b = d >> BKT_SHIFT;
      int r = atomicAdd(&hist[b], 1);
      binned[base[b] + r] = ((unsigned)(d & (BKT_RANGE - 1)) << 24) | (unsigned)src[e];
    }
  }
}

__global__ __launch_bounds__(256) void k_build(const int* __restrict__ bucketCount,
                                               const unsigned* __restrict__ binned,
                                               int* __restrict__ rowptr,
                                               int* __restrict__ deg,
                                               int* __restrict__ srt, int N, int B) {
  __shared__ int sc[512];
  __shared__ int ldeg[BKT_RANGE];
  __shared__ int sm[BKT_RANGE];
  __shared__ int lcur[BKT_RANGE];
  int t = threadIdx.x;
  int b = blockIdx.x;
  sc[t]       = (t < B) ? bucketCount[t] : 0;
  sc[t + 256] = (t + 256 < B) ? bucketCount[t + 256] : 0;
  ldeg[t] = 0;
  __syncthreads();
  for (int o = 1; o < 512; o <<= 1) {
    int a0 = (t >= o) ? sc[t - o] : 0;
    int a1 = (t + 256 >= o) ? sc[t + 256 - o] : 0;
    __syncthreads();
    sc[t] += a0;
    sc[t + 256] += a1;
    __syncthreads();
  }
  int eend = sc[b];
  int estart = eend - bucketCount[b];
  int nbase = b * BKT_RANGE;
  for (int e = estart + t; e < eend; e += 256)
    atomicAdd(&ldeg[binned[e] >> 24], 1);
  __syncthreads();
  int v = ldeg[t];
  sm[t] = v;
  __syncthreads();
  int acc = v;
#pragma unroll
  for (int o = 1; o < 256; o <<= 1) {
    int u = (t >= o) ? sm[t - o] : 0;
    __syncthreads();
    acc += u;
    sm[t] = acc;
    __syncthreads();
  }
  int excl = estart + acc - v;
  int node = nbase + t;
  if (node < N) {
    rowptr[node] = excl;
    deg[node] = v;
  }
  lcur[t] = excl;
  __syncthreads();
  for (int e = estart + t; e < eend; e += 256) {
    unsigned p = binned[e];
    int pos = atomicAdd(&lcur[p >> 24], 1);
    srt[pos] = (int)(p & 0xFFFFFFu);
  }
}

// ---------------- K agg1f: gather-reduce L1 (combined hx rows) + fused L2 node work ----------------
__global__ __launch_bounds__(256) void k_agg1f(const int* __restrict__ rowptr,
                                               const int* __restrict__ deg,
                                               const int* __restrict__ srt,
                                               const unsigned* __restrict__ hx,
                                               const unsigned* __restrict__ ef1dp,
                                               const float* __restrict__ b1,
                                               const float* __restrict__ W2,
                                               const float* __restrict__ a2s,
                                               const float* __restrict__ a2d,
                                               unsigned short* __restrict__ h2b,
                                               unsigned* __restrict__ ef2sp,
                                               float* __restrict__ ef2d, int N) {
  __shared__ float vsm[4][64];
  const int t = threadIdx.x;
  const int w = t >> 6;
  const int lane = t & 63;
  const int wid = blockIdx.x * 4 + w;
  const int slot = lane >> 4;
  const int c4 = lane & 15;
  const int h = c4 >> 1;
  float a2sr = a2s[c4];
  float a2dr = a2d[c4];
  float wreg[16];
#pragma unroll
  for (int m = 0; m < 16; ++m) wreg[m] = W2[(slot * 16 + m) * 16 + c4];
  float4 b1v = *(const float4*)(b1 + c4 * 4);
  if (wid >= N) return;
  const int d = wid;

  unsigned ddu = ef1dp[(size_t)d * 8 + h];
  float ddx = bflo(ddu), ddy = bfhi(ddu);
  // self loop (slot 0 only)
  unsigned es0 = hx[(size_t)d * 24 + h];
  unsigned sv = hx[(size_t)d * 24 + 8 + c4];
  float ex0 = fmaxf(bflo(es0) * ddx, bfhi(es0) * ddy);
  ex0 = (slot == 0) ? ex0 : 0.f;
  float a0 = ex0 * __builtin_amdgcn_cvt_f32_fp8(sv, 0);
  float a1 = ex0 * __builtin_amdgcn_cvt_f32_fp8(sv, 1);
  float a2 = ex0 * __builtin_amdgcn_cvt_f32_fp8(sv, 2);
  float a3 = ex0 * __builtin_amdgcn_cvt_f32_fp8(sv, 3);
  float den = ex0;

  int start = rowptr[d];
  int len = deg[d];
  for (int kb = 0; kb < len; kb += 64) {
    int li = kb + lane;
    int sreg = (li < len) ? srt[start + li] : 0;
    int nit = min(16, (len - kb + 3) >> 2);
#pragma unroll 4
    for (int it = 0; it < nit; ++it) {
      int idx = kb + it * 4 + slot;
      int s = __shfl(sreg, it * 4 + slot);
      bool valid = idx < len;
      unsigned es = hx[(size_t)s * 24 + h];
      unsigned hv = hx[(size_t)s * 24 + 8 + c4];
      float ex = fmaxf(bflo(es) * ddx, bfhi(es) * ddy);
      ex = valid ? ex : 0.f;
      a0 = fmaf(ex, __builtin_amdgcn_cvt_f32_fp8(hv, 0), a0);
      a1 = fmaf(ex, __builtin_amdgcn_cvt_f32_fp8(hv, 1), a1);
      a2 = fmaf(ex, __builtin_amdgcn_cvt_f32_fp8(hv, 2), a2);
      a3 = fmaf(ex, __builtin_amdgcn_cvt_f32_fp8(hv, 3), a3);
      den += ex;
    }
  }
#pragma unroll
  for (int o = 16; o < 64; o <<= 1) {
    a0 += __shfl_xor(a0, o);
    a1 += __shfl_xor(a1, o);
    a2 += __shfl_xor(a2, o);
    a3 += __shfl_xor(a3, o);
    den += __shfl_xor(den, o);
  }
  float rden = 1.f / (den + 1e-16f);
  if (slot == 0) {
    float4 vv;
    vv.x = elu1(a0 * rden + b1v.x);
    vv.y = elu1(a1 * rden + b1v.y);
    vv.z = elu1(a2 * rden + b1v.z);
    vv.w = elu1(a3 * rden + b1v.w);
    *(float4*)&vsm[w][c4 * 4] = vv;
  }
  float partial = 0.f;
#pragma unroll
  for (int m = 0; m < 16; ++m) partial = fmaf(vsm[w][slot * 16 + m], wreg[m], partial);
  float qs = partial * a2sr;
  float qd = partial * a2dr;
#pragma unroll
  for (int o = 1; o < 64; o <<= 1) {
    qs += __shfl_xor(qs, o);
    qd += __shfl_xor(qd, o);
  }
  float p2 = partial + __shfl_down(partial, 32);
  float hcv = p2 + __shfl_down(p2, 16);
  if (lane < 16) h2b[(size_t)d * 16 + c4] = f2bf(hcv);
  if (lane == 0) {
    ef2sp[d] = cvt_pk_bf16(expf(qs), expf(NEG_SLOPE * qs));
    *(float2*)(ef2d + (size_t)d * 2) = make_float2(expf(qd), expf(NEG_SLOPE * qd));
  }
}

// ---------------- K agg2: gather-reduce layer 2 + b2 + log_softmax ----------------
__global__ __launch_bounds__(256) void k_agg2(const int* __restrict__ rowptr,
                                              const int* __restrict__ deg,
                                              const int* __restrict__ srt,
                                              const unsigned* __restrict__ ef2sp,
                                              const float* __restrict__ ef2d,
                                              const unsigned short* __restrict__ h2b,
                                              const float* __restrict__ b2,
                                              float* __restrict__ out, int N) {
  const int t = threadIdx.x;
  const int lane = t & 63;
  const int wid = (blockIdx.x * 256 + t) >> 6;
  const int slot = lane >> 2;
  const int cg = lane & 3;
  float4 b2v = *(const float4*)(b2 + cg * 4);
  if (wid >= N) return;
  const int d = wid;
  float2 ddp = *(const float2*)(ef2d + (size_t)d * 2);
  unsigned ps0 = ef2sp[d];
  uint2 sv = *(const uint2*)(h2b + (size_t)d * 16 + cg * 4);
  float ex0 = fmaxf(bflo(ps0) * ddp.x, bfhi(ps0) * ddp.y);
  ex0 = (slot == 0) ? ex0 : 0.f;
  float a0 = ex0 * bflo(sv.x), a1 = ex0 * bfhi(sv.x);
  float a2 = ex0 * bflo(sv.y), a3 = ex0 * bfhi(sv.y);
  float den = ex0;

  int start = rowptr[d];
  int len = deg[d];
  for (int kb = 0; kb < len; kb += 64) {
    int li = kb + lane;
    int sreg = (li < len) ? srt[start + li] : 0;
    int nit = min(4, (len - kb + 15) >> 4);
#pragma unroll 4
    for (int it = 0; it < nit; ++it) {
      int idx = kb + it * 16 + slot;
      int s = __shfl(sreg, it * 16 + slot);
      bool valid = idx < len;
      unsigned ps = ef2sp[s];
      uint2 hv = *(const uint2*)(h2b + (size_t)s * 16 + cg * 4);
      float ex = fmaxf(bflo(ps) * ddp.x, bfhi(ps) * ddp.y);
      ex = valid ? ex : 0.f;
      a0 = fmaf(ex, bflo(hv.x), a0);
      a1 = fmaf(ex, bfhi(hv.x), a1);
      a2 = fmaf(ex, bflo(hv.y), a2);
      a3 = fmaf(ex, bfhi(hv.y), a3);
      den += ex;
    }
  }
#pragma unroll
  for (int o = 4; o < 64; o <<= 1) {
    a0 += __shfl_xor(a0, o);
    a1 += __shfl_xor(a1, o);
    a2 += __shfl_xor(a2, o);
    a3 += __shfl_xor(a3, o);
    den += __shfl_xor(den, o);
  }
  float rden = 1.f / (den + 1e-16f);
  float v0 = a0 * rden + b2v.x;
  float v1 = a1 * rden + b2v.y;
  float v2 = a2 * rden + b2v.z;
  float v3 = a3 * rden + b2v.w;
  float m = fmaxf(fmaxf(v0, v1), fmaxf(v2, v3));
  m = fmaxf(m, __shfl_xor(m, 1));
  m = fmaxf(m, __shfl_xor(m, 2));
  float s = expf(v0 - m) + expf(v1 - m) + expf(v2 - m) + expf(v3 - m);
  s += __shfl_xor(s, 1);
  s += __shfl_xor(s, 2);
  float lse = m + logf(s);
  if (lane < 4) {
    float4 o4 = make_float4(v0 - lse, v1 - lse, v2 - lse, v3 - lse);
    *(float4*)(out + (size_t)d * 16 + cg * 4) = o4;
  }
}

extern "C" void kernel_launch(void* const* d_in, const int* in_sizes, int n_in,
                              void* d_out, int out_size, void* d_ws, size_t ws_size,
                              hipStream_t stream) {
  const float* x    = (const float*)d_in[0];
  const int*   ei   = (const int*)d_in[1];
  const float* W1   = (const float*)d_in[2];
  const float* a1s  = (const float*)d_in[3];
  const float* a1d  = (const float*)d_in[4];
  const float* b1   = (const float*)d_in[5];
  const float* W2   = (const float*)d_in[6];
  const float* a2s  = (const float*)d_in[7];
  const float* a2d  = (const float*)d_in[8];
  const float* b2   = (const float*)d_in[9];
  float* out = (float*)d_out;

  const int N = in_sizes[0] / 512;
  const int E = in_sizes[1] / 2;
  const int* src = ei;
  const int* dst = ei + E;
  const int B = (N + BKT_RANGE - 1) >> BKT_SHIFT;
  const int EB = (E + EPB - 1) / EPB;

  float* w = (float*)d_ws;
  float* ef2d = w;  w += (size_t)N * 2;
  unsigned* ef1dp = (unsigned*)w;  w += (size_t)N * 8;
  unsigned* ef2sp = (unsigned*)w;  w += (size_t)N;
  unsigned* hx    = (unsigned*)w;  w += (size_t)N * 24;
  unsigned short* h2b = (unsigned short*)w;  w += (size_t)N * 8;
  unsigned short* Wt  = (unsigned short*)w;  w += 512 * 64 / 2;
  int* iw = (int*)w;
  int* deg         = iw;  iw += N;
  int* rowptr      = iw;  iw += N;
  int* bucketCount = iw;  iw += 512;
  int* gCursorRel  = iw;  iw += 512;
  int* srt         = iw;  iw += E;
  unsigned* binned = (unsigned*)iw;  iw += E;

  // K0: converts W, zeroes bucketCount + gCursorRel
  k_cvtW_zero<<<(512 * 64 + 255) / 256, 256, 0, stream>>>(W1, Wt, bucketCount);

  // CSR build (bscan folded into bin/build as local scans)
  k_bhist<<<EB, 256, 0, stream>>>(dst, bucketCount, E, B);
  k_bin<<<EB, 256, 0, stream>>>(src, dst, bucketCount, gCursorRel, binned, E, B);
  k_build<<<B, 256, 0, stream>>>(bucketCount, binned, rowptr, deg, srt, N, B);

  // Layer 1: GEMM with fused alpha/fp8 epilogue, then gather (+fused L2 node work)
  k_gemm1_mfma<<<(N + 127) / 128, 256, 0, stream>>>(x, Wt, a1s, a1d, hx, ef1dp, N);
  k_agg1f<<<(N + 3) / 4, 256, 0, stream>>>(rowptr, deg, srt, hx, ef1dp,
                                           b1, W2, a2s, a2d, h2b, ef2sp, ef2d, N);

  // Layer 2
  k_agg2<<<(N + 3) / 4, 256, 0, stream>>>(rowptr, deg, srt, ef2sp, ef2d, h2b, b2, out, N);
}

// Round 12
// 210.992 us; speedup vs baseline: 6.3359x; 1.0047x over previous
//
#include <hip/hip_runtime.h>
#include <math.h>

#define NEG_SLOPE 0.2f
#define BKT_SHIFT 8                 // 256 dst nodes per bucket
#define BKT_RANGE 256
#define EPB 4096                    // edges per block in binning kernels

typedef __attribute__((ext_vector_type(8))) short bf16x8;
typedef __attribute__((ext_vector_type(4))) float f32x4;

__device__ __forceinline__ float elu1(float x)  { return x > 0.f ? x : expm1f(x); }

__device__ __forceinline__ unsigned short f2bf(float f) {
  unsigned u = __float_as_uint(f);
  unsigned r = (u + 0x7FFFu + ((u >> 16) & 1u)) >> 16;
  return (unsigned short)r;
}
__device__ __forceinline__ float bflo(unsigned u) { return __uint_as_float(u << 16); }
__device__ __forceinline__ float bfhi(unsigned u) { return __uint_as_float(u & 0xFFFF0000u); }
// HW packed f32->bf16 (RNE)
__device__ __forceinline__ unsigned cvt_pk_bf16(float lo, float hi) {
  unsigned r;
  asm("v_cvt_pk_bf16_f32 %0, %1, %2" : "=v"(r) : "v"(lo), "v"(hi));
  return r;
}

// ---------------- K1: MFMA GEMM (A direct-to-reg) + fused alpha/fp8 epilogue ----------------
// hx row per node: 32 u32 = 128B ALIGNED.
//   words 0..7  : packed {exp(as),exp(.2as)} per head (src-side, line 0)
//   words 8..15 : packed {exp(ad),exp(.2ad)} per head (dst-side, line 0)
//   words 16..31: 64 channels fp8 e4m3 (line 1, exactly one 64B line)
__global__ __launch_bounds__(256) void k_gemm1_mfma(const float* __restrict__ x,
                                                    const unsigned short* __restrict__ Wt,
                                                    const float* __restrict__ a1s,
                                                    const float* __restrict__ a1d,
                                                    unsigned* __restrict__ hx, int N) {
  __shared__ __align__(16) float Sm[64 * 64];        // 16 KB: Bs in loop, Asf in epilogue
  unsigned short* Bs = (unsigned short*)Sm;
  float* Asf = Sm;
  const int t = threadIdx.x;
  const int w = t >> 6;
  const int l = t & 63;
  const int fr = l & 15;
  const int fq = l >> 4;
  const int rowbase = blockIdx.x * 128;
  f32x4 acc[2][4] = {};

  const int r0g = rowbase + w * 32 + fr;
  const int r1g = r0g + 16;
  const bool v0 = r0g < N, v1 = r1g < N;
  const float* xr0 = x + (size_t)r0g * 512 + fq * 8;
  const float* xr1 = x + (size_t)r1g * 512 + fq * 8;

  for (int k0 = 0; k0 < 512; k0 += 64) {
#pragma unroll
    for (int rep = 0; rep < 2; ++rep) {
      int i = t + rep * 256;
      int c = i >> 3, ch = i & 7;
      uint4 v = *(const uint4*)(Wt + (size_t)c * 512 + k0 + ch * 8);
      *((uint4*)(Bs + c * 64 + (ch ^ (c & 7)) * 8)) = v;
    }
    bf16x8 a[2][2];
#pragma unroll
    for (int m = 0; m < 2; ++m) {
      const float* xr = m ? xr1 : xr0;
      bool vv = m ? v1 : v0;
#pragma unroll
      for (int ks = 0; ks < 2; ++ks) {
        float4 f0 = make_float4(0.f, 0.f, 0.f, 0.f), f1 = f0;
        if (vv) {
          f0 = *(const float4*)(xr + k0 + ks * 32);
          f1 = *(const float4*)(xr + k0 + ks * 32 + 4);
        }
        union { unsigned u[4]; bf16x8 v8; } un;
        un.u[0] = cvt_pk_bf16(f0.x, f0.y);
        un.u[1] = cvt_pk_bf16(f0.z, f0.w);
        un.u[2] = cvt_pk_bf16(f1.x, f1.y);
        un.u[3] = cvt_pk_bf16(f1.z, f1.w);
        a[m][ks] = un.v8;
      }
    }
    __syncthreads();
#pragma unroll
    for (int ks = 0; ks < 2; ++ks) {
      bf16x8 b[4];
#pragma unroll
      for (int n = 0; n < 4; ++n) {
        int c = n * 16 + fr;
        int ch = (ks * 4 + fq) ^ (c & 7);
        b[n] = *((const bf16x8*)(Bs + c * 64 + ch * 8));
      }
#pragma unroll
      for (int m = 0; m < 2; ++m)
#pragma unroll
        for (int n = 0; n < 4; ++n)
          acc[m][n] = __builtin_amdgcn_mfma_f32_16x16x32_bf16(a[m][ks], b[n], acc[m][n], 0, 0, 0);
    }
    __syncthreads();
  }

  // ---- fused epilogue: stage tile half (64x64 f32) in LDS
#pragma unroll
  for (int m = 0; m < 2; ++m) {
    if (m) __syncthreads();
#pragma unroll
    for (int reg = 0; reg < 4; ++reg) {
      int lrow = w * 16 + fq * 4 + reg;
#pragma unroll
      for (int n = 0; n < 4; ++n)
        Asf[lrow * 64 + n * 16 + fr] = acc[m][n][reg];
    }
    __syncthreads();
    // fp8 pack -> hx words 16..31
#pragma unroll
    for (int p = 0; p < 4; ++p) {
      int flat = p * 256 + t;
      int lrow = flat >> 4, j = flat & 15;
      int g = rowbase + ((lrow >> 4) << 5) + m * 16 + (lrow & 15);
      float4 f = *(float4*)(Asf + lrow * 64 + j * 4);
      unsigned u = __builtin_amdgcn_cvt_pk_fp8_f32(f.x, f.y, 0u, 0);
      u = __builtin_amdgcn_cvt_pk_fp8_f32(f.z, f.w, u, 1);
      if (g < N) hx[(size_t)g * 32 + 16 + j] = u;
    }
    // alpha tables -> hx words 0..7 (src) and 8..15 (dst)
#pragma unroll
    for (int p = 0; p < 2; ++p) {
      int flat = p * 256 + t;
      int lrow = flat >> 3, hh = flat & 7;
      int g = rowbase + ((lrow >> 4) << 5) + m * 16 + (lrow & 15);
      float4 f0 = *(float4*)(Asf + lrow * 64 + hh * 8);
      float4 f1 = *(float4*)(Asf + lrow * 64 + hh * 8 + 4);
      const float* sa = a1s + hh * 8;
      const float* da = a1d + hh * 8;
      float ss = f0.x*sa[0]+f0.y*sa[1]+f0.z*sa[2]+f0.w*sa[3]
               + f1.x*sa[4]+f1.y*sa[5]+f1.z*sa[6]+f1.w*sa[7];
      float dd = f0.x*da[0]+f0.y*da[1]+f0.z*da[2]+f0.w*da[3]
               + f1.x*da[4]+f1.y*da[5]+f1.z*da[6]+f1.w*da[7];
      if (g < N) {
        hx[(size_t)g * 32 + hh]     = cvt_pk_bf16(expf(ss), expf(NEG_SLOPE * ss));
        hx[(size_t)g * 32 + 8 + hh] = cvt_pk_bf16(expf(dd), expf(NEG_SLOPE * dd));
      }
    }
  }
}

// ---------------- CSR build ----------------
// bhist + fused Wt conversion (extra blocks); bucketCount pre-zeroed by memsetAsync.
__global__ __launch_bounds__(256) void k_bhist_cvtW(const int* __restrict__ dst,
                                                    int* __restrict__ bucketCount,
                                                    const float* __restrict__ W,
                                                    unsigned short* __restrict__ Wt,
                                                    int E, int B, int EB) {
  int blk = blockIdx.x;
  int t = threadIdx.x;
  if (blk >= EB) {
    int i = (blk - EB) * 256 + t;   // i = k*64 + c
    if (i < 512 * 64) {
      int k = i >> 6, c = i & 63;
      Wt[(size_t)c * 512 + k] = f2bf(W[i]);
    }
    return;
  }
  __shared__ int h[512];
  for (int i = t; i < B; i += 256) h[i] = 0;
  __syncthreads();
  int e0 = blk * EPB;
#pragma unroll
  for (int i = 0; i < EPB / 256; ++i) {
    int e = e0 + i * 256 + t;
    if (e < E) atomicAdd(&h[dst[e] >> BKT_SHIFT], 1);
  }
  __syncthreads();
  for (int i = t; i < B; i += 256)
    if (h[i]) atomicAdd(bucketCount + i, h[i]);
}

// radix partition with LOCAL bucket scan; gCursorRel is relative (pre-zeroed).
__global__ __launch_bounds__(256) void k_bin(const int* __restrict__ src,
                                             const int* __restrict__ dst,
                                             const int* __restrict__ bucketCount,
                                             int* __restrict__ gCursorRel,
                                             unsigned* __restrict__ binned,
                                             int E, int B) {
  __shared__ int sc[512];
  __shared__ int hist[512];
  __shared__ int base[512];
  int t = threadIdx.x;
  sc[t]       = (t < B) ? bucketCount[t] : 0;
  sc[t + 256] = (t + 256 < B) ? bucketCount[t + 256] : 0;
  for (int i = t; i < 512; i += 256) hist[i] = 0;
  __syncthreads();
  for (int o = 1; o < 512; o <<= 1) {
    int a0 = (t >= o) ? sc[t - o] : 0;
    int a1 = (t + 256 >= o) ? sc[t + 256 - o] : 0;
    __syncthreads();
    sc[t] += a0;
    sc[t + 256] += a1;
    __syncthreads();
  }
  int e0 = blockIdx.x * EPB;
#pragma unroll
  for (int i = 0; i < EPB / 256; ++i) {
    int e = e0 + i * 256 + t;
    if (e < E) atomicAdd(&hist[dst[e] >> BKT_SHIFT], 1);
  }
  __syncthreads();
  for (int i = t; i < B; i += 256) {
    int c = hist[i];
    int excl = sc[i] - bucketCount[i];
    base[i] = c ? (excl + atomicAdd(gCursorRel + i, c)) : 0;
    hist[i] = 0;
  }
  __syncthreads();
#pragma unroll
  for (int i = 0; i < EPB / 256; ++i) {
    int e = e0 + i * 256 + t;
    if (e < E) {
      int d = dst[e];
      int b = d >> BKT_SHIFT;
      int r = atomicAdd(&hist[b], 1);
      binned[base[b] + r] = ((unsigned)(d & (BKT_RANGE - 1)) << 24) | (unsigned)src[e];
    }
  }
}

__global__ __launch_bounds__(256) void k_build(const int* __restrict__ bucketCount,
                                               const unsigned* __restrict__ binned,
                                               int* __restrict__ rowptr,
                                               int* __restrict__ deg,
                                               int* __restrict__ srt, int N, int B) {
  __shared__ int sc[512];
  __shared__ int ldeg[BKT_RANGE];
  __shared__ int sm[BKT_RANGE];
  __shared__ int lcur[BKT_RANGE];
  int t = threadIdx.x;
  int b = blockIdx.x;
  sc[t]       = (t < B) ? bucketCount[t] : 0;
  sc[t + 256] = (t + 256 < B) ? bucketCount[t + 256] : 0;
  ldeg[t] = 0;
  __syncthreads();
  for (int o = 1; o < 512; o <<= 1) {
    int a0 = (t >= o) ? sc[t - o] : 0;
    int a1 = (t + 256 >= o) ? sc[t + 256 - o] : 0;
    __syncthreads();
    sc[t] += a0;
    sc[t + 256] += a1;
    __syncthreads();
  }
  int eend = sc[b];
  int estart = eend - bucketCount[b];
  int nbase = b * BKT_RANGE;
  for (int e = estart + t; e < eend; e += 256)
    atomicAdd(&ldeg[binned[e] >> 24], 1);
  __syncthreads();
  int v = ldeg[t];
  sm[t] = v;
  __syncthreads();
  int acc = v;
#pragma unroll
  for (int o = 1; o < 256; o <<= 1) {
    int u = (t >= o) ? sm[t - o] : 0;
    __syncthreads();
    acc += u;
    sm[t] = acc;
    __syncthreads();
  }
  int excl = estart + acc - v;
  int node = nbase + t;
  if (node < N) {
    rowptr[node] = excl;
    deg[node] = v;
  }
  lcur[t] = excl;
  __syncthreads();
  for (int e = estart + t; e < eend; e += 256) {
    unsigned p = binned[e];
    int pos = atomicAdd(&lcur[p >> 24], 1);
    srt[pos] = (int)(p & 0xFFFFFFu);
  }
}

// ---------------- K agg1f: gather-reduce L1 (128B hx rows) + fused L2 node work ----------------
// h2x row per node: 16 u32 = 64B ALIGNED (one line):
//   word 0: packed {exp(as2),exp(.2as2)}; words 2,3: f32 {exp(ad2),exp(.2ad2)};
//   words 4..11: 16 channels bf16.
__global__ __launch_bounds__(256) void k_agg1f(const int* __restrict__ rowptr,
                                               const int* __restrict__ deg,
                                               const int* __restrict__ srt,
                                               const unsigned* __restrict__ hx,
                                               const float* __restrict__ b1,
                                               const float* __restrict__ W2,
                                               const float* __restrict__ a2s,
                                               const float* __restrict__ a2d,
                                               unsigned* __restrict__ h2x, int N) {
  __shared__ float vsm[4][64];
  const int t = threadIdx.x;
  const int w = t >> 6;
  const int lane = t & 63;
  const int wid = blockIdx.x * 4 + w;
  const int slot = lane >> 4;
  const int c4 = lane & 15;
  const int h = c4 >> 1;
  float a2sr = a2s[c4];
  float a2dr = a2d[c4];
  float wreg[16];
#pragma unroll
  for (int m = 0; m < 16; ++m) wreg[m] = W2[(slot * 16 + m) * 16 + c4];
  float4 b1v = *(const float4*)(b1 + c4 * 4);
  if (wid >= N) return;
  const int d = wid;

  unsigned ddu = hx[(size_t)d * 32 + 8 + h];
  float ddx = bflo(ddu), ddy = bfhi(ddu);
  // self loop (slot 0 only)
  unsigned es0 = hx[(size_t)d * 32 + h];
  unsigned sv = hx[(size_t)d * 32 + 16 + c4];
  float ex0 = fmaxf(bflo(es0) * ddx, bfhi(es0) * ddy);
  ex0 = (slot == 0) ? ex0 : 0.f;
  float a0 = ex0 * __builtin_amdgcn_cvt_f32_fp8(sv, 0);
  float a1 = ex0 * __builtin_amdgcn_cvt_f32_fp8(sv, 1);
  float a2 = ex0 * __builtin_amdgcn_cvt_f32_fp8(sv, 2);
  float a3 = ex0 * __builtin_amdgcn_cvt_f32_fp8(sv, 3);
  float den = ex0;

  int start = rowptr[d];
  int len = deg[d];
  for (int kb = 0; kb < len; kb += 64) {
    int li = kb + lane;
    int sreg = (li < len) ? srt[start + li] : 0;
    int nit = min(16, (len - kb + 3) >> 2);
#pragma unroll 4
    for (int it = 0; it < nit; ++it) {
      int idx = kb + it * 4 + slot;
      int s = __shfl(sreg, it * 4 + slot);
      bool valid = idx < len;
      unsigned es = hx[(size_t)s * 32 + h];
      unsigned hv = hx[(size_t)s * 32 + 16 + c4];
      float ex = fmaxf(bflo(es) * ddx, bfhi(es) * ddy);
      ex = valid ? ex : 0.f;
      a0 = fmaf(ex, __builtin_amdgcn_cvt_f32_fp8(hv, 0), a0);
      a1 = fmaf(ex, __builtin_amdgcn_cvt_f32_fp8(hv, 1), a1);
      a2 = fmaf(ex, __builtin_amdgcn_cvt_f32_fp8(hv, 2), a2);
      a3 = fmaf(ex, __builtin_amdgcn_cvt_f32_fp8(hv, 3), a3);
      den += ex;
    }
  }
#pragma unroll
  for (int o = 16; o < 64; o <<= 1) {
    a0 += __shfl_xor(a0, o);
    a1 += __shfl_xor(a1, o);
    a2 += __shfl_xor(a2, o);
    a3 += __shfl_xor(a3, o);
    den += __shfl_xor(den, o);
  }
  float rden = 1.f / (den + 1e-16f);
  if (slot == 0) {
    float4 vv;
    vv.x = elu1(a0 * rden + b1v.x);
    vv.y = elu1(a1 * rden + b1v.y);
    vv.z = elu1(a2 * rden + b1v.z);
    vv.w = elu1(a3 * rden + b1v.w);
    *(float4*)&vsm[w][c4 * 4] = vv;
  }
  float partial = 0.f;
#pragma unroll
  for (int m = 0; m < 16; ++m) partial = fmaf(vsm[w][slot * 16 + m], wreg[m], partial);
  float qs = partial * a2sr;
  float qd = partial * a2dr;
#pragma unroll
  for (int o = 1; o < 64; o <<= 1) {
    qs += __shfl_xor(qs, o);
    qd += __shfl_xor(qd, o);
  }
  float p2 = partial + __shfl_down(partial, 32);
  float hcv = p2 + __shfl_down(p2, 16);
  if (lane < 16)
    ((unsigned short*)h2x)[(size_t)d * 32 + 8 + c4] = f2bf(hcv);
  if (lane == 0) {
    h2x[(size_t)d * 16] = cvt_pk_bf16(expf(qs), expf(NEG_SLOPE * qs));
    *(float2*)(h2x + (size_t)d * 16 + 2) = make_float2(expf(qd), expf(NEG_SLOPE * qd));
  }
}

// ---------------- K agg2: gather-reduce layer 2 (64B h2x rows) + b2 + log_softmax ----------------
__global__ __launch_bounds__(256) void k_agg2(const int* __restrict__ rowptr,
                                              const int* __restrict__ deg,
                                              const int* __restrict__ srt,
                                              const unsigned* __restrict__ h2x,
                                              const float* __restrict__ b2,
                                              float* __restrict__ out, int N) {
  const int t = threadIdx.x;
  const int lane = t & 63;
  const int wid = (blockIdx.x * 256 + t) >> 6;
  const int slot = lane >> 2;
  const int cg = lane & 3;
  float4 b2v = *(const float4*)(b2 + cg * 4);
  if (wid >= N) return;
  const int d = wid;
  float2 ddp = *(const float2*)(h2x + (size_t)d * 16 + 2);
  unsigned ps0 = h2x[(size_t)d * 16];
  uint2 sv = *(const uint2*)(h2x + (size_t)d * 16 + 4 + cg * 2);
  float ex0 = fmaxf(bflo(ps0) * ddp.x, bfhi(ps0) * ddp.y);
  ex0 = (slot == 0) ? ex0 : 0.f;
  float a0 = ex0 * bflo(sv.x), a1 = ex0 * bfhi(sv.x);
  float a2 = ex0 * bflo(sv.y), a3 = ex0 * bfhi(sv.y);
  float den = ex0;

  int start = rowptr[d];
  int len = deg[d];
  for (int kb = 0; kb < len; kb += 64) {
    int li = kb + lane;
    int sreg = (li < len) ? srt[start + li] : 0;
    int nit = min(4, (len - kb + 15) >> 4);
#pragma unroll 4
    for (int it = 0; it < nit; ++it) {
      int idx = kb + it * 16 + slot;
      int s = __shfl(sreg, it * 16 + slot);
      bool valid = idx < len;
      unsigned ps = h2x[(size_t)s * 16];
      uint2 hv = *(const uint2*)(h2x + (size_t)s * 16 + 4 + cg * 2);
      float ex = fmaxf(bflo(ps) * ddp.x, bfhi(ps) * ddp.y);
      ex = valid ? ex : 0.f;
      a0 = fmaf(ex, bflo(hv.x), a0);
      a1 = fmaf(ex, bfhi(hv.x), a1);
      a2 = fmaf(ex, bflo(hv.y), a2);
      a3 = fmaf(ex, bfhi(hv.y), a3);
      den += ex;
    }
  }
#pragma unroll
  for (int o = 4; o < 64; o <<= 1) {
    a0 += __shfl_xor(a0, o);
    a1 += __shfl_xor(a1, o);
    a2 += __shfl_xor(a2, o);
    a3 += __shfl_xor(a3, o);
    den += __shfl_xor(den, o);
  }
  float rden = 1.f / (den + 1e-16f);
  float v0 = a0 * rden + b2v.x;
  float v1 = a1 * rden + b2v.y;
  float v2 = a2 * rden + b2v.z;
  float v3 = a3 * rden + b2v.w;
  float m = fmaxf(fmaxf(v0, v1), fmaxf(v2, v3));
  m = fmaxf(m, __shfl_xor(m, 1));
  m = fmaxf(m, __shfl_xor(m, 2));
  float s = expf(v0 - m) + expf(v1 - m) + expf(v2 - m) + expf(v3 - m);
  s += __shfl_xor(s, 1);
  s += __shfl_xor(s, 2);
  float lse = m + logf(s);
  if (lane < 4) {
    float4 o4 = make_float4(v0 - lse, v1 - lse, v2 - lse, v3 - lse);
    *(float4*)(out + (size_t)d * 16 + cg * 4) = o4;
  }
}

extern "C" void kernel_launch(void* const* d_in, const int* in_sizes, int n_in,
                              void* d_out, int out_size, void* d_ws, size_t ws_size,
                              hipStream_t stream) {
  const float* x    = (const float*)d_in[0];
  const int*   ei   = (const int*)d_in[1];
  const float* W1   = (const float*)d_in[2];
  const float* a1s  = (const float*)d_in[3];
  const float* a1d  = (const float*)d_in[4];
  const float* b1   = (const float*)d_in[5];
  const float* W2   = (const float*)d_in[6];
  const float* a2s  = (const float*)d_in[7];
  const float* a2d  = (const float*)d_in[8];
  const float* b2   = (const float*)d_in[9];
  float* out = (float*)d_out;

  const int N = in_sizes[0] / 512;
  const int E = in_sizes[1] / 2;
  const int* src = ei;
  const int* dst = ei + E;
  const int B = (N + BKT_RANGE - 1) >> BKT_SHIFT;
  const int EB = (E + EPB - 1) / EPB;

  // 128B-aligned workspace carve-up (d_ws is at least 256B aligned)
  float* w = (float*)d_ws;
  unsigned* hx  = (unsigned*)w;             w += (size_t)N * 32;   // 128B rows
  unsigned* h2x = (unsigned*)w;             w += (size_t)N * 16;   // 64B rows
  unsigned short* Wt = (unsigned short*)w;  w += 512 * 64 / 2;
  int* iw = (int*)w;
  int* deg         = iw;  iw += N;
  int* rowptr      = iw;  iw += N;
  int* bucketCount = iw;  iw += 512;
  int* gCursorRel  = iw;  iw += 512;
  int* srt         = iw;  iw += E;
  unsigned* binned = (unsigned*)iw;  iw += E;

  // zero bucketCount + gCursorRel (contiguous 1024 ints)
  hipMemsetAsync(bucketCount, 0, 1024 * sizeof(int), stream);

  // CSR build (+ fused Wt conversion blocks)
  k_bhist_cvtW<<<EB + 128, 256, 0, stream>>>(dst, bucketCount, W1, Wt, E, B, EB);
  k_bin<<<EB, 256, 0, stream>>>(src, dst, bucketCount, gCursorRel, binned, E, B);
  k_build<<<B, 256, 0, stream>>>(bucketCount, binned, rowptr, deg, srt, N, B);

  // Layer 1: GEMM with fused alpha/fp8 epilogue, then gather (+fused L2 node work)
  k_gemm1_mfma<<<(N + 127) / 128, 256, 0, stream>>>(x, Wt, a1s, a1d, hx, N);
  k_agg1f<<<(N + 3) / 4, 256, 0, stream>>>(rowptr, deg, srt, hx,
                                           b1, W2, a2s, a2d, h2x, N);

  // Layer 2
  k_agg2<<<(N + 3) / 4, 256, 0, stream>>>(rowptr, deg, srt, h2x, b2, out, N);
}